// Round 6
// baseline (6922.483 us; speedup 1.0000x reference)
//
#include <hip/hip_runtime.h>
#include <cstddef>
#include <cstdint>

#define NB 2

// Nmax per resolution (upper bounds on active sites, both batches)
#define NMAX512 32768
#define NMAX256 28672
#define NMAX128 20480
#define NMAX64  8192
#define NMAX32  2048

// ------------------------------------------------------------------ list build (res 512 from x, Cin=1)
__global__ __launch_bounds__(256) void build_l0_k(const float* __restrict__ x,
    int* __restrict__ list, int* __restrict__ im, float* __restrict__ f0,
    int* __restrict__ nact, int total, int nmax) {
  int i = blockIdx.x * 256 + threadIdx.x;
  bool act = false;
  float v = 0.f;
  if (i < total) { v = x[i]; act = (v != 0.f); }
  unsigned long long mb = __ballot(act);
  int lane = threadIdx.x & 63;
  int prefix = __popcll(mb & ((1ull << lane) - 1));
  int base = 0;
  if (lane == 0) base = atomicAdd(nact, __popcll(mb));
  base = __shfl(base, 0);
  if (i < total) {
    int idx = act ? (base + prefix) : -1;
    if (idx >= nmax) idx = -1;
    im[i] = idx;
    if (idx >= 0) {
      int b = i >> 18;            // 512*512 = 2^18
      int rem = i & 262143;
      list[idx] = (b << 20) | ((rem >> 9) << 10) | (rem & 511);
      f0[idx] = v;
    }
  }
}

// ------------------------------------------------------------------ pooled list from finer idxmap
__global__ __launch_bounds__(256) void build_pl_k(const int* __restrict__ imF,
    int* __restrict__ list, int* __restrict__ im, int* __restrict__ nact,
    int Hc, int nmax) {
  int total = NB * Hc * Hc;
  int i = blockIdx.x * 256 + threadIdx.x;
  bool act = false;
  int b = 0, y = 0, x = 0;
  int Hf = Hc * 2;
  if (i < total) {
    x = i % Hc; y = (i / Hc) % Hc; b = i / (Hc * Hc);
    const int* p = imF + ((size_t)b * Hf + 2 * y) * Hf + 2 * x;
    act = (p[0] >= 0) || (p[1] >= 0) || (p[Hf] >= 0) || (p[Hf + 1] >= 0);
  }
  unsigned long long mb = __ballot(act);
  int lane = threadIdx.x & 63;
  int prefix = __popcll(mb & ((1ull << lane) - 1));
  int base = 0;
  if (lane == 0) base = atomicAdd(nact, __popcll(mb));
  base = __shfl(base, 0);
  if (i < total) {
    int idx = act ? (base + prefix) : -1;
    if (idx >= nmax) idx = -1;
    im[i] = idx;
    if (idx >= 0) list[idx] = (b << 20) | (y << 10) | x;
  }
}

// ------------------------------------------------------------------ 9-neighbor index table
__global__ __launch_bounds__(256) void build_nbr_k(const int* __restrict__ list,
    const int* __restrict__ im, const int* __restrict__ nactp,
    int* __restrict__ nbr, int H, int nmax) {
  int i = blockIdx.x * 256 + threadIdx.x;
  if (i >= nactp[0]) return;
  int code = list[i];
  int b = code >> 20, y = (code >> 10) & 1023, x = code & 1023;
#pragma unroll
  for (int k = 0; k < 9; ++k) {
    int yy = y + k / 3 - 1, xx = x + k % 3 - 1;
    int v = -1;
    if (yy >= 0 && yy < H && xx >= 0 && xx < H)
      v = im[((size_t)b * H + yy) * H + xx];
    nbr[k * nmax + i] = v;
  }
}

// ------------------------------------------------------------------ weight transpose  [R][C] -> [C][R]
__global__ __launch_bounds__(256) void transpose_k(const float* __restrict__ in,
                                                   float* __restrict__ out,
                                                   int R, int C) {
  __shared__ float tile[32][33];
  int bx = blockIdx.x * 32;  // col base (C dim)
  int by = blockIdx.y * 32;  // row base (R dim)
  int tx = threadIdx.x % 32, ty0 = threadIdx.x / 32;
  for (int ty = ty0; ty < 32; ty += 8) {
    int r = by + ty, c = bx + tx;
    tile[ty][tx] = (r < R && c < C) ? in[(size_t)r * C + c] : 0.f;
  }
  __syncthreads();
  for (int ty = ty0; ty < 32; ty += 8) {
    int r = bx + ty, c = by + tx;
    if (r < C && c < R) out[(size_t)r * R + c] = tile[tx][ty];
  }
}

// ------------------------------------------------------------------ gather-GEMM submanifold conv (256 thr, 4x8 / L1 variant)
// Used for L1-L4 and L11-13 (proven round-3 config).
template <int CC, int SITES, int OCB, int SPT, int OPT, bool RAW>
__global__ __launch_bounds__(256, 2) void gconv_k(
    const float* __restrict__ in, float* __restrict__ out,
    const float* __restrict__ wT, const float* __restrict__ bias,
    const int* __restrict__ nbr, const int* __restrict__ nactp,
    int Cin, int Cout, int Nmax, int cinCnt, int nocb) {
  constexpr int KSL = CC * 9;
  __shared__ int s_nbr[9][SITES];
  __shared__ float s_a[KSL][SITES];
  __shared__ float s_w[KSL][OCB];
  const int n = nactp[0];
  const int gid = blockIdx.x;
  const int xcd = gid & 7;
  const int pos = gid >> 3;
  const int ocbI = pos % nocb;
  const int sb = (pos / nocb) * 8 + xcd;
  const int base = sb * SITES;
  if (base >= n) return;
  const int ocb = ocbI * OCB;
  const int t = threadIdx.x;
  for (int s = t; s < 9 * SITES; s += 256) {
    int i = s % SITES, k = s / SITES;
    int gi = base + i;
    s_nbr[k][i] = (gi < n) ? nbr[k * Nmax + gi] : -1;
  }
  constexpr int OCG = OCB / OPT;
  const int oc0 = (t % OCG) * 4;           // 4-float chunk base
  const int si0 = (t / OCG) * SPT;
  float acc[SPT][OPT];
#pragma unroll
  for (int a = 0; a < SPT; ++a)
#pragma unroll
    for (int j = 0; j < OPT; ++j) acc[a][j] = 0.f;
  __syncthreads();
  const int cinStart = RAW ? (blockIdx.z * cinCnt) : 0;
  const int nch = cinCnt / CC;
  for (int ch = 0; ch < nch; ++ch) {
    const int c0 = cinStart + ch * CC;
    const float* wrow = wT + ((size_t)c0 * 9) * Cout + ocb;
    for (int s = t; s < KSL * (OCB / 4); s += 256) {
      int j4 = s % (OCB / 4), r = s / (OCB / 4);
      *(float4*)&s_w[r][j4 * 4] = *(const float4*)(wrow + (size_t)r * Cout + j4 * 4);
    }
    if constexpr (CC == 1) {
      for (int s = t; s < 9 * SITES; s += 256) {
        int i = s % SITES, k = s / SITES;
        int row = s_nbr[k][i];
        s_a[k][i] = (row >= 0) ? in[row] : 0.f;
      }
    } else {
      constexpr int H4 = CC / 4;
      for (int s = t; s < H4 * 9 * SITES; s += 256) {
        int i = s % SITES, m = s / SITES;
        int c4 = m % H4, k = m / H4;
        int row = s_nbr[k][i];
        float4 v = make_float4(0.f, 0.f, 0.f, 0.f);
        if (row >= 0)
          v = *(const float4*)(in + (size_t)row * Cin + c0 + c4 * 4);
        s_a[(c4 * 4 + 0) * 9 + k][i] = v.x;
        s_a[(c4 * 4 + 1) * 9 + k][i] = v.y;
        s_a[(c4 * 4 + 2) * 9 + k][i] = v.z;
        s_a[(c4 * 4 + 3) * 9 + k][i] = v.w;
      }
    }
    __syncthreads();
#pragma unroll
    for (int kk = 0; kk < KSL; ++kk) {
      float av[SPT];
      if constexpr (SPT == 4) {
        float4 a4 = *(const float4*)&s_a[kk][si0];
        av[0] = a4.x; av[1] = a4.y; av[2] = a4.z; av[3] = a4.w;
      } else {
        float2 a2 = *(const float2*)&s_a[kk][si0];
        av[0] = a2.x; av[1] = a2.y;
      }
      float wv[OPT];
      if constexpr (OPT == 8) {
        float4 w4a = *(const float4*)&s_w[kk][oc0];
        float4 w4b = *(const float4*)&s_w[kk][OCB / 2 + oc0];
        wv[0] = w4a.x; wv[1] = w4a.y; wv[2] = w4a.z; wv[3] = w4a.w;
        wv[4] = w4b.x; wv[5] = w4b.y; wv[6] = w4b.z; wv[7] = w4b.w;
      } else {
        float4 w4 = *(const float4*)&s_w[kk][oc0];
        wv[0] = w4.x; wv[1] = w4.y; wv[2] = w4.z; wv[3] = w4.w;
      }
#pragma unroll
      for (int a = 0; a < SPT; ++a)
#pragma unroll
        for (int j = 0; j < OPT; ++j)
          acc[a][j] = fmaf(av[a], wv[j], acc[a][j]);
    }
    __syncthreads();
  }
  float bz[OPT];
  if constexpr (!RAW) {
#pragma unroll
    for (int j = 0; j < OPT; ++j) {
      int oj = (OPT == 8) ? ((j < 4) ? (oc0 + j) : (OCB / 2 + oc0 + j - 4))
                          : (oc0 + j);
      bz[j] = bias[ocb + oj];
    }
  }
  float* ob = out;
  if constexpr (RAW) ob += (size_t)blockIdx.z * Nmax * Cout;
#pragma unroll
  for (int a = 0; a < SPT; ++a) {
    int gi = base + si0 + a;
    if (gi < n) {
      float* po = ob + (size_t)gi * Cout + ocb;
      if constexpr (OPT == 8) {
        float4 v0, v1;
        if constexpr (RAW) {
          v0 = make_float4(acc[a][0], acc[a][1], acc[a][2], acc[a][3]);
          v1 = make_float4(acc[a][4], acc[a][5], acc[a][6], acc[a][7]);
        } else {
          v0.x = fmaxf(acc[a][0] + bz[0], 0.f); v0.y = fmaxf(acc[a][1] + bz[1], 0.f);
          v0.z = fmaxf(acc[a][2] + bz[2], 0.f); v0.w = fmaxf(acc[a][3] + bz[3], 0.f);
          v1.x = fmaxf(acc[a][4] + bz[4], 0.f); v1.y = fmaxf(acc[a][5] + bz[5], 0.f);
          v1.z = fmaxf(acc[a][6] + bz[6], 0.f); v1.w = fmaxf(acc[a][7] + bz[7], 0.f);
        }
        *(float4*)(po + oc0) = v0;
        *(float4*)(po + OCB / 2 + oc0) = v1;
      } else {
        float4 v;
        if constexpr (RAW) {
          v = make_float4(acc[a][0], acc[a][1], acc[a][2], acc[a][3]);
        } else {
          v.x = fmaxf(acc[a][0] + bz[0], 0.f); v.y = fmaxf(acc[a][1] + bz[1], 0.f);
          v.z = fmaxf(acc[a][2] + bz[2], 0.f); v.w = fmaxf(acc[a][3] + bz[3], 0.f);
        }
        *(float4*)(po + oc0) = v;
      }
    }
  }
}

// ------------------------------------------------------------------ 128-thread 8x8 gather-GEMM (L5-L10)
// SITES=64 x OCB=128, thread tile 8 sites x 8 oc (split-oc), 2 waves/block,
// LDS 29.9KB -> up to 5 blocks/CU. Grid stays >= 492 blocks for deep layers.
// Per kk: 4 ds_read_b128 per 64 FMA-inst -> LDS:VALU = 1.5 (was 2.25 in 4x8).
template <int CC, bool RAW>
__global__ __launch_bounds__(128, 3) void gconv8_k(
    const float* __restrict__ in, float* __restrict__ out,
    const float* __restrict__ wT, const float* __restrict__ bias,
    const int* __restrict__ nbr, const int* __restrict__ nactp,
    int Cin, int Cout, int Nmax, int cinCnt, int nocb) {
  constexpr int KSL = CC * 9;
  constexpr int SITES = 64, OCB = 128;
  __shared__ int s_nbr[9][SITES];
  __shared__ float s_a[KSL][SITES];
  __shared__ float s_w[KSL][OCB];
  const int n = nactp[0];
  const int gid = blockIdx.x;
  const int xcd = gid & 7;
  const int pos = gid >> 3;
  const int ocbI = pos % nocb;
  const int sb = (pos / nocb) * 8 + xcd;
  const int base = sb * SITES;
  if (base >= n) return;
  const int ocb = ocbI * OCB;
  const int t = threadIdx.x;
  for (int s = t; s < 9 * SITES; s += 128) {
    int i = s & 63, k = s >> 6;
    int gi = base + i;
    s_nbr[k][i] = (gi < n) ? nbr[k * Nmax + gi] : -1;
  }
  const int oc0 = (t & 15) * 4;   // 16 oc-groups
  const int si0 = (t >> 4) * 8;   // 8 site-groups
  float acc[8][8];
#pragma unroll
  for (int a = 0; a < 8; ++a)
#pragma unroll
    for (int j = 0; j < 8; ++j) acc[a][j] = 0.f;
  __syncthreads();
  const int cinStart = RAW ? (blockIdx.z * cinCnt) : 0;
  const int nch = cinCnt / CC;
  for (int ch = 0; ch < nch; ++ch) {
    const int c0 = cinStart + ch * CC;
    const float* wrow = wT + ((size_t)c0 * 9) * Cout + ocb;
    for (int s = t; s < KSL * (OCB / 4); s += 128) {
      int j4 = s & 31, r = s >> 5;  // OCB/4 = 32
      *(float4*)&s_w[r][j4 * 4] = *(const float4*)(wrow + (size_t)r * Cout + j4 * 4);
    }
    constexpr int H4 = CC / 4;
    for (int s = t; s < H4 * 9 * SITES; s += 128) {
      int i = s & 63, m = s >> 6;
      int c4 = m % H4, k = m / H4;
      int row = s_nbr[k][i];
      float4 v = make_float4(0.f, 0.f, 0.f, 0.f);
      if (row >= 0)
        v = *(const float4*)(in + (size_t)row * Cin + c0 + c4 * 4);
      s_a[(c4 * 4 + 0) * 9 + k][i] = v.x;
      s_a[(c4 * 4 + 1) * 9 + k][i] = v.y;
      s_a[(c4 * 4 + 2) * 9 + k][i] = v.z;
      s_a[(c4 * 4 + 3) * 9 + k][i] = v.w;
    }
    __syncthreads();
#pragma unroll
    for (int kk = 0; kk < KSL; ++kk) {
      float4 a0 = *(const float4*)&s_a[kk][si0];
      float4 a1 = *(const float4*)&s_a[kk][si0 + 4];
      float4 w4a = *(const float4*)&s_w[kk][oc0];
      float4 w4b = *(const float4*)&s_w[kk][64 + oc0];
      float av[8] = {a0.x, a0.y, a0.z, a0.w, a1.x, a1.y, a1.z, a1.w};
      float wv[8] = {w4a.x, w4a.y, w4a.z, w4a.w, w4b.x, w4b.y, w4b.z, w4b.w};
#pragma unroll
      for (int a = 0; a < 8; ++a)
#pragma unroll
        for (int j = 0; j < 8; ++j)
          acc[a][j] = fmaf(av[a], wv[j], acc[a][j]);
    }
    __syncthreads();
  }
  float bz[8];
  if constexpr (!RAW) {
#pragma unroll
    for (int j = 0; j < 8; ++j) {
      int oj = (j < 4) ? (oc0 + j) : (64 + oc0 + j - 4);
      bz[j] = bias[ocb + oj];
    }
  }
  float* ob = out;
  if constexpr (RAW) ob += (size_t)blockIdx.z * Nmax * Cout;
#pragma unroll
  for (int a = 0; a < 8; ++a) {
    int gi = base + si0 + a;
    if (gi < n) {
      float* po = ob + (size_t)gi * Cout + ocb;
      float4 v0, v1;
      if constexpr (RAW) {
        v0 = make_float4(acc[a][0], acc[a][1], acc[a][2], acc[a][3]);
        v1 = make_float4(acc[a][4], acc[a][5], acc[a][6], acc[a][7]);
      } else {
        v0.x = fmaxf(acc[a][0] + bz[0], 0.f); v0.y = fmaxf(acc[a][1] + bz[1], 0.f);
        v0.z = fmaxf(acc[a][2] + bz[2], 0.f); v0.w = fmaxf(acc[a][3] + bz[3], 0.f);
        v1.x = fmaxf(acc[a][4] + bz[4], 0.f); v1.y = fmaxf(acc[a][5] + bz[5], 0.f);
        v1.z = fmaxf(acc[a][6] + bz[6], 0.f); v1.w = fmaxf(acc[a][7] + bz[7], 0.f);
      }
      *(float4*)(po + oc0) = v0;
      *(float4*)(po + 64 + oc0) = v1;
    }
  }
}

// ------------------------------------------------------------------ K-split combine (+bias+relu)
__global__ __launch_bounds__(256) void combine_k(const float* __restrict__ P,
    float* __restrict__ out, const float* __restrict__ bias,
    const int* __restrict__ nactp, int C, int S, int sliceStride) {
  int tg = blockIdx.x * 256 + threadIdx.x;
  int cg = C >> 2;
  int j = tg / cg, c4 = tg % cg;
  if (j >= nactp[0]) return;
  size_t o = (size_t)j * C + c4 * 4;
  float4 v = *(const float4*)(bias + c4 * 4);
  for (int s = 0; s < S; ++s) {
    float4 u = *(const float4*)(P + (size_t)s * sliceStride + o);
    v.x += u.x; v.y += u.y; v.z += u.z; v.w += u.w;
  }
  v.x = fmaxf(v.x, 0.f); v.y = fmaxf(v.y, 0.f);
  v.z = fmaxf(v.z, 0.f); v.w = fmaxf(v.w, 0.f);
  *(float4*)(out + o) = v;
}

// ------------------------------------------------------------------ compact 2x2 maxpool
__global__ __launch_bounds__(256) void pool_c_k(const float* __restrict__ inF,
    float* __restrict__ outF, const int* __restrict__ listC,
    const int* __restrict__ imF, const int* __restrict__ nactp, int Hf, int C) {
  int tg = blockIdx.x * 256 + threadIdx.x;
  int cg = C >> 2;
  int j = tg / cg, c4 = tg % cg;
  if (j >= nactp[0]) return;
  int code = listC[j];
  int b = code >> 20, Y = (code >> 10) & 1023, X = code & 1023;
  float4 v = make_float4(0.f, 0.f, 0.f, 0.f);
#pragma unroll
  for (int dy = 0; dy < 2; ++dy)
#pragma unroll
    for (int dx = 0; dx < 2; ++dx) {
      int ci = imF[((size_t)b * Hf + 2 * Y + dy) * Hf + 2 * X + dx];
      if (ci >= 0) {
        float4 u = *(const float4*)(inF + (size_t)ci * C + c4 * 4);
        v.x = fmaxf(v.x, u.x); v.y = fmaxf(v.y, u.y);
        v.z = fmaxf(v.z, u.z); v.w = fmaxf(v.w, u.w);
      }
    }
  *(float4*)(outF + (size_t)j * C + c4 * 4) = v;
}

// ------------------------------------------------------------------ final pool -> dense [2,512,16,16]
__global__ __launch_bounds__(256) void pool_d_k(const float* __restrict__ inF,
    float* __restrict__ outD, const int* __restrict__ im32) {
  int tg = blockIdx.x * 256 + threadIdx.x;  // 2*16*16*128 = 65536
  int c4 = tg & 127;
  int rest = tg >> 7;
  int X = rest & 15, Y = (rest >> 4) & 15, b = rest >> 8;
  float4 v = make_float4(0.f, 0.f, 0.f, 0.f);
#pragma unroll
  for (int dy = 0; dy < 2; ++dy)
#pragma unroll
    for (int dx = 0; dx < 2; ++dx) {
      int ci = im32[((size_t)b * 32 + 2 * Y + dy) * 32 + 2 * X + dx];
      if (ci >= 0) {
        float4 u = *(const float4*)(inF + (size_t)ci * 512 + c4 * 4);
        v.x = fmaxf(v.x, u.x); v.y = fmaxf(v.y, u.y);
        v.z = fmaxf(v.z, u.z); v.w = fmaxf(v.w, u.w);
      }
    }
  const float* pv = &v.x;
#pragma unroll
  for (int u = 0; u < 4; ++u) {
    int c = c4 * 4 + u;
    outD[(((size_t)b * 512 + c) * 16 + Y) * 16 + X] = pv[u];
  }
}

// ------------------------------------------------------------------ fully connected
template <bool RELU>
__global__ __launch_bounds__(256) void fc_k(const float* __restrict__ in,
                                            const float* __restrict__ w,
                                            const float* __restrict__ bias,
                                            float* __restrict__ out, int K,
                                            int R) {
  const int r = blockIdx.x;
  const int t = threadIdx.x;
  const float* wr = w + (size_t)r * K;
  float a0 = 0.f, a1 = 0.f;
  for (int k = t * 4; k < K; k += 1024) {
    float4 wv = *(const float4*)(wr + k);
    float4 x0 = *(const float4*)(in + k);
    float4 x1 = *(const float4*)(in + K + k);
    a0 += wv.x * x0.x + wv.y * x0.y + wv.z * x0.z + wv.w * x0.w;
    a1 += wv.x * x1.x + wv.y * x1.y + wv.z * x1.z + wv.w * x1.w;
  }
#pragma unroll
  for (int off = 32; off > 0; off >>= 1) {
    a0 += __shfl_down(a0, off);
    a1 += __shfl_down(a1, off);
  }
  __shared__ float s0[4], s1[4];
  const int lane = t & 63, wid = t >> 6;
  if (lane == 0) { s0[wid] = a0; s1[wid] = a1; }
  __syncthreads();
  if (t == 0) {
    float v0 = s0[0] + s0[1] + s0[2] + s0[3] + bias[r];
    float v1 = s1[0] + s1[1] + s1[2] + s1[3] + bias[r];
    if (RELU) { v0 = fmaxf(v0, 0.f); v1 = fmaxf(v1, 0.f); }
    out[r] = v0;
    out[R + r] = v1;
  }
}

// ------------------------------------------------------------------ launch
extern "C" void kernel_launch(void* const* d_in, const int* in_sizes, int n_in,
                              void* d_out, int out_size, void* d_ws,
                              size_t ws_size, hipStream_t stream) {
  (void)in_sizes; (void)n_in; (void)out_size; (void)ws_size;
  const float* x = (const float*)d_in[0];
  const float* Wc[14];
  const float* Bc[14];
  for (int i = 1; i <= 13; ++i) {
    Wc[i] = (const float*)d_in[2 * i - 1];
    Bc[i] = (const float*)d_in[2 * i];
  }
  const float* fw1 = (const float*)d_in[27];
  const float* fb1 = (const float*)d_in[28];
  const float* fw2 = (const float*)d_in[29];
  const float* fb2 = (const float*)d_in[30];
  const float* fw3 = (const float*)d_in[31];
  const float* fb3 = (const float*)d_in[32];
  const float* fw4 = (const float*)d_in[33];
  const float* fb4 = (const float*)d_in[34];

  static const int CH[14] = {1, 64, 64, 128, 128, 256, 256, 256,
                             512, 512, 512, 512, 512, 512};

  char* ws = (char*)d_ws;
  size_t cur = 0;
  auto alloc = [&](size_t bytes) {
    size_t o = cur;
    cur += (bytes + 255) & ~(size_t)255;
    return o;
  };
  // weight transposes
  size_t wtOff[14];
  for (int i = 1; i <= 13; ++i)
    wtOff[i] = alloc((size_t)CH[i] * CH[i - 1] * 9 * 4);
  float* wT[14];
  for (int i = 1; i <= 13; ++i) wT[i] = (float*)(ws + wtOff[i]);
  // features.  A1..A3 (dead by L9) are reused as Praw2 for L9/L10 K-split
  // partials: need 2*NMAX64*512*4 = 33.6MB; A1+A2+P2+A3 span 38.8MB.
  float* F0  = (float*)(ws + alloc((size_t)NMAX512 * 1 * 4));
  size_t a1Off = alloc((size_t)NMAX512 * 64 * 4);
  float* A1  = (float*)(ws + a1Off);
  float* Praw2 = A1;  // aliased K-split partial buffer (L9/L10)
  float* A2  = (float*)(ws + alloc((size_t)NMAX512 * 64 * 4));
  float* P2  = (float*)(ws + alloc((size_t)NMAX256 * 64 * 4));
  float* A3  = (float*)(ws + alloc((size_t)NMAX256 * 128 * 4));
  float* A4  = (float*)(ws + alloc((size_t)NMAX256 * 128 * 4));
  float* P4  = (float*)(ws + alloc((size_t)NMAX128 * 128 * 4));
  float* A5  = (float*)(ws + alloc((size_t)NMAX128 * 256 * 4));
  float* A6  = (float*)(ws + alloc((size_t)NMAX128 * 256 * 4));
  float* P7  = (float*)(ws + alloc((size_t)NMAX64 * 256 * 4));
  float* A8  = (float*)(ws + alloc((size_t)NMAX64 * 512 * 4));
  float* A9  = (float*)(ws + alloc((size_t)NMAX64 * 512 * 4));  // also Praw for L11-13
  float* P10 = (float*)(ws + alloc((size_t)NMAX32 * 512 * 4));
  float* A11 = (float*)(ws + alloc((size_t)NMAX32 * 512 * 4));
  float* A12 = (float*)(ws + alloc((size_t)NMAX32 * 512 * 4));
  float* D13 = (float*)(ws + alloc((size_t)NB * 512 * 16 * 16 * 4));
  float* F1  = (float*)(ws + alloc(NB * 1024 * 4));
  float* F2  = (float*)(ws + alloc(NB * 512 * 4));
  float* F3  = (float*)(ws + alloc(NB * 256 * 4));
  // index maps / lists / neighbor tables / counters
  int* im512 = (int*)(ws + alloc((size_t)NB * 512 * 512 * 4));
  int* im256 = (int*)(ws + alloc((size_t)NB * 256 * 256 * 4));
  int* im128 = (int*)(ws + alloc((size_t)NB * 128 * 128 * 4));
  int* im64  = (int*)(ws + alloc((size_t)NB * 64 * 64 * 4));
  int* im32  = (int*)(ws + alloc((size_t)NB * 32 * 32 * 4));
  int* l512 = (int*)(ws + alloc((size_t)NMAX512 * 4));
  int* l256 = (int*)(ws + alloc((size_t)NMAX256 * 4));
  int* l128 = (int*)(ws + alloc((size_t)NMAX128 * 4));
  int* l64  = (int*)(ws + alloc((size_t)NMAX64 * 4));
  int* l32  = (int*)(ws + alloc((size_t)NMAX32 * 4));
  int* nb512 = (int*)(ws + alloc((size_t)9 * NMAX512 * 4));
  int* nb256 = (int*)(ws + alloc((size_t)9 * NMAX256 * 4));
  int* nb128 = (int*)(ws + alloc((size_t)9 * NMAX128 * 4));
  int* nb64  = (int*)(ws + alloc((size_t)9 * NMAX64 * 4));
  int* nb32  = (int*)(ws + alloc((size_t)9 * NMAX32 * 4));
  int* nact = (int*)(ws + alloc(256));  // [0..4] per-resolution counts

  const dim3 blk(256);
  const dim3 blk128(128);
  hipMemsetAsync(nact, 0, 32, stream);

  // ---- lists / index maps / neighbors
  hipLaunchKernelGGL(build_l0_k, dim3(2048), blk, 0, stream, x, l512, im512, F0, nact + 0, NB * 512 * 512, NMAX512);
  hipLaunchKernelGGL(build_pl_k, dim3(512), blk, 0, stream, im512, l256, im256, nact + 1, 256, NMAX256);
  hipLaunchKernelGGL(build_pl_k, dim3(128), blk, 0, stream, im256, l128, im128, nact + 2, 128, NMAX128);
  hipLaunchKernelGGL(build_pl_k, dim3(32), blk, 0, stream, im128, l64, im64, nact + 3, 64, NMAX64);
  hipLaunchKernelGGL(build_pl_k, dim3(8), blk, 0, stream, im64, l32, im32, nact + 4, 32, NMAX32);
  hipLaunchKernelGGL(build_nbr_k, dim3(NMAX512 / 256), blk, 0, stream, l512, im512, nact + 0, nb512, 512, NMAX512);
  hipLaunchKernelGGL(build_nbr_k, dim3(NMAX256 / 256), blk, 0, stream, l256, im256, nact + 1, nb256, 256, NMAX256);
  hipLaunchKernelGGL(build_nbr_k, dim3(NMAX128 / 256), blk, 0, stream, l128, im128, nact + 2, nb128, 128, NMAX128);
  hipLaunchKernelGGL(build_nbr_k, dim3(NMAX64 / 256), blk, 0, stream, l64, im64, nact + 3, nb64, 64, NMAX64);
  hipLaunchKernelGGL(build_nbr_k, dim3(NMAX32 / 256), blk, 0, stream, l32, im32, nact + 4, nb32, 32, NMAX32);

  // ---- weight transposes: w[Cout][Cin*9] -> wT[Cin*9][Cout]
  for (int i = 1; i <= 13; ++i) {
    int R = CH[i], C = CH[i - 1] * 9;
    hipLaunchKernelGGL(transpose_k, dim3((C + 31) / 32, (R + 31) / 32), blk, 0,
                       stream, Wc[i], wT[i], R, C);
  }

  // ---- convs
  // L1: 1->64 @512
  hipLaunchKernelGGL((gconv_k<1, 64, 64, 4, 4, false>), dim3(512, 1, 1), blk, 0, stream,
                     F0, A1, wT[1], Bc[1], nb512, nact + 0, 1, 64, NMAX512, 1, 1);
  // L2: 64->64 @512
  hipLaunchKernelGGL((gconv_k<8, 64, 64, 4, 4, false>), dim3(512, 1, 1), blk, 0, stream,
                     A1, A2, wT[2], Bc[2], nb512, nact + 0, 64, 64, NMAX512, 64, 1);
  hipLaunchKernelGGL(pool_c_k, dim3(NMAX256 * 16 / 256), blk, 0, stream, A2, P2, l256, im512, nact + 1, 512, 64);
  // L3: 64->128 @256
  hipLaunchKernelGGL((gconv_k<8, 64, 128, 4, 8, false>), dim3(448, 1, 1), blk, 0, stream,
                     P2, A3, wT[3], Bc[3], nb256, nact + 1, 64, 128, NMAX256, 64, 1);
  // L4: 128->128 @256
  hipLaunchKernelGGL((gconv_k<8, 64, 128, 4, 8, false>), dim3(448, 1, 1), blk, 0, stream,
                     A3, A4, wT[4], Bc[4], nb256, nact + 1, 128, 128, NMAX256, 128, 1);
  hipLaunchKernelGGL(pool_c_k, dim3(NMAX128 * 32 / 256), blk, 0, stream, A4, P4, l128, im256, nact + 2, 256, 128);

  // L5-L10: 128-thread 8x8 kernel (SITES=64, OCB=128, CC=4)
  // L5: 128->256 @128  grid = (NMAX128/64)*2 = 640
  hipLaunchKernelGGL((gconv8_k<4, false>), dim3(640, 1, 1), blk128, 0, stream,
                     P4, A5, wT[5], Bc[5], nb128, nact + 2, 128, 256, NMAX128, 128, 2);
  // L6: 256->256 @128
  hipLaunchKernelGGL((gconv8_k<4, false>), dim3(640, 1, 1), blk128, 0, stream,
                     A5, A6, wT[6], Bc[6], nb128, nact + 2, 256, 256, NMAX128, 256, 2);
  // L7: 256->256 @128
  hipLaunchKernelGGL((gconv8_k<4, false>), dim3(640, 1, 1), blk128, 0, stream,
                     A6, A5, wT[7], Bc[7], nb128, nact + 2, 256, 256, NMAX128, 256, 2);
  hipLaunchKernelGGL(pool_c_k, dim3(NMAX64 * 64 / 256), blk, 0, stream, A5, P7, l64, im128, nact + 3, 128, 256);
  // L8: 256->512 @64  grid = (NMAX64/64)*4 = 512
  hipLaunchKernelGGL((gconv8_k<4, false>), dim3(512, 1, 1), blk128, 0, stream,
                     P7, A8, wT[8], Bc[8], nb64, nact + 3, 256, 512, NMAX64, 256, 4);
  // L9: 512->512 @64, K-split 2 (compact partials in Praw2, write-once)
  hipLaunchKernelGGL((gconv8_k<4, true>), dim3(512, 1, 2), blk128, 0, stream,
                     A8, Praw2, wT[9], nullptr, nb64, nact + 3, 512, 512, NMAX64, 256, 4);
  hipLaunchKernelGGL(combine_k, dim3(NMAX64 * 128 / 256), blk, 0, stream, Praw2, A9, Bc[9], nact + 3, 512, 2, NMAX64 * 512);
  // L10: 512->512 @64, K-split 2
  hipLaunchKernelGGL((gconv8_k<4, true>), dim3(512, 1, 2), blk128, 0, stream,
                     A9, Praw2, wT[10], nullptr, nb64, nact + 3, 512, 512, NMAX64, 256, 4);
  hipLaunchKernelGGL(combine_k, dim3(NMAX64 * 128 / 256), blk, 0, stream, Praw2, A8, Bc[10], nact + 3, 512, 2, NMAX64 * 512);
  hipLaunchKernelGGL(pool_c_k, dim3(NMAX32 * 128 / 256), blk, 0, stream, A8, P10, l32, im64, nact + 4, 64, 512);

  // L11-13: 512->512 @32, round-3 structure (RAW split-4 into A9 + combine)
  const int SLICE = NMAX32 * 512;
  hipLaunchKernelGGL((gconv_k<8, 64, 128, 4, 8, true>), dim3(32 * 4, 1, 4), blk, 0, stream,
                     P10, A9, wT[11], nullptr, nb32, nact + 4, 512, 512, NMAX32, 128, 4);
  hipLaunchKernelGGL(combine_k, dim3(NMAX32 * 128 / 256), blk, 0, stream, A9, A11, Bc[11], nact + 4, 512, 4, SLICE);
  hipLaunchKernelGGL((gconv_k<8, 64, 128, 4, 8, true>), dim3(32 * 4, 1, 4), blk, 0, stream,
                     A11, A9, wT[12], nullptr, nb32, nact + 4, 512, 512, NMAX32, 128, 4);
  hipLaunchKernelGGL(combine_k, dim3(NMAX32 * 128 / 256), blk, 0, stream, A9, A12, Bc[12], nact + 4, 512, 4, SLICE);
  hipLaunchKernelGGL((gconv_k<8, 64, 128, 4, 8, true>), dim3(32 * 4, 1, 4), blk, 0, stream,
                     A12, A9, wT[13], nullptr, nb32, nact + 4, 512, 512, NMAX32, 128, 4);
  hipLaunchKernelGGL(combine_k, dim3(NMAX32 * 128 / 256), blk, 0, stream, A9, A11, Bc[13], nact + 4, 512, 4, SLICE);
  // final pool -> dense
  hipLaunchKernelGGL(pool_d_k, dim3(256), blk, 0, stream, A11, D13, im32);

  // ---- MLP
  hipLaunchKernelGGL((fc_k<true>), dim3(1024), blk, 0, stream, D13, fw1, fb1, F1, 131072, 1024);
  hipLaunchKernelGGL((fc_k<true>), dim3(512), blk, 0, stream, F1, fw2, fb2, F2, 1024, 512);
  hipLaunchKernelGGL((fc_k<true>), dim3(256), blk, 0, stream, F2, fw3, fb3, F3, 512, 256);
  hipLaunchKernelGGL((fc_k<false>), dim3(2), blk, 0, stream, F3, fw4, fb4, (float*)d_out, 256, 2);
}

// Round 7
// 5040.461 us; speedup vs baseline: 1.3734x; 1.3734x over previous
//
#include <hip/hip_runtime.h>
#include <cstddef>
#include <cstdint>

#define NB 2

// Nmax per resolution (upper bounds on active sites, both batches)
#define NMAX512 32768
#define NMAX256 28672
#define NMAX128 20480
#define NMAX64  8192
#define NMAX32  2048

// ------------------------------------------------------------------ list build (res 512 from x, Cin=1)
__global__ __launch_bounds__(256) void build_l0_k(const float* __restrict__ x,
    int* __restrict__ list, int* __restrict__ im, float* __restrict__ f0,
    int* __restrict__ nact, int total, int nmax) {
  int i = blockIdx.x * 256 + threadIdx.x;
  bool act = false;
  float v = 0.f;
  if (i < total) { v = x[i]; act = (v != 0.f); }
  unsigned long long mb = __ballot(act);
  int lane = threadIdx.x & 63;
  int prefix = __popcll(mb & ((1ull << lane) - 1));
  int base = 0;
  if (lane == 0) base = atomicAdd(nact, __popcll(mb));
  base = __shfl(base, 0);
  if (i < total) {
    int idx = act ? (base + prefix) : -1;
    if (idx >= nmax) idx = -1;
    im[i] = idx;
    if (idx >= 0) {
      int b = i >> 18;            // 512*512 = 2^18
      int rem = i & 262143;
      list[idx] = (b << 20) | ((rem >> 9) << 10) | (rem & 511);
      f0[idx] = v;
    }
  }
}

// ------------------------------------------------------------------ pooled list from finer idxmap
__global__ __launch_bounds__(256) void build_pl_k(const int* __restrict__ imF,
    int* __restrict__ list, int* __restrict__ im, int* __restrict__ nact,
    int Hc, int nmax) {
  int total = NB * Hc * Hc;
  int i = blockIdx.x * 256 + threadIdx.x;
  bool act = false;
  int b = 0, y = 0, x = 0;
  int Hf = Hc * 2;
  if (i < total) {
    x = i % Hc; y = (i / Hc) % Hc; b = i / (Hc * Hc);
    const int* p = imF + ((size_t)b * Hf + 2 * y) * Hf + 2 * x;
    act = (p[0] >= 0) || (p[1] >= 0) || (p[Hf] >= 0) || (p[Hf + 1] >= 0);
  }
  unsigned long long mb = __ballot(act);
  int lane = threadIdx.x & 63;
  int prefix = __popcll(mb & ((1ull << lane) - 1));
  int base = 0;
  if (lane == 0) base = atomicAdd(nact, __popcll(mb));
  base = __shfl(base, 0);
  if (i < total) {
    int idx = act ? (base + prefix) : -1;
    if (idx >= nmax) idx = -1;
    im[i] = idx;
    if (idx >= 0) list[idx] = (b << 20) | (y << 10) | x;
  }
}

// ------------------------------------------------------------------ 9-neighbor index table
__global__ __launch_bounds__(256) void build_nbr_k(const int* __restrict__ list,
    const int* __restrict__ im, const int* __restrict__ nactp,
    int* __restrict__ nbr, int H, int nmax) {
  int i = blockIdx.x * 256 + threadIdx.x;
  if (i >= nactp[0]) return;
  int code = list[i];
  int b = code >> 20, y = (code >> 10) & 1023, x = code & 1023;
#pragma unroll
  for (int k = 0; k < 9; ++k) {
    int yy = y + k / 3 - 1, xx = x + k % 3 - 1;
    int v = -1;
    if (yy >= 0 && yy < H && xx >= 0 && xx < H)
      v = im[((size_t)b * H + yy) * H + xx];
    nbr[k * nmax + i] = v;
  }
}

// ------------------------------------------------------------------ weight transpose  [R][C] -> [C][R]
__global__ __launch_bounds__(256) void transpose_k(const float* __restrict__ in,
                                                   float* __restrict__ out,
                                                   int R, int C) {
  __shared__ float tile[32][33];
  int bx = blockIdx.x * 32;  // col base (C dim)
  int by = blockIdx.y * 32;  // row base (R dim)
  int tx = threadIdx.x % 32, ty0 = threadIdx.x / 32;
  for (int ty = ty0; ty < 32; ty += 8) {
    int r = by + ty, c = bx + tx;
    tile[ty][tx] = (r < R && c < C) ? in[(size_t)r * C + c] : 0.f;
  }
  __syncthreads();
  for (int ty = ty0; ty < 32; ty += 8) {
    int r = bx + ty, c = by + tx;
    if (r < C && c < R) out[(size_t)r * R + c] = tile[tx][ty];
  }
}

// ------------------------------------------------------------------ gather-GEMM submanifold conv (256 thr; L1-L4)
template <int CC, int SITES, int OCB, int SPT, int OPT, bool RAW>
__global__ __launch_bounds__(256, 2) void gconv_k(
    const float* __restrict__ in, float* __restrict__ out,
    const float* __restrict__ wT, const float* __restrict__ bias,
    const int* __restrict__ nbr, const int* __restrict__ nactp,
    int Cin, int Cout, int Nmax, int cinCnt, int nocb) {
  constexpr int KSL = CC * 9;
  __shared__ int s_nbr[9][SITES];
  __shared__ float s_a[KSL][SITES];
  __shared__ float s_w[KSL][OCB];
  const int n = nactp[0];
  const int gid = blockIdx.x;
  const int xcd = gid & 7;
  const int pos = gid >> 3;
  const int ocbI = pos % nocb;
  const int sb = (pos / nocb) * 8 + xcd;
  const int base = sb * SITES;
  if (base >= n) return;
  const int ocb = ocbI * OCB;
  const int t = threadIdx.x;
  for (int s = t; s < 9 * SITES; s += 256) {
    int i = s % SITES, k = s / SITES;
    int gi = base + i;
    s_nbr[k][i] = (gi < n) ? nbr[k * Nmax + gi] : -1;
  }
  constexpr int OCG = OCB / OPT;
  const int oc0 = (t % OCG) * 4;           // 4-float chunk base
  const int si0 = (t / OCG) * SPT;
  float acc[SPT][OPT];
#pragma unroll
  for (int a = 0; a < SPT; ++a)
#pragma unroll
    for (int j = 0; j < OPT; ++j) acc[a][j] = 0.f;
  __syncthreads();
  const int cinStart = RAW ? (blockIdx.z * cinCnt) : 0;
  const int nch = cinCnt / CC;
  for (int ch = 0; ch < nch; ++ch) {
    const int c0 = cinStart + ch * CC;
    const float* wrow = wT + ((size_t)c0 * 9) * Cout + ocb;
    for (int s = t; s < KSL * (OCB / 4); s += 256) {
      int j4 = s % (OCB / 4), r = s / (OCB / 4);
      *(float4*)&s_w[r][j4 * 4] = *(const float4*)(wrow + (size_t)r * Cout + j4 * 4);
    }
    if constexpr (CC == 1) {
      for (int s = t; s < 9 * SITES; s += 256) {
        int i = s % SITES, k = s / SITES;
        int row = s_nbr[k][i];
        s_a[k][i] = (row >= 0) ? in[row] : 0.f;
      }
    } else {
      constexpr int H4 = CC / 4;
      for (int s = t; s < H4 * 9 * SITES; s += 256) {
        int i = s % SITES, m = s / SITES;
        int c4 = m % H4, k = m / H4;
        int row = s_nbr[k][i];
        float4 v = make_float4(0.f, 0.f, 0.f, 0.f);
        if (row >= 0)
          v = *(const float4*)(in + (size_t)row * Cin + c0 + c4 * 4);
        s_a[(c4 * 4 + 0) * 9 + k][i] = v.x;
        s_a[(c4 * 4 + 1) * 9 + k][i] = v.y;
        s_a[(c4 * 4 + 2) * 9 + k][i] = v.z;
        s_a[(c4 * 4 + 3) * 9 + k][i] = v.w;
      }
    }
    __syncthreads();
#pragma unroll
    for (int kk = 0; kk < KSL; ++kk) {
      float av[SPT];
      if constexpr (SPT == 4) {
        float4 a4 = *(const float4*)&s_a[kk][si0];
        av[0] = a4.x; av[1] = a4.y; av[2] = a4.z; av[3] = a4.w;
      } else {
        float2 a2 = *(const float2*)&s_a[kk][si0];
        av[0] = a2.x; av[1] = a2.y;
      }
      float wv[OPT];
      if constexpr (OPT == 8) {
        float4 w4a = *(const float4*)&s_w[kk][oc0];
        float4 w4b = *(const float4*)&s_w[kk][OCB / 2 + oc0];
        wv[0] = w4a.x; wv[1] = w4a.y; wv[2] = w4a.z; wv[3] = w4a.w;
        wv[4] = w4b.x; wv[5] = w4b.y; wv[6] = w4b.z; wv[7] = w4b.w;
      } else {
        float4 w4 = *(const float4*)&s_w[kk][oc0];
        wv[0] = w4.x; wv[1] = w4.y; wv[2] = w4.z; wv[3] = w4.w;
      }
#pragma unroll
      for (int a = 0; a < SPT; ++a)
#pragma unroll
        for (int j = 0; j < OPT; ++j)
          acc[a][j] = fmaf(av[a], wv[j], acc[a][j]);
    }
    __syncthreads();
  }
  float bz[OPT];
  if constexpr (!RAW) {
#pragma unroll
    for (int j = 0; j < OPT; ++j) {
      int oj = (OPT == 8) ? ((j < 4) ? (oc0 + j) : (OCB / 2 + oc0 + j - 4))
                          : (oc0 + j);
      bz[j] = bias[ocb + oj];
    }
  }
  float* ob = out;
  if constexpr (RAW) ob += (size_t)blockIdx.z * Nmax * Cout;
#pragma unroll
  for (int a = 0; a < SPT; ++a) {
    int gi = base + si0 + a;
    if (gi < n) {
      float* po = ob + (size_t)gi * Cout + ocb;
      if constexpr (OPT == 8) {
        float4 v0, v1;
        if constexpr (RAW) {
          v0 = make_float4(acc[a][0], acc[a][1], acc[a][2], acc[a][3]);
          v1 = make_float4(acc[a][4], acc[a][5], acc[a][6], acc[a][7]);
        } else {
          v0.x = fmaxf(acc[a][0] + bz[0], 0.f); v0.y = fmaxf(acc[a][1] + bz[1], 0.f);
          v0.z = fmaxf(acc[a][2] + bz[2], 0.f); v0.w = fmaxf(acc[a][3] + bz[3], 0.f);
          v1.x = fmaxf(acc[a][4] + bz[4], 0.f); v1.y = fmaxf(acc[a][5] + bz[5], 0.f);
          v1.z = fmaxf(acc[a][6] + bz[6], 0.f); v1.w = fmaxf(acc[a][7] + bz[7], 0.f);
        }
        *(float4*)(po + oc0) = v0;
        *(float4*)(po + OCB / 2 + oc0) = v1;
      } else {
        float4 v;
        if constexpr (RAW) {
          v = make_float4(acc[a][0], acc[a][1], acc[a][2], acc[a][3]);
        } else {
          v.x = fmaxf(acc[a][0] + bz[0], 0.f); v.y = fmaxf(acc[a][1] + bz[1], 0.f);
          v.z = fmaxf(acc[a][2] + bz[2], 0.f); v.w = fmaxf(acc[a][3] + bz[3], 0.f);
        }
        *(float4*)(po + oc0) = v;
      }
    }
  }
}

// ------------------------------------------------------------------ 128-thread 8x8 gather-GEMM (L5-L13)
// SITES=64 x OCB=128, thread tile 8 sites x 8 oc (split-oc), 2 waves/block.
// LDS 29.9KB. Per kk: 4 ds_read_b128 per 64 FMA -> LDS:VALU = 1.5.
// LESSON (r4/r6): a min-occupancy launch_bounds arg here caps VGPR at 84 and
// spills the 64-reg accumulator to scratch (GB-scale TCC traffic, 2.4x slow).
// Plain __launch_bounds__(128): compiler picks ~110-130 VGPR, no spill.
template <int CC, bool RAW>
__global__ __launch_bounds__(128) void gconv8_k(
    const float* __restrict__ in, float* __restrict__ out,
    const float* __restrict__ wT, const float* __restrict__ bias,
    const int* __restrict__ nbr, const int* __restrict__ nactp,
    int Cin, int Cout, int Nmax, int cinCnt, int nocb) {
  constexpr int KSL = CC * 9;
  constexpr int SITES = 64, OCB = 128;
  __shared__ int s_nbr[9][SITES];
  __shared__ float s_a[KSL][SITES];
  __shared__ float s_w[KSL][OCB];
  const int n = nactp[0];
  const int gid = blockIdx.x;
  const int xcd = gid & 7;
  const int pos = gid >> 3;
  const int ocbI = pos % nocb;
  const int sb = (pos / nocb) * 8 + xcd;
  const int base = sb * SITES;
  if (base >= n) return;
  const int ocb = ocbI * OCB;
  const int t = threadIdx.x;
  for (int s = t; s < 9 * SITES; s += 128) {
    int i = s & 63, k = s >> 6;
    int gi = base + i;
    s_nbr[k][i] = (gi < n) ? nbr[k * Nmax + gi] : -1;
  }
  const int oc0 = (t & 15) * 4;   // 16 oc-groups
  const int si0 = (t >> 4) * 8;   // 8 site-groups
  float acc[8][8];
#pragma unroll
  for (int a = 0; a < 8; ++a)
#pragma unroll
    for (int j = 0; j < 8; ++j) acc[a][j] = 0.f;
  __syncthreads();
  const int cinStart = RAW ? (blockIdx.z * cinCnt) : 0;
  const int nch = cinCnt / CC;
  for (int ch = 0; ch < nch; ++ch) {
    const int c0 = cinStart + ch * CC;
    const float* wrow = wT + ((size_t)c0 * 9) * Cout + ocb;
    for (int s = t; s < KSL * (OCB / 4); s += 128) {
      int j4 = s & 31, r = s >> 5;  // OCB/4 = 32
      *(float4*)&s_w[r][j4 * 4] = *(const float4*)(wrow + (size_t)r * Cout + j4 * 4);
    }
    constexpr int H4 = CC / 4;
    for (int s = t; s < H4 * 9 * SITES; s += 128) {
      int i = s & 63, m = s >> 6;
      int c4 = m % H4, k = m / H4;
      int row = s_nbr[k][i];
      float4 v = make_float4(0.f, 0.f, 0.f, 0.f);
      if (row >= 0)
        v = *(const float4*)(in + (size_t)row * Cin + c0 + c4 * 4);
      s_a[(c4 * 4 + 0) * 9 + k][i] = v.x;
      s_a[(c4 * 4 + 1) * 9 + k][i] = v.y;
      s_a[(c4 * 4 + 2) * 9 + k][i] = v.z;
      s_a[(c4 * 4 + 3) * 9 + k][i] = v.w;
    }
    __syncthreads();
#pragma unroll
    for (int kk = 0; kk < KSL; ++kk) {
      float4 a0 = *(const float4*)&s_a[kk][si0];
      float4 a1 = *(const float4*)&s_a[kk][si0 + 4];
      float4 w4a = *(const float4*)&s_w[kk][oc0];
      float4 w4b = *(const float4*)&s_w[kk][64 + oc0];
      float av[8] = {a0.x, a0.y, a0.z, a0.w, a1.x, a1.y, a1.z, a1.w};
      float wv[8] = {w4a.x, w4a.y, w4a.z, w4a.w, w4b.x, w4b.y, w4b.z, w4b.w};
#pragma unroll
      for (int a = 0; a < 8; ++a)
#pragma unroll
        for (int j = 0; j < 8; ++j)
          acc[a][j] = fmaf(av[a], wv[j], acc[a][j]);
    }
    __syncthreads();
  }
  float bz[8];
  if constexpr (!RAW) {
#pragma unroll
    for (int j = 0; j < 8; ++j) {
      int oj = (j < 4) ? (oc0 + j) : (64 + oc0 + j - 4);
      bz[j] = bias[ocb + oj];
    }
  }
  float* ob = out;
  if constexpr (RAW) ob += (size_t)blockIdx.z * Nmax * Cout;
#pragma unroll
  for (int a = 0; a < 8; ++a) {
    int gi = base + si0 + a;
    if (gi < n) {
      float* po = ob + (size_t)gi * Cout + ocb;
      float4 v0, v1;
      if constexpr (RAW) {
        v0 = make_float4(acc[a][0], acc[a][1], acc[a][2], acc[a][3]);
        v1 = make_float4(acc[a][4], acc[a][5], acc[a][6], acc[a][7]);
      } else {
        v0.x = fmaxf(acc[a][0] + bz[0], 0.f); v0.y = fmaxf(acc[a][1] + bz[1], 0.f);
        v0.z = fmaxf(acc[a][2] + bz[2], 0.f); v0.w = fmaxf(acc[a][3] + bz[3], 0.f);
        v1.x = fmaxf(acc[a][4] + bz[4], 0.f); v1.y = fmaxf(acc[a][5] + bz[5], 0.f);
        v1.z = fmaxf(acc[a][6] + bz[6], 0.f); v1.w = fmaxf(acc[a][7] + bz[7], 0.f);
      }
      *(float4*)(po + oc0) = v0;
      *(float4*)(po + 64 + oc0) = v1;
    }
  }
}

// ------------------------------------------------------------------ K-split combine (+bias+relu)
__global__ __launch_bounds__(256) void combine_k(const float* __restrict__ P,
    float* __restrict__ out, const float* __restrict__ bias,
    const int* __restrict__ nactp, int C, int S, int sliceStride) {
  int tg = blockIdx.x * 256 + threadIdx.x;
  int cg = C >> 2;
  int j = tg / cg, c4 = tg % cg;
  if (j >= nactp[0]) return;
  size_t o = (size_t)j * C + c4 * 4;
  float4 v = *(const float4*)(bias + c4 * 4);
  for (int s = 0; s < S; ++s) {
    float4 u = *(const float4*)(P + (size_t)s * sliceStride + o);
    v.x += u.x; v.y += u.y; v.z += u.z; v.w += u.w;
  }
  v.x = fmaxf(v.x, 0.f); v.y = fmaxf(v.y, 0.f);
  v.z = fmaxf(v.z, 0.f); v.w = fmaxf(v.w, 0.f);
  *(float4*)(out + o) = v;
}

// ------------------------------------------------------------------ compact 2x2 maxpool
__global__ __launch_bounds__(256) void pool_c_k(const float* __restrict__ inF,
    float* __restrict__ outF, const int* __restrict__ listC,
    const int* __restrict__ imF, const int* __restrict__ nactp, int Hf, int C) {
  int tg = blockIdx.x * 256 + threadIdx.x;
  int cg = C >> 2;
  int j = tg / cg, c4 = tg % cg;
  if (j >= nactp[0]) return;
  int code = listC[j];
  int b = code >> 20, Y = (code >> 10) & 1023, X = code & 1023;
  float4 v = make_float4(0.f, 0.f, 0.f, 0.f);
#pragma unroll
  for (int dy = 0; dy < 2; ++dy)
#pragma unroll
    for (int dx = 0; dx < 2; ++dx) {
      int ci = imF[((size_t)b * Hf + 2 * Y + dy) * Hf + 2 * X + dx];
      if (ci >= 0) {
        float4 u = *(const float4*)(inF + (size_t)ci * C + c4 * 4);
        v.x = fmaxf(v.x, u.x); v.y = fmaxf(v.y, u.y);
        v.z = fmaxf(v.z, u.z); v.w = fmaxf(v.w, u.w);
      }
    }
  *(float4*)(outF + (size_t)j * C + c4 * 4) = v;
}

// ------------------------------------------------------------------ final pool -> dense [2,512,16,16]
__global__ __launch_bounds__(256) void pool_d_k(const float* __restrict__ inF,
    float* __restrict__ outD, const int* __restrict__ im32) {
  int tg = blockIdx.x * 256 + threadIdx.x;  // 2*16*16*128 = 65536
  int c4 = tg & 127;
  int rest = tg >> 7;
  int X = rest & 15, Y = (rest >> 4) & 15, b = rest >> 8;
  float4 v = make_float4(0.f, 0.f, 0.f, 0.f);
#pragma unroll
  for (int dy = 0; dy < 2; ++dy)
#pragma unroll
    for (int dx = 0; dx < 2; ++dx) {
      int ci = im32[((size_t)b * 32 + 2 * Y + dy) * 32 + 2 * X + dx];
      if (ci >= 0) {
        float4 u = *(const float4*)(inF + (size_t)ci * 512 + c4 * 4);
        v.x = fmaxf(v.x, u.x); v.y = fmaxf(v.y, u.y);
        v.z = fmaxf(v.z, u.z); v.w = fmaxf(v.w, u.w);
      }
    }
  const float* pv = &v.x;
#pragma unroll
  for (int u = 0; u < 4; ++u) {
    int c = c4 * 4 + u;
    outD[(((size_t)b * 512 + c) * 16 + Y) * 16 + X] = pv[u];
  }
}

// ------------------------------------------------------------------ fully connected
template <bool RELU>
__global__ __launch_bounds__(256) void fc_k(const float* __restrict__ in,
                                            const float* __restrict__ w,
                                            const float* __restrict__ bias,
                                            float* __restrict__ out, int K,
                                            int R) {
  const int r = blockIdx.x;
  const int t = threadIdx.x;
  const float* wr = w + (size_t)r * K;
  float a0 = 0.f, a1 = 0.f;
  for (int k = t * 4; k < K; k += 1024) {
    float4 wv = *(const float4*)(wr + k);
    float4 x0 = *(const float4*)(in + k);
    float4 x1 = *(const float4*)(in + K + k);
    a0 += wv.x * x0.x + wv.y * x0.y + wv.z * x0.z + wv.w * x0.w;
    a1 += wv.x * x1.x + wv.y * x1.y + wv.z * x1.z + wv.w * x1.w;
  }
#pragma unroll
  for (int off = 32; off > 0; off >>= 1) {
    a0 += __shfl_down(a0, off);
    a1 += __shfl_down(a1, off);
  }
  __shared__ float s0[4], s1[4];
  const int lane = t & 63, wid = t >> 6;
  if (lane == 0) { s0[wid] = a0; s1[wid] = a1; }
  __syncthreads();
  if (t == 0) {
    float v0 = s0[0] + s0[1] + s0[2] + s0[3] + bias[r];
    float v1 = s1[0] + s1[1] + s1[2] + s1[3] + bias[r];
    if (RELU) { v0 = fmaxf(v0, 0.f); v1 = fmaxf(v1, 0.f); }
    out[r] = v0;
    out[R + r] = v1;
  }
}

// ------------------------------------------------------------------ launch
extern "C" void kernel_launch(void* const* d_in, const int* in_sizes, int n_in,
                              void* d_out, int out_size, void* d_ws,
                              size_t ws_size, hipStream_t stream) {
  (void)in_sizes; (void)n_in; (void)out_size; (void)ws_size;
  const float* x = (const float*)d_in[0];
  const float* Wc[14];
  const float* Bc[14];
  for (int i = 1; i <= 13; ++i) {
    Wc[i] = (const float*)d_in[2 * i - 1];
    Bc[i] = (const float*)d_in[2 * i];
  }
  const float* fw1 = (const float*)d_in[27];
  const float* fb1 = (const float*)d_in[28];
  const float* fw2 = (const float*)d_in[29];
  const float* fb2 = (const float*)d_in[30];
  const float* fw3 = (const float*)d_in[31];
  const float* fb3 = (const float*)d_in[32];
  const float* fw4 = (const float*)d_in[33];
  const float* fb4 = (const float*)d_in[34];

  static const int CH[14] = {1, 64, 64, 128, 128, 256, 256, 256,
                             512, 512, 512, 512, 512, 512};

  char* ws = (char*)d_ws;
  size_t cur = 0;
  auto alloc = [&](size_t bytes) {
    size_t o = cur;
    cur += (bytes + 255) & ~(size_t)255;
    return o;
  };
  // weight transposes
  size_t wtOff[14];
  for (int i = 1; i <= 13; ++i)
    wtOff[i] = alloc((size_t)CH[i] * CH[i - 1] * 9 * 4);
  float* wT[14];
  for (int i = 1; i <= 13; ++i) wT[i] = (float*)(ws + wtOff[i]);
  // features.  A1..A4 (contiguous, 53.5MB, all dead by L5) are reused as Praw
  // for L5-L10 K-split partials (max need: L5-L7 = 2*NMAX128*256*4 = 41.9MB,
  // L8-L10 = 2*NMAX64*512*4 = 33.6MB).  L11-13 partials go in A9 (16.8MB,
  // dead after L10 combine).
  float* F0  = (float*)(ws + alloc((size_t)NMAX512 * 1 * 4));
  size_t a1Off = alloc((size_t)NMAX512 * 64 * 4);
  float* A1  = (float*)(ws + a1Off);
  float* Praw = A1;  // aliased K-split partial buffer (L5-L10)
  float* A2  = (float*)(ws + alloc((size_t)NMAX512 * 64 * 4));
  float* P2  = (float*)(ws + alloc((size_t)NMAX256 * 64 * 4));
  float* A3  = (float*)(ws + alloc((size_t)NMAX256 * 128 * 4));
  float* A4  = (float*)(ws + alloc((size_t)NMAX256 * 128 * 4));
  float* P4  = (float*)(ws + alloc((size_t)NMAX128 * 128 * 4));
  float* A5  = (float*)(ws + alloc((size_t)NMAX128 * 256 * 4));
  float* A6  = (float*)(ws + alloc((size_t)NMAX128 * 256 * 4));
  float* P7  = (float*)(ws + alloc((size_t)NMAX64 * 256 * 4));
  float* A8  = (float*)(ws + alloc((size_t)NMAX64 * 512 * 4));
  float* A9  = (float*)(ws + alloc((size_t)NMAX64 * 512 * 4));  // also Praw for L11-13
  float* P10 = (float*)(ws + alloc((size_t)NMAX32 * 512 * 4));
  float* A11 = (float*)(ws + alloc((size_t)NMAX32 * 512 * 4));
  float* A12 = (float*)(ws + alloc((size_t)NMAX32 * 512 * 4));
  float* D13 = (float*)(ws + alloc((size_t)NB * 512 * 16 * 16 * 4));
  float* F1  = (float*)(ws + alloc(NB * 1024 * 4));
  float* F2  = (float*)(ws + alloc(NB * 512 * 4));
  float* F3  = (float*)(ws + alloc(NB * 256 * 4));
  // index maps / lists / neighbor tables / counters
  int* im512 = (int*)(ws + alloc((size_t)NB * 512 * 512 * 4));
  int* im256 = (int*)(ws + alloc((size_t)NB * 256 * 256 * 4));
  int* im128 = (int*)(ws + alloc((size_t)NB * 128 * 128 * 4));
  int* im64  = (int*)(ws + alloc((size_t)NB * 64 * 64 * 4));
  int* im32  = (int*)(ws + alloc((size_t)NB * 32 * 32 * 4));
  int* l512 = (int*)(ws + alloc((size_t)NMAX512 * 4));
  int* l256 = (int*)(ws + alloc((size_t)NMAX256 * 4));
  int* l128 = (int*)(ws + alloc((size_t)NMAX128 * 4));
  int* l64  = (int*)(ws + alloc((size_t)NMAX64 * 4));
  int* l32  = (int*)(ws + alloc((size_t)NMAX32 * 4));
  int* nb512 = (int*)(ws + alloc((size_t)9 * NMAX512 * 4));
  int* nb256 = (int*)(ws + alloc((size_t)9 * NMAX256 * 4));
  int* nb128 = (int*)(ws + alloc((size_t)9 * NMAX128 * 4));
  int* nb64  = (int*)(ws + alloc((size_t)9 * NMAX64 * 4));
  int* nb32  = (int*)(ws + alloc((size_t)9 * NMAX32 * 4));
  int* nact = (int*)(ws + alloc(256));  // [0..4] per-resolution counts

  const dim3 blk(256);
  const dim3 blk128(128);
  hipMemsetAsync(nact, 0, 32, stream);

  // ---- lists / index maps / neighbors
  hipLaunchKernelGGL(build_l0_k, dim3(2048), blk, 0, stream, x, l512, im512, F0, nact + 0, NB * 512 * 512, NMAX512);
  hipLaunchKernelGGL(build_pl_k, dim3(512), blk, 0, stream, im512, l256, im256, nact + 1, 256, NMAX256);
  hipLaunchKernelGGL(build_pl_k, dim3(128), blk, 0, stream, im256, l128, im128, nact + 2, 128, NMAX128);
  hipLaunchKernelGGL(build_pl_k, dim3(32), blk, 0, stream, im128, l64, im64, nact + 3, 64, NMAX64);
  hipLaunchKernelGGL(build_pl_k, dim3(8), blk, 0, stream, im64, l32, im32, nact + 4, 32, NMAX32);
  hipLaunchKernelGGL(build_nbr_k, dim3(NMAX512 / 256), blk, 0, stream, l512, im512, nact + 0, nb512, 512, NMAX512);
  hipLaunchKernelGGL(build_nbr_k, dim3(NMAX256 / 256), blk, 0, stream, l256, im256, nact + 1, nb256, 256, NMAX256);
  hipLaunchKernelGGL(build_nbr_k, dim3(NMAX128 / 256), blk, 0, stream, l128, im128, nact + 2, nb128, 128, NMAX128);
  hipLaunchKernelGGL(build_nbr_k, dim3(NMAX64 / 256), blk, 0, stream, l64, im64, nact + 3, nb64, 64, NMAX64);
  hipLaunchKernelGGL(build_nbr_k, dim3(NMAX32 / 256), blk, 0, stream, l32, im32, nact + 4, nb32, 32, NMAX32);

  // ---- weight transposes: w[Cout][Cin*9] -> wT[Cin*9][Cout]
  for (int i = 1; i <= 13; ++i) {
    int R = CH[i], C = CH[i - 1] * 9;
    hipLaunchKernelGGL(transpose_k, dim3((C + 31) / 32, (R + 31) / 32), blk, 0,
                       stream, Wc[i], wT[i], R, C);
  }

  // ---- convs
  // L1: 1->64 @512
  hipLaunchKernelGGL((gconv_k<1, 64, 64, 4, 4, false>), dim3(512, 1, 1), blk, 0, stream,
                     F0, A1, wT[1], Bc[1], nb512, nact + 0, 1, 64, NMAX512, 1, 1);
  // L2: 64->64 @512
  hipLaunchKernelGGL((gconv_k<8, 64, 64, 4, 4, false>), dim3(512, 1, 1), blk, 0, stream,
                     A1, A2, wT[2], Bc[2], nb512, nact + 0, 64, 64, NMAX512, 64, 1);
  hipLaunchKernelGGL(pool_c_k, dim3(NMAX256 * 16 / 256), blk, 0, stream, A2, P2, l256, im512, nact + 1, 512, 64);
  // L3: 64->128 @256
  hipLaunchKernelGGL((gconv_k<8, 64, 128, 4, 8, false>), dim3(448, 1, 1), blk, 0, stream,
                     P2, A3, wT[3], Bc[3], nb256, nact + 1, 64, 128, NMAX256, 64, 1);
  // L4: 128->128 @256
  hipLaunchKernelGGL((gconv_k<8, 64, 128, 4, 8, false>), dim3(448, 1, 1), blk, 0, stream,
                     A3, A4, wT[4], Bc[4], nb256, nact + 1, 128, 128, NMAX256, 128, 1);
  hipLaunchKernelGGL(pool_c_k, dim3(NMAX128 * 32 / 256), blk, 0, stream, A4, P4, l128, im256, nact + 2, 256, 128);

  // L5-L10: 128-thread 8x8 kernel, K-split x2 -> Praw (A1..A4 region) + combine
  const int SL128 = NMAX128 * 256;  // slice stride (floats) for L5-L7
  const int SL64  = NMAX64 * 512;   // slice stride for L8-L10
  // L5: 128->256 @128, cin split 64+64
  hipLaunchKernelGGL((gconv8_k<4, true>), dim3(640, 1, 2), blk128, 0, stream,
                     P4, Praw, wT[5], nullptr, nb128, nact + 2, 128, 256, NMAX128, 64, 2);
  hipLaunchKernelGGL(combine_k, dim3(NMAX128 * 64 / 256), blk, 0, stream, Praw, A5, Bc[5], nact + 2, 256, 2, SL128);
  // L6: 256->256 @128, split 128+128
  hipLaunchKernelGGL((gconv8_k<4, true>), dim3(640, 1, 2), blk128, 0, stream,
                     A5, Praw, wT[6], nullptr, nb128, nact + 2, 256, 256, NMAX128, 128, 2);
  hipLaunchKernelGGL(combine_k, dim3(NMAX128 * 64 / 256), blk, 0, stream, Praw, A6, Bc[6], nact + 2, 256, 2, SL128);
  // L7: 256->256 @128, split 128+128
  hipLaunchKernelGGL((gconv8_k<4, true>), dim3(640, 1, 2), blk128, 0, stream,
                     A6, Praw, wT[7], nullptr, nb128, nact + 2, 256, 256, NMAX128, 128, 2);
  hipLaunchKernelGGL(combine_k, dim3(NMAX128 * 64 / 256), blk, 0, stream, Praw, A5, Bc[7], nact + 2, 256, 2, SL128);
  hipLaunchKernelGGL(pool_c_k, dim3(NMAX64 * 64 / 256), blk, 0, stream, A5, P7, l64, im128, nact + 3, 128, 256);
  // L8: 256->512 @64, split 128+128
  hipLaunchKernelGGL((gconv8_k<4, true>), dim3(512, 1, 2), blk128, 0, stream,
                     P7, Praw, wT[8], nullptr, nb64, nact + 3, 256, 512, NMAX64, 128, 4);
  hipLaunchKernelGGL(combine_k, dim3(NMAX64 * 128 / 256), blk, 0, stream, Praw, A8, Bc[8], nact + 3, 512, 2, SL64);
  // L9: 512->512 @64, split 256+256
  hipLaunchKernelGGL((gconv8_k<4, true>), dim3(512, 1, 2), blk128, 0, stream,
                     A8, Praw, wT[9], nullptr, nb64, nact + 3, 512, 512, NMAX64, 256, 4);
  hipLaunchKernelGGL(combine_k, dim3(NMAX64 * 128 / 256), blk, 0, stream, Praw, A9, Bc[9], nact + 3, 512, 2, SL64);
  // L10: 512->512 @64, split 256+256
  hipLaunchKernelGGL((gconv8_k<4, true>), dim3(512, 1, 2), blk128, 0, stream,
                     A9, Praw, wT[10], nullptr, nb64, nact + 3, 512, 512, NMAX64, 256, 4);
  hipLaunchKernelGGL(combine_k, dim3(NMAX64 * 128 / 256), blk, 0, stream, Praw, A8, Bc[10], nact + 3, 512, 2, SL64);
  hipLaunchKernelGGL(pool_c_k, dim3(NMAX32 * 128 / 256), blk, 0, stream, A8, P10, l32, im64, nact + 4, 64, 512);

  // L11-13: 512->512 @32, gconv8 K-split x4 -> A9 + combine
  const int SL32 = NMAX32 * 512;
  hipLaunchKernelGGL((gconv8_k<4, true>), dim3(128, 1, 4), blk128, 0, stream,
                     P10, A9, wT[11], nullptr, nb32, nact + 4, 512, 512, NMAX32, 128, 4);
  hipLaunchKernelGGL(combine_k, dim3(NMAX32 * 128 / 256), blk, 0, stream, A9, A11, Bc[11], nact + 4, 512, 4, SL32);
  hipLaunchKernelGGL((gconv8_k<4, true>), dim3(128, 1, 4), blk128, 0, stream,
                     A11, A9, wT[12], nullptr, nb32, nact + 4, 512, 512, NMAX32, 128, 4);
  hipLaunchKernelGGL(combine_k, dim3(NMAX32 * 128 / 256), blk, 0, stream, A9, A12, Bc[12], nact + 4, 512, 4, SL32);
  hipLaunchKernelGGL((gconv8_k<4, true>), dim3(128, 1, 4), blk128, 0, stream,
                     A12, A9, wT[13], nullptr, nb32, nact + 4, 512, 512, NMAX32, 128, 4);
  hipLaunchKernelGGL(combine_k, dim3(NMAX32 * 128 / 256), blk, 0, stream, A9, A11, Bc[13], nact + 4, 512, 4, SL32);
  // final pool -> dense
  hipLaunchKernelGGL(pool_d_k, dim3(256), blk, 0, stream, A11, D13, im32);

  // ---- MLP
  hipLaunchKernelGGL((fc_k<true>), dim3(1024), blk, 0, stream, D13, fw1, fb1, F1, 131072, 1024);
  hipLaunchKernelGGL((fc_k<true>), dim3(512), blk, 0, stream, F1, fw2, fb2, F2, 1024, 512);
  hipLaunchKernelGGL((fc_k<true>), dim3(256), blk, 0, stream, F2, fw3, fb3, F3, 512, 256);
  hipLaunchKernelGGL((fc_k<false>), dim3(2), blk, 0, stream, F3, fw4, fb4, (float*)d_out, 256, 2);
}

// Round 8
// 4938.337 us; speedup vs baseline: 1.4018x; 1.0207x over previous
//
#include <hip/hip_runtime.h>
#include <cstddef>
#include <cstdint>

#define NB 2

// Nmax per resolution (upper bounds on active sites, both batches)
#define NMAX512 32768
#define NMAX256 28672
#define NMAX128 20480
#define NMAX64  8192
#define NMAX32  2048

// ------------------------------------------------------------------ list build (res 512 from x, Cin=1)
__global__ __launch_bounds__(256) void build_l0_k(const float* __restrict__ x,
    int* __restrict__ list, int* __restrict__ im, float* __restrict__ f0,
    int* __restrict__ nact, int total, int nmax) {
  int i = blockIdx.x * 256 + threadIdx.x;
  bool act = false;
  float v = 0.f;
  if (i < total) { v = x[i]; act = (v != 0.f); }
  unsigned long long mb = __ballot(act);
  int lane = threadIdx.x & 63;
  int prefix = __popcll(mb & ((1ull << lane) - 1));
  int base = 0;
  if (lane == 0) base = atomicAdd(nact, __popcll(mb));
  base = __shfl(base, 0);
  if (i < total) {
    int idx = act ? (base + prefix) : -1;
    if (idx >= nmax) idx = -1;
    im[i] = idx;
    if (idx >= 0) {
      int b = i >> 18;            // 512*512 = 2^18
      int rem = i & 262143;
      list[idx] = (b << 20) | ((rem >> 9) << 10) | (rem & 511);
      f0[idx] = v;
    }
  }
}

// ------------------------------------------------------------------ pooled list from finer idxmap
__global__ __launch_bounds__(256) void build_pl_k(const int* __restrict__ imF,
    int* __restrict__ list, int* __restrict__ im, int* __restrict__ nact,
    int Hc, int nmax) {
  int total = NB * Hc * Hc;
  int i = blockIdx.x * 256 + threadIdx.x;
  bool act = false;
  int b = 0, y = 0, x = 0;
  int Hf = Hc * 2;
  if (i < total) {
    x = i % Hc; y = (i / Hc) % Hc; b = i / (Hc * Hc);
    const int* p = imF + ((size_t)b * Hf + 2 * y) * Hf + 2 * x;
    act = (p[0] >= 0) || (p[1] >= 0) || (p[Hf] >= 0) || (p[Hf + 1] >= 0);
  }
  unsigned long long mb = __ballot(act);
  int lane = threadIdx.x & 63;
  int prefix = __popcll(mb & ((1ull << lane) - 1));
  int base = 0;
  if (lane == 0) base = atomicAdd(nact, __popcll(mb));
  base = __shfl(base, 0);
  if (i < total) {
    int idx = act ? (base + prefix) : -1;
    if (idx >= nmax) idx = -1;
    im[i] = idx;
    if (idx >= 0) list[idx] = (b << 20) | (y << 10) | x;
  }
}

// ------------------------------------------------------------------ 9-neighbor index table
__global__ __launch_bounds__(256) void build_nbr_k(const int* __restrict__ list,
    const int* __restrict__ im, const int* __restrict__ nactp,
    int* __restrict__ nbr, int H, int nmax) {
  int i = blockIdx.x * 256 + threadIdx.x;
  if (i >= nactp[0]) return;
  int code = list[i];
  int b = code >> 20, y = (code >> 10) & 1023, x = code & 1023;
#pragma unroll
  for (int k = 0; k < 9; ++k) {
    int yy = y + k / 3 - 1, xx = x + k % 3 - 1;
    int v = -1;
    if (yy >= 0 && yy < H && xx >= 0 && xx < H)
      v = im[((size_t)b * H + yy) * H + xx];
    nbr[k * nmax + i] = v;
  }
}

// ------------------------------------------------------------------ weight transpose  [R][C] -> [C][R]
__global__ __launch_bounds__(256) void transpose_k(const float* __restrict__ in,
                                                   float* __restrict__ out,
                                                   int R, int C) {
  __shared__ float tile[32][33];
  int bx = blockIdx.x * 32;  // col base (C dim)
  int by = blockIdx.y * 32;  // row base (R dim)
  int tx = threadIdx.x % 32, ty0 = threadIdx.x / 32;
  for (int ty = ty0; ty < 32; ty += 8) {
    int r = by + ty, c = bx + tx;
    tile[ty][tx] = (r < R && c < C) ? in[(size_t)r * C + c] : 0.f;
  }
  __syncthreads();
  for (int ty = ty0; ty < 32; ty += 8) {
    int r = bx + ty, c = by + tx;
    if (r < C && c < R) out[(size_t)r * R + c] = tile[tx][ty];
  }
}

// ------------------------------------------------------------------ gather-GEMM submanifold conv (256 thr, 4x8; L1-L4)
template <int CC, int SITES, int OCB, int SPT, int OPT, bool RAW>
__global__ __launch_bounds__(256, 2) void gconv_k(
    const float* __restrict__ in, float* __restrict__ out,
    const float* __restrict__ wT, const float* __restrict__ bias,
    const int* __restrict__ nbr, const int* __restrict__ nactp,
    int Cin, int Cout, int Nmax, int cinCnt, int nocb) {
  constexpr int KSL = CC * 9;
  __shared__ int s_nbr[9][SITES];
  __shared__ float s_a[KSL][SITES];
  __shared__ float s_w[KSL][OCB];
  const int n = nactp[0];
  const int gid = blockIdx.x;
  const int xcd = gid & 7;
  const int pos = gid >> 3;
  const int ocbI = pos % nocb;
  const int sb = (pos / nocb) * 8 + xcd;
  const int base = sb * SITES;
  if (base >= n) return;
  const int ocb = ocbI * OCB;
  const int t = threadIdx.x;
  for (int s = t; s < 9 * SITES; s += 256) {
    int i = s % SITES, k = s / SITES;
    int gi = base + i;
    s_nbr[k][i] = (gi < n) ? nbr[k * Nmax + gi] : -1;
  }
  constexpr int OCG = OCB / OPT;
  const int oc0 = (t % OCG) * 4;           // 4-float chunk base
  const int si0 = (t / OCG) * SPT;
  float acc[SPT][OPT];
#pragma unroll
  for (int a = 0; a < SPT; ++a)
#pragma unroll
    for (int j = 0; j < OPT; ++j) acc[a][j] = 0.f;
  __syncthreads();
  const int cinStart = RAW ? (blockIdx.z * cinCnt) : 0;
  const int nch = cinCnt / CC;
  for (int ch = 0; ch < nch; ++ch) {
    const int c0 = cinStart + ch * CC;
    const float* wrow = wT + ((size_t)c0 * 9) * Cout + ocb;
    for (int s = t; s < KSL * (OCB / 4); s += 256) {
      int j4 = s % (OCB / 4), r = s / (OCB / 4);
      *(float4*)&s_w[r][j4 * 4] = *(const float4*)(wrow + (size_t)r * Cout + j4 * 4);
    }
    if constexpr (CC == 1) {
      for (int s = t; s < 9 * SITES; s += 256) {
        int i = s % SITES, k = s / SITES;
        int row = s_nbr[k][i];
        s_a[k][i] = (row >= 0) ? in[row] : 0.f;
      }
    } else {
      constexpr int H4 = CC / 4;
      for (int s = t; s < H4 * 9 * SITES; s += 256) {
        int i = s % SITES, m = s / SITES;
        int c4 = m % H4, k = m / H4;
        int row = s_nbr[k][i];
        float4 v = make_float4(0.f, 0.f, 0.f, 0.f);
        if (row >= 0)
          v = *(const float4*)(in + (size_t)row * Cin + c0 + c4 * 4);
        s_a[(c4 * 4 + 0) * 9 + k][i] = v.x;
        s_a[(c4 * 4 + 1) * 9 + k][i] = v.y;
        s_a[(c4 * 4 + 2) * 9 + k][i] = v.z;
        s_a[(c4 * 4 + 3) * 9 + k][i] = v.w;
      }
    }
    __syncthreads();
#pragma unroll
    for (int kk = 0; kk < KSL; ++kk) {
      float av[SPT];
      if constexpr (SPT == 4) {
        float4 a4 = *(const float4*)&s_a[kk][si0];
        av[0] = a4.x; av[1] = a4.y; av[2] = a4.z; av[3] = a4.w;
      } else {
        float2 a2 = *(const float2*)&s_a[kk][si0];
        av[0] = a2.x; av[1] = a2.y;
      }
      float wv[OPT];
      if constexpr (OPT == 8) {
        float4 w4a = *(const float4*)&s_w[kk][oc0];
        float4 w4b = *(const float4*)&s_w[kk][OCB / 2 + oc0];
        wv[0] = w4a.x; wv[1] = w4a.y; wv[2] = w4a.z; wv[3] = w4a.w;
        wv[4] = w4b.x; wv[5] = w4b.y; wv[6] = w4b.z; wv[7] = w4b.w;
      } else {
        float4 w4 = *(const float4*)&s_w[kk][oc0];
        wv[0] = w4.x; wv[1] = w4.y; wv[2] = w4.z; wv[3] = w4.w;
      }
#pragma unroll
      for (int a = 0; a < SPT; ++a)
#pragma unroll
        for (int j = 0; j < OPT; ++j)
          acc[a][j] = fmaf(av[a], wv[j], acc[a][j]);
    }
    __syncthreads();
  }
  float bz[OPT];
  if constexpr (!RAW) {
#pragma unroll
    for (int j = 0; j < OPT; ++j) {
      int oj = (OPT == 8) ? ((j < 4) ? (oc0 + j) : (OCB / 2 + oc0 + j - 4))
                          : (oc0 + j);
      bz[j] = bias[ocb + oj];
    }
  }
  float* ob = out;
  if constexpr (RAW) ob += (size_t)blockIdx.z * Nmax * Cout;
#pragma unroll
  for (int a = 0; a < SPT; ++a) {
    int gi = base + si0 + a;
    if (gi < n) {
      float* po = ob + (size_t)gi * Cout + ocb;
      if constexpr (OPT == 8) {
        float4 v0, v1;
        if constexpr (RAW) {
          v0 = make_float4(acc[a][0], acc[a][1], acc[a][2], acc[a][3]);
          v1 = make_float4(acc[a][4], acc[a][5], acc[a][6], acc[a][7]);
        } else {
          v0.x = fmaxf(acc[a][0] + bz[0], 0.f); v0.y = fmaxf(acc[a][1] + bz[1], 0.f);
          v0.z = fmaxf(acc[a][2] + bz[2], 0.f); v0.w = fmaxf(acc[a][3] + bz[3], 0.f);
          v1.x = fmaxf(acc[a][4] + bz[4], 0.f); v1.y = fmaxf(acc[a][5] + bz[5], 0.f);
          v1.z = fmaxf(acc[a][6] + bz[6], 0.f); v1.w = fmaxf(acc[a][7] + bz[7], 0.f);
        }
        *(float4*)(po + oc0) = v0;
        *(float4*)(po + OCB / 2 + oc0) = v1;
      } else {
        float4 v;
        if constexpr (RAW) {
          v = make_float4(acc[a][0], acc[a][1], acc[a][2], acc[a][3]);
        } else {
          v.x = fmaxf(acc[a][0] + bz[0], 0.f); v.y = fmaxf(acc[a][1] + bz[1], 0.f);
          v.z = fmaxf(acc[a][2] + bz[2], 0.f); v.w = fmaxf(acc[a][3] + bz[3], 0.f);
        }
        *(float4*)(po + oc0) = v;
      }
    }
  }
}

// ------------------------------------------------------------------ 256-thread 8x8 gather-GEMM (L5-L13)
// SITES=64 x OCB=256, thread tile 8 sites x 8 oc (split-oc at 128), 4 waves.
// LDS 48.4KB -> 3 blocks/CU (12 waves/CU at VGPR<=170).
// Per kk: 4 ds_read_b128 per 64 FMA -> LDS:VALU = 1.5 (r3 was 2.25).
// LESSONS: (r4/r6) min-occupancy launch_bounds -> VGPR 84 -> acc spills to
// scratch (GB-scale TCC traffic). Plain bounds -> ~132 VGPR, no spill.
// (r3/r5/r7) 4-wave blocks reach steady residency; 2-wave/1-block don't.
template <int CC, bool RAW>
__global__ __launch_bounds__(256) void gconv8_k(
    const float* __restrict__ in, float* __restrict__ out,
    const float* __restrict__ wT, const float* __restrict__ bias,
    const int* __restrict__ nbr, const int* __restrict__ nactp,
    int Cin, int Cout, int Nmax, int cinCnt, int nocb) {
  constexpr int KSL = CC * 9;
  constexpr int SITES = 64, OCB = 256;
  __shared__ int s_nbr[9][SITES];
  __shared__ float s_a[KSL][SITES];
  __shared__ float s_w[KSL][OCB];
  const int n = nactp[0];
  const int gid = blockIdx.x;
  const int xcd = gid & 7;
  const int pos = gid >> 3;
  const int ocbI = pos % nocb;
  const int sb = (pos / nocb) * 8 + xcd;
  const int base = sb * SITES;
  if (base >= n) return;
  const int ocb = ocbI * OCB;
  const int t = threadIdx.x;
  for (int s = t; s < 9 * SITES; s += 256) {
    int i = s & 63, k = s >> 6;
    int gi = base + i;
    s_nbr[k][i] = (gi < n) ? nbr[k * Nmax + gi] : -1;
  }
  const int oc0 = (t & 31) * 4;   // 32 oc-groups covering OCB/2=128
  const int si0 = (t >> 5) * 8;   // 8 site-groups
  float acc[8][8];
#pragma unroll
  for (int a = 0; a < 8; ++a)
#pragma unroll
    for (int j = 0; j < 8; ++j) acc[a][j] = 0.f;
  __syncthreads();
  const int cinStart = RAW ? (blockIdx.z * cinCnt) : 0;
  const int nch = cinCnt / CC;
  for (int ch = 0; ch < nch; ++ch) {
    const int c0 = cinStart + ch * CC;
    const float* wrow = wT + ((size_t)c0 * 9) * Cout + ocb;
    for (int s = t; s < KSL * (OCB / 4); s += 256) {
      int j4 = s & 63, r = s >> 6;  // OCB/4 = 64
      *(float4*)&s_w[r][j4 * 4] = *(const float4*)(wrow + (size_t)r * Cout + j4 * 4);
    }
    constexpr int H4 = CC / 4;
    for (int s = t; s < H4 * 9 * SITES; s += 256) {
      int i = s & 63, m = s >> 6;
      int c4 = m % H4, k = m / H4;
      int row = s_nbr[k][i];
      float4 v = make_float4(0.f, 0.f, 0.f, 0.f);
      if (row >= 0)
        v = *(const float4*)(in + (size_t)row * Cin + c0 + c4 * 4);
      s_a[(c4 * 4 + 0) * 9 + k][i] = v.x;
      s_a[(c4 * 4 + 1) * 9 + k][i] = v.y;
      s_a[(c4 * 4 + 2) * 9 + k][i] = v.z;
      s_a[(c4 * 4 + 3) * 9 + k][i] = v.w;
    }
    __syncthreads();
#pragma unroll
    for (int kk = 0; kk < KSL; ++kk) {
      float4 a0 = *(const float4*)&s_a[kk][si0];
      float4 a1 = *(const float4*)&s_a[kk][si0 + 4];
      float4 w4a = *(const float4*)&s_w[kk][oc0];
      float4 w4b = *(const float4*)&s_w[kk][128 + oc0];
      float av[8] = {a0.x, a0.y, a0.z, a0.w, a1.x, a1.y, a1.z, a1.w};
      float wv[8] = {w4a.x, w4a.y, w4a.z, w4a.w, w4b.x, w4b.y, w4b.z, w4b.w};
#pragma unroll
      for (int a = 0; a < 8; ++a)
#pragma unroll
        for (int j = 0; j < 8; ++j)
          acc[a][j] = fmaf(av[a], wv[j], acc[a][j]);
    }
    __syncthreads();
  }
  float bz[8];
  if constexpr (!RAW) {
#pragma unroll
    for (int j = 0; j < 8; ++j) {
      int oj = (j < 4) ? (oc0 + j) : (128 + oc0 + j - 4);
      bz[j] = bias[ocb + oj];
    }
  }
  float* ob = out;
  if constexpr (RAW) ob += (size_t)blockIdx.z * Nmax * Cout;
#pragma unroll
  for (int a = 0; a < 8; ++a) {
    int gi = base + si0 + a;
    if (gi < n) {
      float* po = ob + (size_t)gi * Cout + ocb;
      float4 v0, v1;
      if constexpr (RAW) {
        v0 = make_float4(acc[a][0], acc[a][1], acc[a][2], acc[a][3]);
        v1 = make_float4(acc[a][4], acc[a][5], acc[a][6], acc[a][7]);
      } else {
        v0.x = fmaxf(acc[a][0] + bz[0], 0.f); v0.y = fmaxf(acc[a][1] + bz[1], 0.f);
        v0.z = fmaxf(acc[a][2] + bz[2], 0.f); v0.w = fmaxf(acc[a][3] + bz[3], 0.f);
        v1.x = fmaxf(acc[a][4] + bz[4], 0.f); v1.y = fmaxf(acc[a][5] + bz[5], 0.f);
        v1.z = fmaxf(acc[a][6] + bz[6], 0.f); v1.w = fmaxf(acc[a][7] + bz[7], 0.f);
      }
      *(float4*)(po + oc0) = v0;
      *(float4*)(po + 128 + oc0) = v1;
    }
  }
}

// ------------------------------------------------------------------ K-split combine (+bias+relu)
__global__ __launch_bounds__(256) void combine_k(const float* __restrict__ P,
    float* __restrict__ out, const float* __restrict__ bias,
    const int* __restrict__ nactp, int C, int S, int sliceStride) {
  int tg = blockIdx.x * 256 + threadIdx.x;
  int cg = C >> 2;
  int j = tg / cg, c4 = tg % cg;
  if (j >= nactp[0]) return;
  size_t o = (size_t)j * C + c4 * 4;
  float4 v = *(const float4*)(bias + c4 * 4);
  for (int s = 0; s < S; ++s) {
    float4 u = *(const float4*)(P + (size_t)s * sliceStride + o);
    v.x += u.x; v.y += u.y; v.z += u.z; v.w += u.w;
  }
  v.x = fmaxf(v.x, 0.f); v.y = fmaxf(v.y, 0.f);
  v.z = fmaxf(v.z, 0.f); v.w = fmaxf(v.w, 0.f);
  *(float4*)(out + o) = v;
}

// ------------------------------------------------------------------ compact 2x2 maxpool
__global__ __launch_bounds__(256) void pool_c_k(const float* __restrict__ inF,
    float* __restrict__ outF, const int* __restrict__ listC,
    const int* __restrict__ imF, const int* __restrict__ nactp, int Hf, int C) {
  int tg = blockIdx.x * 256 + threadIdx.x;
  int cg = C >> 2;
  int j = tg / cg, c4 = tg % cg;
  if (j >= nactp[0]) return;
  int code = listC[j];
  int b = code >> 20, Y = (code >> 10) & 1023, X = code & 1023;
  float4 v = make_float4(0.f, 0.f, 0.f, 0.f);
#pragma unroll
  for (int dy = 0; dy < 2; ++dy)
#pragma unroll
    for (int dx = 0; dx < 2; ++dx) {
      int ci = imF[((size_t)b * Hf + 2 * Y + dy) * Hf + 2 * X + dx];
      if (ci >= 0) {
        float4 u = *(const float4*)(inF + (size_t)ci * C + c4 * 4);
        v.x = fmaxf(v.x, u.x); v.y = fmaxf(v.y, u.y);
        v.z = fmaxf(v.z, u.z); v.w = fmaxf(v.w, u.w);
      }
    }
  *(float4*)(outF + (size_t)j * C + c4 * 4) = v;
}

// ------------------------------------------------------------------ final pool -> dense [2,512,16,16]
__global__ __launch_bounds__(256) void pool_d_k(const float* __restrict__ inF,
    float* __restrict__ outD, const int* __restrict__ im32) {
  int tg = blockIdx.x * 256 + threadIdx.x;  // 2*16*16*128 = 65536
  int c4 = tg & 127;
  int rest = tg >> 7;
  int X = rest & 15, Y = (rest >> 4) & 15, b = rest >> 8;
  float4 v = make_float4(0.f, 0.f, 0.f, 0.f);
#pragma unroll
  for (int dy = 0; dy < 2; ++dy)
#pragma unroll
    for (int dx = 0; dx < 2; ++dx) {
      int ci = im32[((size_t)b * 32 + 2 * Y + dy) * 32 + 2 * X + dx];
      if (ci >= 0) {
        float4 u = *(const float4*)(inF + (size_t)ci * 512 + c4 * 4);
        v.x = fmaxf(v.x, u.x); v.y = fmaxf(v.y, u.y);
        v.z = fmaxf(v.z, u.z); v.w = fmaxf(v.w, u.w);
      }
    }
  const float* pv = &v.x;
#pragma unroll
  for (int u = 0; u < 4; ++u) {
    int c = c4 * 4 + u;
    outD[(((size_t)b * 512 + c) * 16 + Y) * 16 + X] = pv[u];
  }
}

// ------------------------------------------------------------------ fully connected
template <bool RELU>
__global__ __launch_bounds__(256) void fc_k(const float* __restrict__ in,
                                            const float* __restrict__ w,
                                            const float* __restrict__ bias,
                                            float* __restrict__ out, int K,
                                            int R) {
  const int r = blockIdx.x;
  const int t = threadIdx.x;
  const float* wr = w + (size_t)r * K;
  float a0 = 0.f, a1 = 0.f;
  for (int k = t * 4; k < K; k += 1024) {
    float4 wv = *(const float4*)(wr + k);
    float4 x0 = *(const float4*)(in + k);
    float4 x1 = *(const float4*)(in + K + k);
    a0 += wv.x * x0.x + wv.y * x0.y + wv.z * x0.z + wv.w * x0.w;
    a1 += wv.x * x1.x + wv.y * x1.y + wv.z * x1.z + wv.w * x1.w;
  }
#pragma unroll
  for (int off = 32; off > 0; off >>= 1) {
    a0 += __shfl_down(a0, off);
    a1 += __shfl_down(a1, off);
  }
  __shared__ float s0[4], s1[4];
  const int lane = t & 63, wid = t >> 6;
  if (lane == 0) { s0[wid] = a0; s1[wid] = a1; }
  __syncthreads();
  if (t == 0) {
    float v0 = s0[0] + s0[1] + s0[2] + s0[3] + bias[r];
    float v1 = s1[0] + s1[1] + s1[2] + s1[3] + bias[r];
    if (RELU) { v0 = fmaxf(v0, 0.f); v1 = fmaxf(v1, 0.f); }
    out[r] = v0;
    out[R + r] = v1;
  }
}

// ------------------------------------------------------------------ launch
extern "C" void kernel_launch(void* const* d_in, const int* in_sizes, int n_in,
                              void* d_out, int out_size, void* d_ws,
                              size_t ws_size, hipStream_t stream) {
  (void)in_sizes; (void)n_in; (void)out_size; (void)ws_size;
  const float* x = (const float*)d_in[0];
  const float* Wc[14];
  const float* Bc[14];
  for (int i = 1; i <= 13; ++i) {
    Wc[i] = (const float*)d_in[2 * i - 1];
    Bc[i] = (const float*)d_in[2 * i];
  }
  const float* fw1 = (const float*)d_in[27];
  const float* fb1 = (const float*)d_in[28];
  const float* fw2 = (const float*)d_in[29];
  const float* fb2 = (const float*)d_in[30];
  const float* fw3 = (const float*)d_in[31];
  const float* fb3 = (const float*)d_in[32];
  const float* fw4 = (const float*)d_in[33];
  const float* fb4 = (const float*)d_in[34];

  static const int CH[14] = {1, 64, 64, 128, 128, 256, 256, 256,
                             512, 512, 512, 512, 512, 512};

  char* ws = (char*)d_ws;
  size_t cur = 0;
  auto alloc = [&](size_t bytes) {
    size_t o = cur;
    cur += (bytes + 255) & ~(size_t)255;
    return o;
  };
  // weight transposes
  size_t wtOff[14];
  for (int i = 1; i <= 13; ++i)
    wtOff[i] = alloc((size_t)CH[i] * CH[i - 1] * 9 * 4);
  float* wT[14];
  for (int i = 1; i <= 13; ++i) wT[i] = (float*)(ws + wtOff[i]);
  // features. Praw (K-split partials) aliases the contiguous dead arena
  // starting at A1: L5-L7 need 42MB (< A1..A4 = 53.5MB, inputs P4/A5/A6 are
  // after it or live elsewhere); L8-L10 need 67.1MB (< A1..A6 = 106MB; P7/A8/
  // A9 live, all after); L11-13 need 33.5MB.
  float* F0  = (float*)(ws + alloc((size_t)NMAX512 * 1 * 4));
  size_t a1Off = alloc((size_t)NMAX512 * 64 * 4);
  float* A1  = (float*)(ws + a1Off);
  float* Praw = A1;  // aliased K-split partial buffer
  float* A2  = (float*)(ws + alloc((size_t)NMAX512 * 64 * 4));
  float* P2  = (float*)(ws + alloc((size_t)NMAX256 * 64 * 4));
  float* A3  = (float*)(ws + alloc((size_t)NMAX256 * 128 * 4));
  float* A4  = (float*)(ws + alloc((size_t)NMAX256 * 128 * 4));
  float* P4  = (float*)(ws + alloc((size_t)NMAX128 * 128 * 4));
  float* A5  = (float*)(ws + alloc((size_t)NMAX128 * 256 * 4));
  float* A6  = (float*)(ws + alloc((size_t)NMAX128 * 256 * 4));
  float* P7  = (float*)(ws + alloc((size_t)NMAX64 * 256 * 4));
  float* A8  = (float*)(ws + alloc((size_t)NMAX64 * 512 * 4));
  float* A9  = (float*)(ws + alloc((size_t)NMAX64 * 512 * 4));
  float* P10 = (float*)(ws + alloc((size_t)NMAX32 * 512 * 4));
  float* A11 = (float*)(ws + alloc((size_t)NMAX32 * 512 * 4));
  float* A12 = (float*)(ws + alloc((size_t)NMAX32 * 512 * 4));
  float* D13 = (float*)(ws + alloc((size_t)NB * 512 * 16 * 16 * 4));
  float* F1  = (float*)(ws + alloc(NB * 1024 * 4));
  float* F2  = (float*)(ws + alloc(NB * 512 * 4));
  float* F3  = (float*)(ws + alloc(NB * 256 * 4));
  // index maps / lists / neighbor tables / counters
  int* im512 = (int*)(ws + alloc((size_t)NB * 512 * 512 * 4));
  int* im256 = (int*)(ws + alloc((size_t)NB * 256 * 256 * 4));
  int* im128 = (int*)(ws + alloc((size_t)NB * 128 * 128 * 4));
  int* im64  = (int*)(ws + alloc((size_t)NB * 64 * 64 * 4));
  int* im32  = (int*)(ws + alloc((size_t)NB * 32 * 32 * 4));
  int* l512 = (int*)(ws + alloc((size_t)NMAX512 * 4));
  int* l256 = (int*)(ws + alloc((size_t)NMAX256 * 4));
  int* l128 = (int*)(ws + alloc((size_t)NMAX128 * 4));
  int* l64  = (int*)(ws + alloc((size_t)NMAX64 * 4));
  int* l32  = (int*)(ws + alloc((size_t)NMAX32 * 4));
  int* nb512 = (int*)(ws + alloc((size_t)9 * NMAX512 * 4));
  int* nb256 = (int*)(ws + alloc((size_t)9 * NMAX256 * 4));
  int* nb128 = (int*)(ws + alloc((size_t)9 * NMAX128 * 4));
  int* nb64  = (int*)(ws + alloc((size_t)9 * NMAX64 * 4));
  int* nb32  = (int*)(ws + alloc((size_t)9 * NMAX32 * 4));
  int* nact = (int*)(ws + alloc(256));  // [0..4] per-resolution counts

  const dim3 blk(256);
  hipMemsetAsync(nact, 0, 32, stream);

  // ---- lists / index maps / neighbors
  hipLaunchKernelGGL(build_l0_k, dim3(2048), blk, 0, stream, x, l512, im512, F0, nact + 0, NB * 512 * 512, NMAX512);
  hipLaunchKernelGGL(build_pl_k, dim3(512), blk, 0, stream, im512, l256, im256, nact + 1, 256, NMAX256);
  hipLaunchKernelGGL(build_pl_k, dim3(128), blk, 0, stream, im256, l128, im128, nact + 2, 128, NMAX128);
  hipLaunchKernelGGL(build_pl_k, dim3(32), blk, 0, stream, im128, l64, im64, nact + 3, 64, NMAX64);
  hipLaunchKernelGGL(build_pl_k, dim3(8), blk, 0, stream, im64, l32, im32, nact + 4, 32, NMAX32);
  hipLaunchKernelGGL(build_nbr_k, dim3(NMAX512 / 256), blk, 0, stream, l512, im512, nact + 0, nb512, 512, NMAX512);
  hipLaunchKernelGGL(build_nbr_k, dim3(NMAX256 / 256), blk, 0, stream, l256, im256, nact + 1, nb256, 256, NMAX256);
  hipLaunchKernelGGL(build_nbr_k, dim3(NMAX128 / 256), blk, 0, stream, l128, im128, nact + 2, nb128, 128, NMAX128);
  hipLaunchKernelGGL(build_nbr_k, dim3(NMAX64 / 256), blk, 0, stream, l64, im64, nact + 3, nb64, 64, NMAX64);
  hipLaunchKernelGGL(build_nbr_k, dim3(NMAX32 / 256), blk, 0, stream, l32, im32, nact + 4, nb32, 32, NMAX32);

  // ---- weight transposes: w[Cout][Cin*9] -> wT[Cin*9][Cout]
  for (int i = 1; i <= 13; ++i) {
    int R = CH[i], C = CH[i - 1] * 9;
    hipLaunchKernelGGL(transpose_k, dim3((C + 31) / 32, (R + 31) / 32), blk, 0,
                       stream, Wc[i], wT[i], R, C);
  }

  // ---- convs
  // L1: 1->64 @512
  hipLaunchKernelGGL((gconv_k<1, 64, 64, 4, 4, false>), dim3(512, 1, 1), blk, 0, stream,
                     F0, A1, wT[1], Bc[1], nb512, nact + 0, 1, 64, NMAX512, 1, 1);
  // L2: 64->64 @512
  hipLaunchKernelGGL((gconv_k<8, 64, 64, 4, 4, false>), dim3(512, 1, 1), blk, 0, stream,
                     A1, A2, wT[2], Bc[2], nb512, nact + 0, 64, 64, NMAX512, 64, 1);
  hipLaunchKernelGGL(pool_c_k, dim3(NMAX256 * 16 / 256), blk, 0, stream, A2, P2, l256, im512, nact + 1, 512, 64);
  // L3: 64->128 @256
  hipLaunchKernelGGL((gconv_k<8, 64, 128, 4, 8, false>), dim3(448, 1, 1), blk, 0, stream,
                     P2, A3, wT[3], Bc[3], nb256, nact + 1, 64, 128, NMAX256, 64, 1);
  // L4: 128->128 @256
  hipLaunchKernelGGL((gconv_k<8, 64, 128, 4, 8, false>), dim3(448, 1, 1), blk, 0, stream,
                     A3, A4, wT[4], Bc[4], nb256, nact + 1, 128, 128, NMAX256, 128, 1);
  hipLaunchKernelGGL(pool_c_k, dim3(NMAX128 * 32 / 256), blk, 0, stream, A4, P4, l128, im256, nact + 2, 256, 128);

  // L5-L13: 256-thread 8x8 kernel (SITES=64, OCB=256, CC=4), K-split -> Praw + combine
  const int SL128 = NMAX128 * 256;  // slice stride (floats), res128 layers
  const int SL64  = NMAX64 * 512;   // res64 layers
  const int SL32  = NMAX32 * 512;   // res32 layers
  // L5: 128->256 @128, z=2 (cinCnt=64); grid.x = (NMAX128/64 sb /8)*8*nocb1 = 320
  hipLaunchKernelGGL((gconv8_k<4, true>), dim3(320, 1, 2), blk, 0, stream,
                     P4, Praw, wT[5], nullptr, nb128, nact + 2, 128, 256, NMAX128, 64, 1);
  hipLaunchKernelGGL(combine_k, dim3(NMAX128 * 64 / 256), blk, 0, stream, Praw, A5, Bc[5], nact + 2, 256, 2, SL128);
  // L6: 256->256 @128, z=2 (cinCnt=128)
  hipLaunchKernelGGL((gconv8_k<4, true>), dim3(320, 1, 2), blk, 0, stream,
                     A5, Praw, wT[6], nullptr, nb128, nact + 2, 256, 256, NMAX128, 128, 1);
  hipLaunchKernelGGL(combine_k, dim3(NMAX128 * 64 / 256), blk, 0, stream, Praw, A6, Bc[6], nact + 2, 256, 2, SL128);
  // L7: 256->256 @128, z=2
  hipLaunchKernelGGL((gconv8_k<4, true>), dim3(320, 1, 2), blk, 0, stream,
                     A6, Praw, wT[7], nullptr, nb128, nact + 2, 256, 256, NMAX128, 128, 1);
  hipLaunchKernelGGL(combine_k, dim3(NMAX128 * 64 / 256), blk, 0, stream, Praw, A5, Bc[7], nact + 2, 256, 2, SL128);
  hipLaunchKernelGGL(pool_c_k, dim3(NMAX64 * 64 / 256), blk, 0, stream, A5, P7, l64, im128, nact + 3, 128, 256);
  // L8: 256->512 @64, z=4 (cinCnt=64); grid.x = (NMAX64/64 /8)*8*nocb2 = 256
  hipLaunchKernelGGL((gconv8_k<4, true>), dim3(256, 1, 4), blk, 0, stream,
                     P7, Praw, wT[8], nullptr, nb64, nact + 3, 256, 512, NMAX64, 64, 2);
  hipLaunchKernelGGL(combine_k, dim3(NMAX64 * 128 / 256), blk, 0, stream, Praw, A8, Bc[8], nact + 3, 512, 4, SL64);
  // L9: 512->512 @64, z=4 (cinCnt=128)
  hipLaunchKernelGGL((gconv8_k<4, true>), dim3(256, 1, 4), blk, 0, stream,
                     A8, Praw, wT[9], nullptr, nb64, nact + 3, 512, 512, NMAX64, 128, 2);
  hipLaunchKernelGGL(combine_k, dim3(NMAX64 * 128 / 256), blk, 0, stream, Praw, A9, Bc[9], nact + 3, 512, 4, SL64);
  // L10: 512->512 @64, z=4
  hipLaunchKernelGGL((gconv8_k<4, true>), dim3(256, 1, 4), blk, 0, stream,
                     A9, Praw, wT[10], nullptr, nb64, nact + 3, 512, 512, NMAX64, 128, 2);
  hipLaunchKernelGGL(combine_k, dim3(NMAX64 * 128 / 256), blk, 0, stream, Praw, A8, Bc[10], nact + 3, 512, 4, SL64);
  hipLaunchKernelGGL(pool_c_k, dim3(NMAX32 * 128 / 256), blk, 0, stream, A8, P10, l32, im64, nact + 4, 64, 512);
  // L11-13: 512->512 @32, z=8 (cinCnt=64); grid.x = (NMAX32/64 /8)*8*nocb2 = 64
  hipLaunchKernelGGL((gconv8_k<4, true>), dim3(64, 1, 8), blk, 0, stream,
                     P10, Praw, wT[11], nullptr, nb32, nact + 4, 512, 512, NMAX32, 64, 2);
  hipLaunchKernelGGL(combine_k, dim3(NMAX32 * 128 / 256), blk, 0, stream, Praw, A11, Bc[11], nact + 4, 512, 8, SL32);
  hipLaunchKernelGGL((gconv8_k<4, true>), dim3(64, 1, 8), blk, 0, stream,
                     A11, Praw, wT[12], nullptr, nb32, nact + 4, 512, 512, NMAX32, 64, 2);
  hipLaunchKernelGGL(combine_k, dim3(NMAX32 * 128 / 256), blk, 0, stream, Praw, A12, Bc[12], nact + 4, 512, 8, SL32);
  hipLaunchKernelGGL((gconv8_k<4, true>), dim3(64, 1, 8), blk, 0, stream,
                     A12, Praw, wT[13], nullptr, nb32, nact + 4, 512, 512, NMAX32, 64, 2);
  hipLaunchKernelGGL(combine_k, dim3(NMAX32 * 128 / 256), blk, 0, stream, Praw, A11, Bc[13], nact + 4, 512, 8, SL32);
  // final pool -> dense
  hipLaunchKernelGGL(pool_d_k, dim3(256), blk, 0, stream, A11, D13, im32);

  // ---- MLP
  hipLaunchKernelGGL((fc_k<true>), dim3(1024), blk, 0, stream, D13, fw1, fb1, F1, 131072, 1024);
  hipLaunchKernelGGL((fc_k<true>), dim3(512), blk, 0, stream, F1, fw2, fb2, F2, 1024, 512);
  hipLaunchKernelGGL((fc_k<true>), dim3(256), blk, 0, stream, F2, fw3, fb3, F3, 512, 256);
  hipLaunchKernelGGL((fc_k<false>), dim3(2), blk, 0, stream, F3, fw4, fb4, (float*)d_out, 256, 2);
}

// Round 9
// 3017.510 us; speedup vs baseline: 2.2941x; 1.6366x over previous
//
#include <hip/hip_runtime.h>
#include <cstddef>
#include <cstdint>

#define NB 2

// Nmax per resolution (upper bounds on active sites, both batches)
#define NMAX512 32768
#define NMAX256 28672
#define NMAX128 20480
#define NMAX64  8192
#define NMAX32  2048

// ------------------------------------------------------------------ list build (res 512 from x, Cin=1)
__global__ __launch_bounds__(256) void build_l0_k(const float* __restrict__ x,
    int* __restrict__ list, int* __restrict__ im, float* __restrict__ f0,
    int* __restrict__ nact, int total, int nmax) {
  int i = blockIdx.x * 256 + threadIdx.x;
  bool act = false;
  float v = 0.f;
  if (i < total) { v = x[i]; act = (v != 0.f); }
  unsigned long long mb = __ballot(act);
  int lane = threadIdx.x & 63;
  int prefix = __popcll(mb & ((1ull << lane) - 1));
  int base = 0;
  if (lane == 0) base = atomicAdd(nact, __popcll(mb));
  base = __shfl(base, 0);
  if (i < total) {
    int idx = act ? (base + prefix) : -1;
    if (idx >= nmax) idx = -1;
    im[i] = idx;
    if (idx >= 0) {
      int b = i >> 18;            // 512*512 = 2^18
      int rem = i & 262143;
      list[idx] = (b << 20) | ((rem >> 9) << 10) | (rem & 511);
      f0[idx] = v;
    }
  }
}

// ------------------------------------------------------------------ pooled list from finer idxmap
__global__ __launch_bounds__(256) void build_pl_k(const int* __restrict__ imF,
    int* __restrict__ list, int* __restrict__ im, int* __restrict__ nact,
    int Hc, int nmax) {
  int total = NB * Hc * Hc;
  int i = blockIdx.x * 256 + threadIdx.x;
  bool act = false;
  int b = 0, y = 0, x = 0;
  int Hf = Hc * 2;
  if (i < total) {
    x = i % Hc; y = (i / Hc) % Hc; b = i / (Hc * Hc);
    const int* p = imF + ((size_t)b * Hf + 2 * y) * Hf + 2 * x;
    act = (p[0] >= 0) || (p[1] >= 0) || (p[Hf] >= 0) || (p[Hf + 1] >= 0);
  }
  unsigned long long mb = __ballot(act);
  int lane = threadIdx.x & 63;
  int prefix = __popcll(mb & ((1ull << lane) - 1));
  int base = 0;
  if (lane == 0) base = atomicAdd(nact, __popcll(mb));
  base = __shfl(base, 0);
  if (i < total) {
    int idx = act ? (base + prefix) : -1;
    if (idx >= nmax) idx = -1;
    im[i] = idx;
    if (idx >= 0) list[idx] = (b << 20) | (y << 10) | x;
  }
}

// ------------------------------------------------------------------ 9-neighbor index table
__global__ __launch_bounds__(256) void build_nbr_k(const int* __restrict__ list,
    const int* __restrict__ im, const int* __restrict__ nactp,
    int* __restrict__ nbr, int H, int nmax) {
  int i = blockIdx.x * 256 + threadIdx.x;
  if (i >= nactp[0]) return;
  int code = list[i];
  int b = code >> 20, y = (code >> 10) & 1023, x = code & 1023;
#pragma unroll
  for (int k = 0; k < 9; ++k) {
    int yy = y + k / 3 - 1, xx = x + k % 3 - 1;
    int v = -1;
    if (yy >= 0 && yy < H && xx >= 0 && xx < H)
      v = im[((size_t)b * H + yy) * H + xx];
    nbr[k * nmax + i] = v;
  }
}

// ------------------------------------------------------------------ weight transpose  [R][C] -> [C][R]
__global__ __launch_bounds__(256) void transpose_k(const float* __restrict__ in,
                                                   float* __restrict__ out,
                                                   int R, int C) {
  __shared__ float tile[32][33];
  int bx = blockIdx.x * 32;  // col base (C dim)
  int by = blockIdx.y * 32;  // row base (R dim)
  int tx = threadIdx.x % 32, ty0 = threadIdx.x / 32;
  for (int ty = ty0; ty < 32; ty += 8) {
    int r = by + ty, c = bx + tx;
    tile[ty][tx] = (r < R && c < C) ? in[(size_t)r * C + c] : 0.f;
  }
  __syncthreads();
  for (int ty = ty0; ty < 32; ty += 8) {
    int r = bx + ty, c = by + tx;
    if (r < C && c < R) out[(size_t)r * R + c] = tile[tx][ty];
  }
}

// ------------------------------------------------------------------ gather-GEMM submanifold conv (256 thr, 4x8; L1-L4)
template <int CC, int SITES, int OCB, int SPT, int OPT, bool RAW>
__global__ __launch_bounds__(256, 2) void gconv_k(
    const float* __restrict__ in, float* __restrict__ out,
    const float* __restrict__ wT, const float* __restrict__ bias,
    const int* __restrict__ nbr, const int* __restrict__ nactp,
    int Cin, int Cout, int Nmax, int cinCnt, int nocb) {
  constexpr int KSL = CC * 9;
  __shared__ int s_nbr[9][SITES];
  __shared__ float s_a[KSL][SITES];
  __shared__ float s_w[KSL][OCB];
  const int n = nactp[0];
  const int gid = blockIdx.x;
  const int xcd = gid & 7;
  const int pos = gid >> 3;
  const int ocbI = pos % nocb;
  const int sb = (pos / nocb) * 8 + xcd;
  const int base = sb * SITES;
  if (base >= n) return;
  const int ocb = ocbI * OCB;
  const int t = threadIdx.x;
  for (int s = t; s < 9 * SITES; s += 256) {
    int i = s % SITES, k = s / SITES;
    int gi = base + i;
    s_nbr[k][i] = (gi < n) ? nbr[k * Nmax + gi] : -1;
  }
  constexpr int OCG = OCB / OPT;
  const int oc0 = (t % OCG) * 4;           // 4-float chunk base
  const int si0 = (t / OCG) * SPT;
  float acc[SPT][OPT];
#pragma unroll
  for (int a = 0; a < SPT; ++a)
#pragma unroll
    for (int j = 0; j < OPT; ++j) acc[a][j] = 0.f;
  __syncthreads();
  const int cinStart = RAW ? (blockIdx.z * cinCnt) : 0;
  const int nch = cinCnt / CC;
  for (int ch = 0; ch < nch; ++ch) {
    const int c0 = cinStart + ch * CC;
    const float* wrow = wT + ((size_t)c0 * 9) * Cout + ocb;
    for (int s = t; s < KSL * (OCB / 4); s += 256) {
      int j4 = s % (OCB / 4), r = s / (OCB / 4);
      *(float4*)&s_w[r][j4 * 4] = *(const float4*)(wrow + (size_t)r * Cout + j4 * 4);
    }
    if constexpr (CC == 1) {
      for (int s = t; s < 9 * SITES; s += 256) {
        int i = s % SITES, k = s / SITES;
        int row = s_nbr[k][i];
        s_a[k][i] = (row >= 0) ? in[row] : 0.f;
      }
    } else {
      constexpr int H4 = CC / 4;
      for (int s = t; s < H4 * 9 * SITES; s += 256) {
        int i = s % SITES, m = s / SITES;
        int c4 = m % H4, k = m / H4;
        int row = s_nbr[k][i];
        float4 v = make_float4(0.f, 0.f, 0.f, 0.f);
        if (row >= 0)
          v = *(const float4*)(in + (size_t)row * Cin + c0 + c4 * 4);
        s_a[(c4 * 4 + 0) * 9 + k][i] = v.x;
        s_a[(c4 * 4 + 1) * 9 + k][i] = v.y;
        s_a[(c4 * 4 + 2) * 9 + k][i] = v.z;
        s_a[(c4 * 4 + 3) * 9 + k][i] = v.w;
      }
    }
    __syncthreads();
#pragma unroll
    for (int kk = 0; kk < KSL; ++kk) {
      float av[SPT];
      if constexpr (SPT == 4) {
        float4 a4 = *(const float4*)&s_a[kk][si0];
        av[0] = a4.x; av[1] = a4.y; av[2] = a4.z; av[3] = a4.w;
      } else {
        float2 a2 = *(const float2*)&s_a[kk][si0];
        av[0] = a2.x; av[1] = a2.y;
      }
      float wv[OPT];
      if constexpr (OPT == 8) {
        float4 w4a = *(const float4*)&s_w[kk][oc0];
        float4 w4b = *(const float4*)&s_w[kk][OCB / 2 + oc0];
        wv[0] = w4a.x; wv[1] = w4a.y; wv[2] = w4a.z; wv[3] = w4a.w;
        wv[4] = w4b.x; wv[5] = w4b.y; wv[6] = w4b.z; wv[7] = w4b.w;
      } else {
        float4 w4 = *(const float4*)&s_w[kk][oc0];
        wv[0] = w4.x; wv[1] = w4.y; wv[2] = w4.z; wv[3] = w4.w;
      }
#pragma unroll
      for (int a = 0; a < SPT; ++a)
#pragma unroll
        for (int j = 0; j < OPT; ++j)
          acc[a][j] = fmaf(av[a], wv[j], acc[a][j]);
    }
    __syncthreads();
  }
  float bz[OPT];
  if constexpr (!RAW) {
#pragma unroll
    for (int j = 0; j < OPT; ++j) {
      int oj = (OPT == 8) ? ((j < 4) ? (oc0 + j) : (OCB / 2 + oc0 + j - 4))
                          : (oc0 + j);
      bz[j] = bias[ocb + oj];
    }
  }
  float* ob = out;
  if constexpr (RAW) ob += (size_t)blockIdx.z * Nmax * Cout;
#pragma unroll
  for (int a = 0; a < SPT; ++a) {
    int gi = base + si0 + a;
    if (gi < n) {
      float* po = ob + (size_t)gi * Cout + ocb;
      if constexpr (OPT == 8) {
        float4 v0, v1;
        if constexpr (RAW) {
          v0 = make_float4(acc[a][0], acc[a][1], acc[a][2], acc[a][3]);
          v1 = make_float4(acc[a][4], acc[a][5], acc[a][6], acc[a][7]);
        } else {
          v0.x = fmaxf(acc[a][0] + bz[0], 0.f); v0.y = fmaxf(acc[a][1] + bz[1], 0.f);
          v0.z = fmaxf(acc[a][2] + bz[2], 0.f); v0.w = fmaxf(acc[a][3] + bz[3], 0.f);
          v1.x = fmaxf(acc[a][4] + bz[4], 0.f); v1.y = fmaxf(acc[a][5] + bz[5], 0.f);
          v1.z = fmaxf(acc[a][6] + bz[6], 0.f); v1.w = fmaxf(acc[a][7] + bz[7], 0.f);
        }
        *(float4*)(po + oc0) = v0;
        *(float4*)(po + OCB / 2 + oc0) = v1;
      } else {
        float4 v;
        if constexpr (RAW) {
          v = make_float4(acc[a][0], acc[a][1], acc[a][2], acc[a][3]);
        } else {
          v.x = fmaxf(acc[a][0] + bz[0], 0.f); v.y = fmaxf(acc[a][1] + bz[1], 0.f);
          v.z = fmaxf(acc[a][2] + bz[2], 0.f); v.w = fmaxf(acc[a][3] + bz[3], 0.f);
        }
        *(float4*)(po + oc0) = v;
      }
    }
  }
}

// ------------------------------------------------------------------ 256-thread 8x8 gather-GEMM, CC=4 (L5-L13)
// SITES=64 x OCB=256, thread tile 8 sites x 8 oc (split-oc at 128), 4 waves.
// LDS 48.4KB. Per kk: 4 ds_read_b128 per 64 FMA -> LDS:VALU = 1.5.
// VGPR CLIFF LESSON (r3..r8): occupancy quantizes at VGPR {64,128,256}.
//   VGPR=104 (r3) -> ~7 waves/CU, VALU 53%.  VGPR=132 (r7/r8) -> ~3.5 waves/CU,
//   VALU 32%, 1.5x slower despite better LDS ratio.  So: cap at 128 via
//   __launch_bounds__(256,2) (4-reg deficit, benign) + strength-reduced
//   staging addressing.  NEVER cap far below need (84 -> acc spill disaster).
template <bool RAW>
__global__ __launch_bounds__(256, 2) void gconv8_k(
    const float* __restrict__ in, float* __restrict__ out,
    const float* __restrict__ wT, const float* __restrict__ bias,
    const int* __restrict__ nbr, const int* __restrict__ nactp,
    int Cin, int Cout, int Nmax, int cinCnt, int nocb) {
  constexpr int KSL = 36;           // CC=4 x 9 taps
  constexpr int SITES = 64, OCB = 256;
  __shared__ int s_nbr[9][SITES];
  __shared__ float s_a[KSL][SITES];
  __shared__ float s_w[KSL][OCB];
  const int n = nactp[0];
  const int gid = blockIdx.x;
  const int xcd = gid & 7;
  const int pos = gid >> 3;
  const int ocbI = pos % nocb;
  const int sb = (pos / nocb) * 8 + xcd;
  const int base = sb * SITES;
  if (base >= n) return;
  const int ocb = ocbI * OCB;
  const int t = threadIdx.x;
  // per-thread constant staging decomposition (register diet)
  const int ai = t & 63;         // site index for nbr/A staging
  const int ak0 = t >> 6;        // tap base; taps {ak0, ak0+4, ak0+8(<9)}
  const int wj4 = t & 63;        // weight col-group (x4 floats)
  const int wr0 = t >> 6;        // weight row base (stride 4)
  const bool gvalid = (base + ai) < n;
#pragma unroll
  for (int k = ak0; k < 9; k += 4)
    s_nbr[k][ai] = gvalid ? nbr[k * Nmax + base + ai] : -1;
  const int oc0 = (t & 31) * 4;   // 32 oc-groups covering OCB/2=128
  const int si0 = (t >> 5) * 8;   // 8 site-groups
  float acc[8][8];
#pragma unroll
  for (int a = 0; a < 8; ++a)
#pragma unroll
    for (int j = 0; j < 8; ++j) acc[a][j] = 0.f;
  __syncthreads();
  const int cinStart = RAW ? (blockIdx.z * cinCnt) : 0;
  const int nch = cinCnt >> 2;    // cinCnt / CC
  const float* wsrc0 = wT + ((size_t)(cinStart * 9 + wr0)) * Cout + ocb + wj4 * 4;
  for (int ch = 0; ch < nch; ++ch) {
    const int c0 = cinStart + ch * 4;
    // ---- stage weights: 9 fixed-stride float4 stores per thread
    {
      const float* wsrc = wsrc0 + (size_t)(ch * 36) * Cout;
      float* wdst = &s_w[wr0][wj4 * 4];
#pragma unroll
      for (int i = 0; i < 9; ++i) {
        *(float4*)wdst = *(const float4*)wsrc;
        wdst += 4 * OCB;
        wsrc += (size_t)4 * Cout;
      }
    }
    // ---- stage gathered A tile (4 channels x 9 taps x 64 sites)
#pragma unroll
    for (int k = ak0; k < 9; k += 4) {
      int row = s_nbr[k][ai];
      float4 v = make_float4(0.f, 0.f, 0.f, 0.f);
      if (row >= 0)
        v = *(const float4*)(in + (size_t)row * Cin + c0);
      s_a[k][ai] = v.x;
      s_a[9 + k][ai] = v.y;
      s_a[18 + k][ai] = v.z;
      s_a[27 + k][ai] = v.w;
    }
    __syncthreads();
#pragma unroll
    for (int kk = 0; kk < KSL; ++kk) {
      float4 a0 = *(const float4*)&s_a[kk][si0];
      float4 a1 = *(const float4*)&s_a[kk][si0 + 4];
      float4 w4a = *(const float4*)&s_w[kk][oc0];
      float4 w4b = *(const float4*)&s_w[kk][128 + oc0];
      float av[8] = {a0.x, a0.y, a0.z, a0.w, a1.x, a1.y, a1.z, a1.w};
      float wv[8] = {w4a.x, w4a.y, w4a.z, w4a.w, w4b.x, w4b.y, w4b.z, w4b.w};
#pragma unroll
      for (int a = 0; a < 8; ++a)
#pragma unroll
        for (int j = 0; j < 8; ++j)
          acc[a][j] = fmaf(av[a], wv[j], acc[a][j]);
    }
    __syncthreads();
  }
  float bz[8];
  if constexpr (!RAW) {
#pragma unroll
    for (int j = 0; j < 8; ++j) {
      int oj = (j < 4) ? (oc0 + j) : (128 + oc0 + j - 4);
      bz[j] = bias[ocb + oj];
    }
  }
  float* ob = out;
  if constexpr (RAW) ob += (size_t)blockIdx.z * Nmax * Cout;
#pragma unroll
  for (int a = 0; a < 8; ++a) {
    int gi = base + si0 + a;
    if (gi < n) {
      float* po = ob + (size_t)gi * Cout + ocb;
      float4 v0, v1;
      if constexpr (RAW) {
        v0 = make_float4(acc[a][0], acc[a][1], acc[a][2], acc[a][3]);
        v1 = make_float4(acc[a][4], acc[a][5], acc[a][6], acc[a][7]);
      } else {
        v0.x = fmaxf(acc[a][0] + bz[0], 0.f); v0.y = fmaxf(acc[a][1] + bz[1], 0.f);
        v0.z = fmaxf(acc[a][2] + bz[2], 0.f); v0.w = fmaxf(acc[a][3] + bz[3], 0.f);
        v1.x = fmaxf(acc[a][4] + bz[4], 0.f); v1.y = fmaxf(acc[a][5] + bz[5], 0.f);
        v1.z = fmaxf(acc[a][6] + bz[6], 0.f); v1.w = fmaxf(acc[a][7] + bz[7], 0.f);
      }
      *(float4*)(po + oc0) = v0;
      *(float4*)(po + 128 + oc0) = v1;
    }
  }
}

// ------------------------------------------------------------------ K-split combine (+bias+relu)
__global__ __launch_bounds__(256) void combine_k(const float* __restrict__ P,
    float* __restrict__ out, const float* __restrict__ bias,
    const int* __restrict__ nactp, int C, int S, int sliceStride) {
  int tg = blockIdx.x * 256 + threadIdx.x;
  int cg = C >> 2;
  int j = tg / cg, c4 = tg % cg;
  if (j >= nactp[0]) return;
  size_t o = (size_t)j * C + c4 * 4;
  float4 v = *(const float4*)(bias + c4 * 4);
  for (int s = 0; s < S; ++s) {
    float4 u = *(const float4*)(P + (size_t)s * sliceStride + o);
    v.x += u.x; v.y += u.y; v.z += u.z; v.w += u.w;
  }
  v.x = fmaxf(v.x, 0.f); v.y = fmaxf(v.y, 0.f);
  v.z = fmaxf(v.z, 0.f); v.w = fmaxf(v.w, 0.f);
  *(float4*)(out + o) = v;
}

// ------------------------------------------------------------------ compact 2x2 maxpool
__global__ __launch_bounds__(256) void pool_c_k(const float* __restrict__ inF,
    float* __restrict__ outF, const int* __restrict__ listC,
    const int* __restrict__ imF, const int* __restrict__ nactp, int Hf, int C) {
  int tg = blockIdx.x * 256 + threadIdx.x;
  int cg = C >> 2;
  int j = tg / cg, c4 = tg % cg;
  if (j >= nactp[0]) return;
  int code = listC[j];
  int b = code >> 20, Y = (code >> 10) & 1023, X = code & 1023;
  float4 v = make_float4(0.f, 0.f, 0.f, 0.f);
#pragma unroll
  for (int dy = 0; dy < 2; ++dy)
#pragma unroll
    for (int dx = 0; dx < 2; ++dx) {
      int ci = imF[((size_t)b * Hf + 2 * Y + dy) * Hf + 2 * X + dx];
      if (ci >= 0) {
        float4 u = *(const float4*)(inF + (size_t)ci * C + c4 * 4);
        v.x = fmaxf(v.x, u.x); v.y = fmaxf(v.y, u.y);
        v.z = fmaxf(v.z, u.z); v.w = fmaxf(v.w, u.w);
      }
    }
  *(float4*)(outF + (size_t)j * C + c4 * 4) = v;
}

// ------------------------------------------------------------------ final pool -> dense [2,512,16,16]
__global__ __launch_bounds__(256) void pool_d_k(const float* __restrict__ inF,
    float* __restrict__ outD, const int* __restrict__ im32) {
  int tg = blockIdx.x * 256 + threadIdx.x;  // 2*16*16*128 = 65536
  int c4 = tg & 127;
  int rest = tg >> 7;
  int X = rest & 15, Y = (rest >> 4) & 15, b = rest >> 8;
  float4 v = make_float4(0.f, 0.f, 0.f, 0.f);
#pragma unroll
  for (int dy = 0; dy < 2; ++dy)
#pragma unroll
    for (int dx = 0; dx < 2; ++dx) {
      int ci = im32[((size_t)b * 32 + 2 * Y + dy) * 32 + 2 * X + dx];
      if (ci >= 0) {
        float4 u = *(const float4*)(inF + (size_t)ci * 512 + c4 * 4);
        v.x = fmaxf(v.x, u.x); v.y = fmaxf(v.y, u.y);
        v.z = fmaxf(v.z, u.z); v.w = fmaxf(v.w, u.w);
      }
    }
  const float* pv = &v.x;
#pragma unroll
  for (int u = 0; u < 4; ++u) {
    int c = c4 * 4 + u;
    outD[(((size_t)b * 512 + c) * 16 + Y) * 16 + X] = pv[u];
  }
}

// ------------------------------------------------------------------ fully connected
template <bool RELU>
__global__ __launch_bounds__(256) void fc_k(const float* __restrict__ in,
                                            const float* __restrict__ w,
                                            const float* __restrict__ bias,
                                            float* __restrict__ out, int K,
                                            int R) {
  const int r = blockIdx.x;
  const int t = threadIdx.x;
  const float* wr = w + (size_t)r * K;
  float a0 = 0.f, a1 = 0.f;
  for (int k = t * 4; k < K; k += 1024) {
    float4 wv = *(const float4*)(wr + k);
    float4 x0 = *(const float4*)(in + k);
    float4 x1 = *(const float4*)(in + K + k);
    a0 += wv.x * x0.x + wv.y * x0.y + wv.z * x0.z + wv.w * x0.w;
    a1 += wv.x * x1.x + wv.y * x1.y + wv.z * x1.z + wv.w * x1.w;
  }
#pragma unroll
  for (int off = 32; off > 0; off >>= 1) {
    a0 += __shfl_down(a0, off);
    a1 += __shfl_down(a1, off);
  }
  __shared__ float s0[4], s1[4];
  const int lane = t & 63, wid = t >> 6;
  if (lane == 0) { s0[wid] = a0; s1[wid] = a1; }
  __syncthreads();
  if (t == 0) {
    float v0 = s0[0] + s0[1] + s0[2] + s0[3] + bias[r];
    float v1 = s1[0] + s1[1] + s1[2] + s1[3] + bias[r];
    if (RELU) { v0 = fmaxf(v0, 0.f); v1 = fmaxf(v1, 0.f); }
    out[r] = v0;
    out[R + r] = v1;
  }
}

// ------------------------------------------------------------------ launch
extern "C" void kernel_launch(void* const* d_in, const int* in_sizes, int n_in,
                              void* d_out, int out_size, void* d_ws,
                              size_t ws_size, hipStream_t stream) {
  (void)in_sizes; (void)n_in; (void)out_size; (void)ws_size;
  const float* x = (const float*)d_in[0];
  const float* Wc[14];
  const float* Bc[14];
  for (int i = 1; i <= 13; ++i) {
    Wc[i] = (const float*)d_in[2 * i - 1];
    Bc[i] = (const float*)d_in[2 * i];
  }
  const float* fw1 = (const float*)d_in[27];
  const float* fb1 = (const float*)d_in[28];
  const float* fw2 = (const float*)d_in[29];
  const float* fb2 = (const float*)d_in[30];
  const float* fw3 = (const float*)d_in[31];
  const float* fb3 = (const float*)d_in[32];
  const float* fw4 = (const float*)d_in[33];
  const float* fb4 = (const float*)d_in[34];

  static const int CH[14] = {1, 64, 64, 128, 128, 256, 256, 256,
                             512, 512, 512, 512, 512, 512};

  char* ws = (char*)d_ws;
  size_t cur = 0;
  auto alloc = [&](size_t bytes) {
    size_t o = cur;
    cur += (bytes + 255) & ~(size_t)255;
    return o;
  };
  // weight transposes
  size_t wtOff[14];
  for (int i = 1; i <= 13; ++i)
    wtOff[i] = alloc((size_t)CH[i] * CH[i - 1] * 9 * 4);
  float* wT[14];
  for (int i = 1; i <= 13; ++i) wT[i] = (float*)(ws + wtOff[i]);
  // features. Praw (K-split partials) aliases the contiguous dead arena
  // starting at A1 (see r8 notes; all partial sets fit the dead region).
  float* F0  = (float*)(ws + alloc((size_t)NMAX512 * 1 * 4));
  size_t a1Off = alloc((size_t)NMAX512 * 64 * 4);
  float* A1  = (float*)(ws + a1Off);
  float* Praw = A1;  // aliased K-split partial buffer
  float* A2  = (float*)(ws + alloc((size_t)NMAX512 * 64 * 4));
  float* P2  = (float*)(ws + alloc((size_t)NMAX256 * 64 * 4));
  float* A3  = (float*)(ws + alloc((size_t)NMAX256 * 128 * 4));
  float* A4  = (float*)(ws + alloc((size_t)NMAX256 * 128 * 4));
  float* P4  = (float*)(ws + alloc((size_t)NMAX128 * 128 * 4));
  float* A5  = (float*)(ws + alloc((size_t)NMAX128 * 256 * 4));
  float* A6  = (float*)(ws + alloc((size_t)NMAX128 * 256 * 4));
  float* P7  = (float*)(ws + alloc((size_t)NMAX64 * 256 * 4));
  float* A8  = (float*)(ws + alloc((size_t)NMAX64 * 512 * 4));
  float* A9  = (float*)(ws + alloc((size_t)NMAX64 * 512 * 4));
  float* P10 = (float*)(ws + alloc((size_t)NMAX32 * 512 * 4));
  float* A11 = (float*)(ws + alloc((size_t)NMAX32 * 512 * 4));
  float* A12 = (float*)(ws + alloc((size_t)NMAX32 * 512 * 4));
  float* D13 = (float*)(ws + alloc((size_t)NB * 512 * 16 * 16 * 4));
  float* F1  = (float*)(ws + alloc(NB * 1024 * 4));
  float* F2  = (float*)(ws + alloc(NB * 512 * 4));
  float* F3  = (float*)(ws + alloc(NB * 256 * 4));
  // index maps / lists / neighbor tables / counters
  int* im512 = (int*)(ws + alloc((size_t)NB * 512 * 512 * 4));
  int* im256 = (int*)(ws + alloc((size_t)NB * 256 * 256 * 4));
  int* im128 = (int*)(ws + alloc((size_t)NB * 128 * 128 * 4));
  int* im64  = (int*)(ws + alloc((size_t)NB * 64 * 64 * 4));
  int* im32  = (int*)(ws + alloc((size_t)NB * 32 * 32 * 4));
  int* l512 = (int*)(ws + alloc((size_t)NMAX512 * 4));
  int* l256 = (int*)(ws + alloc((size_t)NMAX256 * 4));
  int* l128 = (int*)(ws + alloc((size_t)NMAX128 * 4));
  int* l64  = (int*)(ws + alloc((size_t)NMAX64 * 4));
  int* l32  = (int*)(ws + alloc((size_t)NMAX32 * 4));
  int* nb512 = (int*)(ws + alloc((size_t)9 * NMAX512 * 4));
  int* nb256 = (int*)(ws + alloc((size_t)9 * NMAX256 * 4));
  int* nb128 = (int*)(ws + alloc((size_t)9 * NMAX128 * 4));
  int* nb64  = (int*)(ws + alloc((size_t)9 * NMAX64 * 4));
  int* nb32  = (int*)(ws + alloc((size_t)9 * NMAX32 * 4));
  int* nact = (int*)(ws + alloc(256));  // [0..4] per-resolution counts

  const dim3 blk(256);
  hipMemsetAsync(nact, 0, 32, stream);

  // ---- lists / index maps / neighbors
  hipLaunchKernelGGL(build_l0_k, dim3(2048), blk, 0, stream, x, l512, im512, F0, nact + 0, NB * 512 * 512, NMAX512);
  hipLaunchKernelGGL(build_pl_k, dim3(512), blk, 0, stream, im512, l256, im256, nact + 1, 256, NMAX256);
  hipLaunchKernelGGL(build_pl_k, dim3(128), blk, 0, stream, im256, l128, im128, nact + 2, 128, NMAX128);
  hipLaunchKernelGGL(build_pl_k, dim3(32), blk, 0, stream, im128, l64, im64, nact + 3, 64, NMAX64);
  hipLaunchKernelGGL(build_pl_k, dim3(8), blk, 0, stream, im64, l32, im32, nact + 4, 32, NMAX32);
  hipLaunchKernelGGL(build_nbr_k, dim3(NMAX512 / 256), blk, 0, stream, l512, im512, nact + 0, nb512, 512, NMAX512);
  hipLaunchKernelGGL(build_nbr_k, dim3(NMAX256 / 256), blk, 0, stream, l256, im256, nact + 1, nb256, 256, NMAX256);
  hipLaunchKernelGGL(build_nbr_k, dim3(NMAX128 / 256), blk, 0, stream, l128, im128, nact + 2, nb128, 128, NMAX128);
  hipLaunchKernelGGL(build_nbr_k, dim3(NMAX64 / 256), blk, 0, stream, l64, im64, nact + 3, nb64, 64, NMAX64);
  hipLaunchKernelGGL(build_nbr_k, dim3(NMAX32 / 256), blk, 0, stream, l32, im32, nact + 4, nb32, 32, NMAX32);

  // ---- weight transposes: w[Cout][Cin*9] -> wT[Cin*9][Cout]
  for (int i = 1; i <= 13; ++i) {
    int R = CH[i], C = CH[i - 1] * 9;
    hipLaunchKernelGGL(transpose_k, dim3((C + 31) / 32, (R + 31) / 32), blk, 0,
                       stream, Wc[i], wT[i], R, C);
  }

  // ---- convs
  // L1: 1->64 @512
  hipLaunchKernelGGL((gconv_k<1, 64, 64, 4, 4, false>), dim3(512, 1, 1), blk, 0, stream,
                     F0, A1, wT[1], Bc[1], nb512, nact + 0, 1, 64, NMAX512, 1, 1);
  // L2: 64->64 @512
  hipLaunchKernelGGL((gconv_k<8, 64, 64, 4, 4, false>), dim3(512, 1, 1), blk, 0, stream,
                     A1, A2, wT[2], Bc[2], nb512, nact + 0, 64, 64, NMAX512, 64, 1);
  hipLaunchKernelGGL(pool_c_k, dim3(NMAX256 * 16 / 256), blk, 0, stream, A2, P2, l256, im512, nact + 1, 512, 64);
  // L3: 64->128 @256
  hipLaunchKernelGGL((gconv_k<8, 64, 128, 4, 8, false>), dim3(448, 1, 1), blk, 0, stream,
                     P2, A3, wT[3], Bc[3], nb256, nact + 1, 64, 128, NMAX256, 64, 1);
  // L4: 128->128 @256
  hipLaunchKernelGGL((gconv_k<8, 64, 128, 4, 8, false>), dim3(448, 1, 1), blk, 0, stream,
                     A3, A4, wT[4], Bc[4], nb256, nact + 1, 128, 128, NMAX256, 128, 1);
  hipLaunchKernelGGL(pool_c_k, dim3(NMAX128 * 32 / 256), blk, 0, stream, A4, P4, l128, im256, nact + 2, 256, 128);

  // L5-L13: 256-thread 8x8 kernel (SITES=64, OCB=256, CC=4), K-split -> Praw + combine
  const int SL128 = NMAX128 * 256;  // slice stride (floats), res128 layers
  const int SL64  = NMAX64 * 512;   // res64 layers
  const int SL32  = NMAX32 * 512;   // res32 layers
  // L5: 128->256 @128, z=2 (cinCnt=64)
  hipLaunchKernelGGL((gconv8_k<true>), dim3(320, 1, 2), blk, 0, stream,
                     P4, Praw, wT[5], nullptr, nb128, nact + 2, 128, 256, NMAX128, 64, 1);
  hipLaunchKernelGGL(combine_k, dim3(NMAX128 * 64 / 256), blk, 0, stream, Praw, A5, Bc[5], nact + 2, 256, 2, SL128);
  // L6: 256->256 @128, z=2 (cinCnt=128)
  hipLaunchKernelGGL((gconv8_k<true>), dim3(320, 1, 2), blk, 0, stream,
                     A5, Praw, wT[6], nullptr, nb128, nact + 2, 256, 256, NMAX128, 128, 1);
  hipLaunchKernelGGL(combine_k, dim3(NMAX128 * 64 / 256), blk, 0, stream, Praw, A6, Bc[6], nact + 2, 256, 2, SL128);
  // L7: 256->256 @128, z=2
  hipLaunchKernelGGL((gconv8_k<true>), dim3(320, 1, 2), blk, 0, stream,
                     A6, Praw, wT[7], nullptr, nb128, nact + 2, 256, 256, NMAX128, 128, 1);
  hipLaunchKernelGGL(combine_k, dim3(NMAX128 * 64 / 256), blk, 0, stream, Praw, A5, Bc[7], nact + 2, 256, 2, SL128);
  hipLaunchKernelGGL(pool_c_k, dim3(NMAX64 * 64 / 256), blk, 0, stream, A5, P7, l64, im128, nact + 3, 128, 256);
  // L8: 256->512 @64, z=4 (cinCnt=64)
  hipLaunchKernelGGL((gconv8_k<true>), dim3(256, 1, 4), blk, 0, stream,
                     P7, Praw, wT[8], nullptr, nb64, nact + 3, 256, 512, NMAX64, 64, 2);
  hipLaunchKernelGGL(combine_k, dim3(NMAX64 * 128 / 256), blk, 0, stream, Praw, A8, Bc[8], nact + 3, 512, 4, SL64);
  // L9: 512->512 @64, z=4 (cinCnt=128)
  hipLaunchKernelGGL((gconv8_k<true>), dim3(256, 1, 4), blk, 0, stream,
                     A8, Praw, wT[9], nullptr, nb64, nact + 3, 512, 512, NMAX64, 128, 2);
  hipLaunchKernelGGL(combine_k, dim3(NMAX64 * 128 / 256), blk, 0, stream, Praw, A9, Bc[9], nact + 3, 512, 4, SL64);
  // L10: 512->512 @64, z=4
  hipLaunchKernelGGL((gconv8_k<true>), dim3(256, 1, 4), blk, 0, stream,
                     A9, Praw, wT[10], nullptr, nb64, nact + 3, 512, 512, NMAX64, 128, 2);
  hipLaunchKernelGGL(combine_k, dim3(NMAX64 * 128 / 256), blk, 0, stream, Praw, A8, Bc[10], nact + 3, 512, 4, SL64);
  hipLaunchKernelGGL(pool_c_k, dim3(NMAX32 * 128 / 256), blk, 0, stream, A8, P10, l32, im64, nact + 4, 64, 512);
  // L11-13: 512->512 @32, z=8 (cinCnt=64)
  hipLaunchKernelGGL((gconv8_k<true>), dim3(64, 1, 8), blk, 0, stream,
                     P10, Praw, wT[11], nullptr, nb32, nact + 4, 512, 512, NMAX32, 64, 2);
  hipLaunchKernelGGL(combine_k, dim3(NMAX32 * 128 / 256), blk, 0, stream, Praw, A11, Bc[11], nact + 4, 512, 8, SL32);
  hipLaunchKernelGGL((gconv8_k<true>), dim3(64, 1, 8), blk, 0, stream,
                     A11, Praw, wT[12], nullptr, nb32, nact + 4, 512, 512, NMAX32, 64, 2);
  hipLaunchKernelGGL(combine_k, dim3(NMAX32 * 128 / 256), blk, 0, stream, Praw, A12, Bc[12], nact + 4, 512, 8, SL32);
  hipLaunchKernelGGL((gconv8_k<true>), dim3(64, 1, 8), blk, 0, stream,
                     A12, Praw, wT[13], nullptr, nb32, nact + 4, 512, 512, NMAX32, 64, 2);
  hipLaunchKernelGGL(combine_k, dim3(NMAX32 * 128 / 256), blk, 0, stream, Praw, A11, Bc[13], nact + 4, 512, 8, SL32);
  // final pool -> dense
  hipLaunchKernelGGL(pool_d_k, dim3(256), blk, 0, stream, A11, D13, im32);

  // ---- MLP
  hipLaunchKernelGGL((fc_k<true>), dim3(1024), blk, 0, stream, D13, fw1, fb1, F1, 131072, 1024);
  hipLaunchKernelGGL((fc_k<true>), dim3(512), blk, 0, stream, F1, fw2, fb2, F2, 1024, 512);
  hipLaunchKernelGGL((fc_k<true>), dim3(256), blk, 0, stream, F2, fw3, fb3, F3, 512, 256);
  hipLaunchKernelGGL((fc_k<false>), dim3(2), blk, 0, stream, F3, fw4, fb4, (float*)d_out, 256, 2);
}

// Round 10
// 2937.637 us; speedup vs baseline: 2.3565x; 1.0272x over previous
//
#include <hip/hip_runtime.h>
#include <hip/hip_bf16.h>
#include <cstddef>
#include <cstdint>

#define NB 2

#define NMAX512 32768
#define NMAX256 28672
#define NMAX128 20480
#define NMAX64  8192
#define NMAX32  2048

typedef __attribute__((ext_vector_type(8))) short bf8v;   // 8 bf16 = 4 VGPR
typedef __attribute__((ext_vector_type(4))) float f32x4;

static __device__ __forceinline__ unsigned short f2bf(float x) {
  __hip_bfloat16 h = __float2bfloat16(x);
  return *reinterpret_cast<unsigned short*>(&h);
}
static __device__ __forceinline__ float bf2f(unsigned short u) {
  __hip_bfloat16 h;
  *reinterpret_cast<unsigned short*>(&h) = u;
  return __bfloat162float(h);
}

// ------------------------------------------------------------------ list build (res 512 from x, Cin=1)
__global__ __launch_bounds__(256) void build_l0_k(const float* __restrict__ x,
    int* __restrict__ list, int* __restrict__ im, float* __restrict__ f0,
    int* __restrict__ nact, int total, int nmax) {
  int i = blockIdx.x * 256 + threadIdx.x;
  bool act = false;
  float v = 0.f;
  if (i < total) { v = x[i]; act = (v != 0.f); }
  unsigned long long mb = __ballot(act);
  int lane = threadIdx.x & 63;
  int prefix = __popcll(mb & ((1ull << lane) - 1));
  int base = 0;
  if (lane == 0) base = atomicAdd(nact, __popcll(mb));
  base = __shfl(base, 0);
  if (i < total) {
    int idx = act ? (base + prefix) : -1;
    if (idx >= nmax) idx = -1;
    im[i] = idx;
    if (idx >= 0) {
      int b = i >> 18;
      int rem = i & 262143;
      list[idx] = (b << 20) | ((rem >> 9) << 10) | (rem & 511);
      f0[idx] = v;
    }
  }
}

// ------------------------------------------------------------------ pooled list from finer idxmap
__global__ __launch_bounds__(256) void build_pl_k(const int* __restrict__ imF,
    int* __restrict__ list, int* __restrict__ im, int* __restrict__ nact,
    int Hc, int nmax) {
  int total = NB * Hc * Hc;
  int i = blockIdx.x * 256 + threadIdx.x;
  bool act = false;
  int b = 0, y = 0, x = 0;
  int Hf = Hc * 2;
  if (i < total) {
    x = i % Hc; y = (i / Hc) % Hc; b = i / (Hc * Hc);
    const int* p = imF + ((size_t)b * Hf + 2 * y) * Hf + 2 * x;
    act = (p[0] >= 0) || (p[1] >= 0) || (p[Hf] >= 0) || (p[Hf + 1] >= 0);
  }
  unsigned long long mb = __ballot(act);
  int lane = threadIdx.x & 63;
  int prefix = __popcll(mb & ((1ull << lane) - 1));
  int base = 0;
  if (lane == 0) base = atomicAdd(nact, __popcll(mb));
  base = __shfl(base, 0);
  if (i < total) {
    int idx = act ? (base + prefix) : -1;
    if (idx >= nmax) idx = -1;
    im[i] = idx;
    if (idx >= 0) list[idx] = (b << 20) | (y << 10) | x;
  }
}

// ------------------------------------------------------------------ 9-neighbor index table
__global__ __launch_bounds__(256) void build_nbr_k(const int* __restrict__ list,
    const int* __restrict__ im, const int* __restrict__ nactp,
    int* __restrict__ nbr, int H, int nmax) {
  int i = blockIdx.x * 256 + threadIdx.x;
  if (i >= nactp[0]) return;
  int code = list[i];
  int b = code >> 20, y = (code >> 10) & 1023, x = code & 1023;
#pragma unroll
  for (int k = 0; k < 9; ++k) {
    int yy = y + k / 3 - 1, xx = x + k % 3 - 1;
    int v = -1;
    if (yy >= 0 && yy < H && xx >= 0 && xx < H)
      v = im[((size_t)b * H + yy) * H + xx];
    nbr[k * nmax + i] = v;
  }
}

// ------------------------------------------------------------------ weight transpose  [R][C] -> [C][R]   (L1-L4 fp32 path)
__global__ __launch_bounds__(256) void transpose_k(const float* __restrict__ in,
                                                   float* __restrict__ out,
                                                   int R, int C) {
  __shared__ float tile[32][33];
  int bx = blockIdx.x * 32;
  int by = blockIdx.y * 32;
  int tx = threadIdx.x % 32, ty0 = threadIdx.x / 32;
  for (int ty = ty0; ty < 32; ty += 8) {
    int r = by + ty, c = bx + tx;
    tile[ty][tx] = (r < R && c < C) ? in[(size_t)r * C + c] : 0.f;
  }
  __syncthreads();
  for (int ty = ty0; ty < 32; ty += 8) {
    int r = bx + ty, c = by + tx;
    if (r < C && c < R) out[(size_t)r * R + c] = tile[tx][ty];
  }
}

// ------------------------------------------------------------------ weight bf16x3 split  w[Cout][Cin][9] -> wx[p][k][oc][cin]
__global__ __launch_bounds__(256) void wprep_k(const float* __restrict__ w,
                                               unsigned short* __restrict__ wx,
                                               int Cout, int Cin) {
  int i = blockIdx.x * 256 + threadIdx.x;
  if (i >= Cout * Cin) return;
  int oc = i / Cin, ci = i - oc * Cin;
  const float* src = w + ((size_t)oc * Cin + ci) * 9;
  const size_t sk = (size_t)Cout * Cin;
#pragma unroll
  for (int k = 0; k < 9; ++k) {
    float x = src[k];
    unsigned short h = f2bf(x);
    float r1 = x - bf2f(h);
    unsigned short m = f2bf(r1);
    float r2 = r1 - bf2f(m);
    wx[(size_t)k * sk + i] = h;
    wx[(size_t)(9 + k) * sk + i] = m;
    wx[(size_t)(18 + k) * sk + i] = f2bf(r2);
  }
}

// ------------------------------------------------------------------ gather-GEMM fp32 (256 thr, 4x8; L1-L4 only)
template <int CC, int SITES, int OCB, int SPT, int OPT>
__global__ __launch_bounds__(256, 2) void gconv_k(
    const float* __restrict__ in, float* __restrict__ out,
    const float* __restrict__ wT, const float* __restrict__ bias,
    const int* __restrict__ nbr, const int* __restrict__ nactp,
    int Cin, int Cout, int Nmax, int cinCnt, int nocb) {
  constexpr int KSL = CC * 9;
  __shared__ int s_nbr[9][SITES];
  __shared__ float s_a[KSL][SITES];
  __shared__ float s_w[KSL][OCB];
  const int n = nactp[0];
  const int gid = blockIdx.x;
  const int xcd = gid & 7;
  const int pos = gid >> 3;
  const int ocbI = pos % nocb;
  const int sb = (pos / nocb) * 8 + xcd;
  const int base = sb * SITES;
  if (base >= n) return;
  const int ocb = ocbI * OCB;
  const int t = threadIdx.x;
  for (int s = t; s < 9 * SITES; s += 256) {
    int i = s % SITES, k = s / SITES;
    int gi = base + i;
    s_nbr[k][i] = (gi < n) ? nbr[k * Nmax + gi] : -1;
  }
  constexpr int OCG = OCB / OPT;
  const int oc0 = (t % OCG) * 4;
  const int si0 = (t / OCG) * SPT;
  float acc[SPT][OPT];
#pragma unroll
  for (int a = 0; a < SPT; ++a)
#pragma unroll
    for (int j = 0; j < OPT; ++j) acc[a][j] = 0.f;
  __syncthreads();
  const int nch = cinCnt / CC;
  for (int ch = 0; ch < nch; ++ch) {
    const int c0 = ch * CC;
    const float* wrow = wT + ((size_t)c0 * 9) * Cout + ocb;
    for (int s = t; s < KSL * (OCB / 4); s += 256) {
      int j4 = s % (OCB / 4), r = s / (OCB / 4);
      *(float4*)&s_w[r][j4 * 4] = *(const float4*)(wrow + (size_t)r * Cout + j4 * 4);
    }
    if constexpr (CC == 1) {
      for (int s = t; s < 9 * SITES; s += 256) {
        int i = s % SITES, k = s / SITES;
        int row = s_nbr[k][i];
        s_a[k][i] = (row >= 0) ? in[row] : 0.f;
      }
    } else {
      constexpr int H4 = CC / 4;
      for (int s = t; s < H4 * 9 * SITES; s += 256) {
        int i = s % SITES, m = s / SITES;
        int c4 = m % H4, k = m / H4;
        int row = s_nbr[k][i];
        float4 v = make_float4(0.f, 0.f, 0.f, 0.f);
        if (row >= 0)
          v = *(const float4*)(in + (size_t)row * Cin + c0 + c4 * 4);
        s_a[(c4 * 4 + 0) * 9 + k][i] = v.x;
        s_a[(c4 * 4 + 1) * 9 + k][i] = v.y;
        s_a[(c4 * 4 + 2) * 9 + k][i] = v.z;
        s_a[(c4 * 4 + 3) * 9 + k][i] = v.w;
      }
    }
    __syncthreads();
#pragma unroll
    for (int kk = 0; kk < KSL; ++kk) {
      float av[SPT];
      if constexpr (SPT == 4) {
        float4 a4 = *(const float4*)&s_a[kk][si0];
        av[0] = a4.x; av[1] = a4.y; av[2] = a4.z; av[3] = a4.w;
      } else {
        float2 a2 = *(const float2*)&s_a[kk][si0];
        av[0] = a2.x; av[1] = a2.y;
      }
      float wv[OPT];
      if constexpr (OPT == 8) {
        float4 w4a = *(const float4*)&s_w[kk][oc0];
        float4 w4b = *(const float4*)&s_w[kk][OCB / 2 + oc0];
        wv[0] = w4a.x; wv[1] = w4a.y; wv[2] = w4a.z; wv[3] = w4a.w;
        wv[4] = w4b.x; wv[5] = w4b.y; wv[6] = w4b.z; wv[7] = w4b.w;
      } else {
        float4 w4 = *(const float4*)&s_w[kk][oc0];
        wv[0] = w4.x; wv[1] = w4.y; wv[2] = w4.z; wv[3] = w4.w;
      }
#pragma unroll
      for (int a = 0; a < SPT; ++a)
#pragma unroll
        for (int j = 0; j < OPT; ++j)
          acc[a][j] = fmaf(av[a], wv[j], acc[a][j]);
    }
    __syncthreads();
  }
  float bz[OPT];
#pragma unroll
  for (int j = 0; j < OPT; ++j) {
    int oj = (OPT == 8) ? ((j < 4) ? (oc0 + j) : (OCB / 2 + oc0 + j - 4))
                        : (oc0 + j);
    bz[j] = bias[ocb + oj];
  }
#pragma unroll
  for (int a = 0; a < SPT; ++a) {
    int gi = base + si0 + a;
    if (gi < n) {
      float* po = out + (size_t)gi * Cout + ocb;
      if constexpr (OPT == 8) {
        float4 v0, v1;
        v0.x = fmaxf(acc[a][0] + bz[0], 0.f); v0.y = fmaxf(acc[a][1] + bz[1], 0.f);
        v0.z = fmaxf(acc[a][2] + bz[2], 0.f); v0.w = fmaxf(acc[a][3] + bz[3], 0.f);
        v1.x = fmaxf(acc[a][4] + bz[4], 0.f); v1.y = fmaxf(acc[a][5] + bz[5], 0.f);
        v1.z = fmaxf(acc[a][6] + bz[6], 0.f); v1.w = fmaxf(acc[a][7] + bz[7], 0.f);
        *(float4*)(po + oc0) = v0;
        *(float4*)(po + OCB / 2 + oc0) = v1;
      } else {
        float4 v;
        v.x = fmaxf(acc[a][0] + bz[0], 0.f); v.y = fmaxf(acc[a][1] + bz[1], 0.f);
        v.z = fmaxf(acc[a][2] + bz[2], 0.f); v.w = fmaxf(acc[a][3] + bz[3], 0.f);
        *(float4*)(po + oc0) = v;
      }
    }
  }
}

// ------------------------------------------------------------------ bf16x3 MFMA gather-GEMM (L5-L13)
// Block: 64 sites x 128 oc, 256 thr = 4 waves; wave = 2 M-tiles x 4 N-tiles
// of 16x16. K-step = 32 channels of one tap. acc f32 via
// mfma_f32_16x16x32_bf16; 6 MFMAs reconstruct fp32 product (bf16x3 split).
// LDS rows padded to 40 elems (80 B): keeps b128 16B-aligned, banks <=2-way.
// C/D layout (verified m89/m91): col=lane&15, row=(lane>>4)*4+reg.
template <bool RAW>
__global__ __launch_bounds__(256) void gmfma_k(
    const unsigned short* __restrict__ AH, const unsigned short* __restrict__ AM,
    const unsigned short* __restrict__ AL, float* __restrict__ out,
    unsigned short* __restrict__ OH, unsigned short* __restrict__ OM,
    unsigned short* __restrict__ OL, const unsigned short* __restrict__ WX,
    const float* __restrict__ bias, const int* __restrict__ nbr,
    const int* __restrict__ nactp, int Cin, int Cout, int Nmax, int cinCnt,
    int nocb) {
  constexpr int PAD = 40;
  __shared__ int s_nbr[9][64];
  __shared__ __align__(16) unsigned short s_a[3][64][PAD];
  __shared__ __align__(16) unsigned short s_w[3][128][PAD];
  const int n = nactp[0];
  const int gid = blockIdx.x;
  const int xcd = gid & 7, pos = gid >> 3;
  const int ocbI = pos % nocb;
  const int sb = (pos / nocb) * 8 + xcd;
  const int base = sb * 64;
  if (base >= n) return;
  const int ocb = ocbI * 128;
  const int t = threadIdx.x;
  for (int s = t; s < 576; s += 256) {
    int i = s & 63, k = s >> 6;
    s_nbr[k][i] = (base + i < n) ? nbr[k * Nmax + base + i] : -1;
  }
  const int w = t >> 6, l = t & 63;
  const int fr = l & 15;
  const int fkb = (l >> 4) * 16;      // byte offset of this lane's k-slice
  const int mtb = (w & 1) * 2;        // 2 M-tiles per wave
  const int ntb = (w >> 1) * 4;       // 4 N-tiles per wave
  f32x4 acc[2][4];
#pragma unroll
  for (int a = 0; a < 2; ++a)
#pragma unroll
    for (int b = 0; b < 4; ++b) acc[a][b] = (f32x4){0.f, 0.f, 0.f, 0.f};
  __syncthreads();
  const int cinStart = RAW ? (blockIdx.z * cinCnt) : 0;
  const int nchunk = cinCnt >> 5;
  for (int k = 0; k < 9; ++k) {
    for (int cc = 0; cc < nchunk; ++cc) {
      const int c0 = cinStart + (cc << 5);
      // stage W: 3 pieces x 128 oc rows x 32 kk (4 x b128 per row)
      for (int r = t; r < 1536; r += 256) {
        int p = r >> 9, rem = r & 511;
        int oc = rem >> 2, q = rem & 3;
        float4 v = *(const float4*)(WX +
            ((size_t)((p * 9 + k) * Cout + ocb + oc)) * Cin + c0 + q * 8);
        *(float4*)&s_w[p][oc][q * 8] = v;
      }
      // stage A: 3 pieces x 64 site rows x 32 ch
      for (int r = t; r < 768; r += 256) {
        int p = r >> 8, rem = r & 255;
        int si = rem >> 2, q = rem & 3;
        const unsigned short* Ap = (p == 0) ? AH : ((p == 1) ? AM : AL);
        int row = s_nbr[k][si];
        float4 v = make_float4(0.f, 0.f, 0.f, 0.f);
        if (row >= 0)
          v = *(const float4*)(Ap + (size_t)row * Cin + c0 + q * 8);
        *(float4*)&s_a[p][si][q * 8] = v;
      }
      __syncthreads();
      bf8v af[2][3], wf[4][3];
#pragma unroll
      for (int mi = 0; mi < 2; ++mi)
#pragma unroll
        for (int p = 0; p < 3; ++p)
          af[mi][p] = *(const bf8v*)((const char*)&s_a[p][(mtb + mi) * 16 + fr][0] + fkb);
#pragma unroll
      for (int ni = 0; ni < 4; ++ni)
#pragma unroll
        for (int p = 0; p < 3; ++p)
          wf[ni][p] = *(const bf8v*)((const char*)&s_w[p][(ntb + ni) * 16 + fr][0] + fkb);
#pragma unroll
      for (int mi = 0; mi < 2; ++mi)
#pragma unroll
        for (int ni = 0; ni < 4; ++ni) {
          f32x4 c = acc[mi][ni];
          c = __builtin_amdgcn_mfma_f32_16x16x32_bf16(af[mi][0], wf[ni][0], c, 0, 0, 0);
          c = __builtin_amdgcn_mfma_f32_16x16x32_bf16(af[mi][0], wf[ni][1], c, 0, 0, 0);
          c = __builtin_amdgcn_mfma_f32_16x16x32_bf16(af[mi][1], wf[ni][0], c, 0, 0, 0);
          c = __builtin_amdgcn_mfma_f32_16x16x32_bf16(af[mi][1], wf[ni][1], c, 0, 0, 0);
          c = __builtin_amdgcn_mfma_f32_16x16x32_bf16(af[mi][0], wf[ni][2], c, 0, 0, 0);
          c = __builtin_amdgcn_mfma_f32_16x16x32_bf16(af[mi][2], wf[ni][0], c, 0, 0, 0);
          acc[mi][ni] = c;
        }
      __syncthreads();
    }
  }
  float* ob = out;
  if constexpr (RAW) ob += (size_t)blockIdx.z * Nmax * Cout;
#pragma unroll
  for (int mi = 0; mi < 2; ++mi) {
    const int rbase = base + (mtb + mi) * 16 + (l >> 4) * 4;
#pragma unroll
    for (int ni = 0; ni < 4; ++ni) {
      const int oc = ocb + (ntb + ni) * 16 + fr;
      float bz = 0.f;
      if constexpr (!RAW) bz = bias[oc];
#pragma unroll
      for (int reg = 0; reg < 4; ++reg) {
        const int gi = rbase + reg;
        if (gi < n) {
          const size_t idx = (size_t)gi * Cout + oc;
          if constexpr (RAW) {
            ob[idx] = acc[mi][ni][reg];
          } else {
            float y = fmaxf(acc[mi][ni][reg] + bz, 0.f);
            ob[idx] = y;
            if (OH) {
              unsigned short h = f2bf(y);
              float r1 = y - bf2f(h);
              unsigned short m2 = f2bf(r1);
              float r2 = r1 - bf2f(m2);
              OH[idx] = h; OM[idx] = m2; OL[idx] = f2bf(r2);
            }
          }
        }
      }
    }
  }
}

// ------------------------------------------------------------------ K-split combine (+bias+relu, optional bf16x3 planes)
__global__ __launch_bounds__(256) void combine_k(const float* __restrict__ P,
    float* __restrict__ out, const float* __restrict__ bias,
    const int* __restrict__ nactp, int C, int S, int sliceStride,
    unsigned short* __restrict__ oh, unsigned short* __restrict__ om,
    unsigned short* __restrict__ ol) {
  int tg = blockIdx.x * 256 + threadIdx.x;
  int cg = C >> 2;
  int j = tg / cg, c4 = tg % cg;
  if (j >= nactp[0]) return;
  size_t o = (size_t)j * C + c4 * 4;
  float4 v = *(const float4*)(bias + c4 * 4);
  for (int s = 0; s < S; ++s) {
    float4 u = *(const float4*)(P + (size_t)s * sliceStride + o);
    v.x += u.x; v.y += u.y; v.z += u.z; v.w += u.w;
  }
  v.x = fmaxf(v.x, 0.f); v.y = fmaxf(v.y, 0.f);
  v.z = fmaxf(v.z, 0.f); v.w = fmaxf(v.w, 0.f);
  *(float4*)(out + o) = v;
  if (oh) {
    const float* pv = &v.x;
#pragma unroll
    for (int u = 0; u < 4; ++u) {
      float y = pv[u];
      unsigned short h = f2bf(y);
      float r1 = y - bf2f(h);
      unsigned short m2 = f2bf(r1);
      float r2 = r1 - bf2f(m2);
      oh[o + u] = h; om[o + u] = m2; ol[o + u] = f2bf(r2);
    }
  }
}

// ------------------------------------------------------------------ compact 2x2 maxpool (optional bf16x3 planes)
__global__ __launch_bounds__(256) void pool_c_k(const float* __restrict__ inF,
    float* __restrict__ outF, const int* __restrict__ listC,
    const int* __restrict__ imF, const int* __restrict__ nactp, int Hf, int C,
    unsigned short* __restrict__ oh, unsigned short* __restrict__ om,
    unsigned short* __restrict__ ol) {
  int tg = blockIdx.x * 256 + threadIdx.x;
  int cg = C >> 2;
  int j = tg / cg, c4 = tg % cg;
  if (j >= nactp[0]) return;
  int code = listC[j];
  int b = code >> 20, Y = (code >> 10) & 1023, X = code & 1023;
  float4 v = make_float4(0.f, 0.f, 0.f, 0.f);
#pragma unroll
  for (int dy = 0; dy < 2; ++dy)
#pragma unroll
    for (int dx = 0; dx < 2; ++dx) {
      int ci = imF[((size_t)b * Hf + 2 * Y + dy) * Hf + 2 * X + dx];
      if (ci >= 0) {
        float4 u = *(const float4*)(inF + (size_t)ci * C + c4 * 4);
        v.x = fmaxf(v.x, u.x); v.y = fmaxf(v.y, u.y);
        v.z = fmaxf(v.z, u.z); v.w = fmaxf(v.w, u.w);
      }
    }
  size_t o = (size_t)j * C + c4 * 4;
  *(float4*)(outF + o) = v;
  if (oh) {
    const float* pv = &v.x;
#pragma unroll
    for (int u = 0; u < 4; ++u) {
      float y = pv[u];
      unsigned short h = f2bf(y);
      float r1 = y - bf2f(h);
      unsigned short m2 = f2bf(r1);
      float r2 = r1 - bf2f(m2);
      oh[o + u] = h; om[o + u] = m2; ol[o + u] = f2bf(r2);
    }
  }
}

// ------------------------------------------------------------------ final pool -> dense [2,512,16,16]
__global__ __launch_bounds__(256) void pool_d_k(const float* __restrict__ inF,
    float* __restrict__ outD, const int* __restrict__ im32) {
  int tg = blockIdx.x * 256 + threadIdx.x;
  int c4 = tg & 127;
  int rest = tg >> 7;
  int X = rest & 15, Y = (rest >> 4) & 15, b = rest >> 8;
  float4 v = make_float4(0.f, 0.f, 0.f, 0.f);
#pragma unroll
  for (int dy = 0; dy < 2; ++dy)
#pragma unroll
    for (int dx = 0; dx < 2; ++dx) {
      int ci = im32[((size_t)b * 32 + 2 * Y + dy) * 32 + 2 * X + dx];
      if (ci >= 0) {
        float4 u = *(const float4*)(inF + (size_t)ci * 512 + c4 * 4);
        v.x = fmaxf(v.x, u.x); v.y = fmaxf(v.y, u.y);
        v.z = fmaxf(v.z, u.z); v.w = fmaxf(v.w, u.w);
      }
    }
  const float* pv = &v.x;
#pragma unroll
  for (int u = 0; u < 4; ++u) {
    int c = c4 * 4 + u;
    outD[(((size_t)b * 512 + c) * 16 + Y) * 16 + X] = pv[u];
  }
}

// ------------------------------------------------------------------ fully connected
template <bool RELU>
__global__ __launch_bounds__(256) void fc_k(const float* __restrict__ in,
                                            const float* __restrict__ w,
                                            const float* __restrict__ bias,
                                            float* __restrict__ out, int K,
                                            int R) {
  const int r = blockIdx.x;
  const int t = threadIdx.x;
  const float* wr = w + (size_t)r * K;
  float a0 = 0.f, a1 = 0.f;
  for (int k = t * 4; k < K; k += 1024) {
    float4 wv = *(const float4*)(wr + k);
    float4 x0 = *(const float4*)(in + k);
    float4 x1 = *(const float4*)(in + K + k);
    a0 += wv.x * x0.x + wv.y * x0.y + wv.z * x0.z + wv.w * x0.w;
    a1 += wv.x * x1.x + wv.y * x1.y + wv.z * x1.z + wv.w * x1.w;
  }
#pragma unroll
  for (int off = 32; off > 0; off >>= 1) {
    a0 += __shfl_down(a0, off);
    a1 += __shfl_down(a1, off);
  }
  __shared__ float s0[4], s1[4];
  const int lane = t & 63, wid = t >> 6;
  if (lane == 0) { s0[wid] = a0; s1[wid] = a1; }
  __syncthreads();
  if (t == 0) {
    float v0 = s0[0] + s0[1] + s0[2] + s0[3] + bias[r];
    float v1 = s1[0] + s1[1] + s1[2] + s1[3] + bias[r];
    if (RELU) { v0 = fmaxf(v0, 0.f); v1 = fmaxf(v1, 0.f); }
    out[r] = v0;
    out[R + r] = v1;
  }
}

// ------------------------------------------------------------------ launch
extern "C" void kernel_launch(void* const* d_in, const int* in_sizes, int n_in,
                              void* d_out, int out_size, void* d_ws,
                              size_t ws_size, hipStream_t stream) {
  (void)in_sizes; (void)n_in; (void)out_size; (void)ws_size;
  const float* x = (const float*)d_in[0];
  const float* Wc[14];
  const float* Bc[14];
  for (int i = 1; i <= 13; ++i) {
    Wc[i] = (const float*)d_in[2 * i - 1];
    Bc[i] = (const float*)d_in[2 * i];
  }
  const float* fw1 = (const float*)d_in[27];
  const float* fb1 = (const float*)d_in[28];
  const float* fw2 = (const float*)d_in[29];
  const float* fb2 = (const float*)d_in[30];
  const float* fw3 = (const float*)d_in[31];
  const float* fb3 = (const float*)d_in[32];
  const float* fw4 = (const float*)d_in[33];
  const float* fb4 = (const float*)d_in[34];

  static const int CH[14] = {1, 64, 64, 128, 128, 256, 256, 256,
                             512, 512, 512, 512, 512, 512};

  char* ws = (char*)d_ws;
  size_t cur = 0;
  auto alloc = [&](size_t bytes) {
    size_t o = cur;
    cur += (bytes + 255) & ~(size_t)255;
    return o;
  };
  // fp32 weight transposes (L1-L4 only)
  size_t wtOff[5];
  for (int i = 1; i <= 4; ++i)
    wtOff[i] = alloc((size_t)CH[i] * CH[i - 1] * 9 * 4);
  float* wT[5];
  for (int i = 1; i <= 4; ++i) wT[i] = (float*)(ws + wtOff[i]);
  // bf16x3 weight planes (L5-L13): layout [p][k][oc][cin]
  unsigned short* wX[14];
  for (int i = 5; i <= 13; ++i)
    wX[i] = (unsigned short*)(ws + alloc((size_t)3 * 9 * CH[i] * CH[i - 1] * 2));
  // features
  float* F0  = (float*)(ws + alloc((size_t)NMAX512 * 1 * 4));
  size_t a1Off = alloc((size_t)NMAX512 * 64 * 4);
  float* A1  = (float*)(ws + a1Off);
  float* Praw = A1;  // L11-13 K-split partials: 4*NMAX32*512*4 = 16.78MB = A1+A2 exactly
  float* A2  = (float*)(ws + alloc((size_t)NMAX512 * 64 * 4));
  float* P2  = (float*)(ws + alloc((size_t)NMAX256 * 64 * 4));
  float* A3  = (float*)(ws + alloc((size_t)NMAX256 * 128 * 4));
  float* A4  = (float*)(ws + alloc((size_t)NMAX256 * 128 * 4));
  float* P4  = (float*)(ws + alloc((size_t)NMAX128 * 128 * 4));
  float* A5  = (float*)(ws + alloc((size_t)NMAX128 * 256 * 4));
  float* A6  = (float*)(ws + alloc((size_t)NMAX128 * 256 * 4));
  float* P7  = (float*)(ws + alloc((size_t)NMAX64 * 256 * 4));
  float* A8  = (float*)(ws + alloc((size_t)NMAX64 * 512 * 4));
  float* A9  = (float*)(ws + alloc((size_t)NMAX64 * 512 * 4));
  float* P10 = (float*)(ws + alloc((size_t)NMAX32 * 512 * 4));
  float* A11 = (float*)(ws + alloc((size_t)NMAX32 * 512 * 4));
  float* A12 = (float*)(ws + alloc((size_t)NMAX32 * 512 * 4));
  float* D13 = (float*)(ws + alloc((size_t)NB * 512 * 16 * 16 * 4));
  float* F1  = (float*)(ws + alloc(NB * 1024 * 4));
  float* F2  = (float*)(ws + alloc(NB * 512 * 4));
  float* F3  = (float*)(ws + alloc(NB * 256 * 4));
  // bf16x3 feature plane arenas (ping-pong X/Y), each piece NMAX128*256 elems
  const size_t PLE = (size_t)NMAX128 * 256;
  unsigned short* XH = (unsigned short*)(ws + alloc(PLE * 2));
  unsigned short* XM = (unsigned short*)(ws + alloc(PLE * 2));
  unsigned short* XL = (unsigned short*)(ws + alloc(PLE * 2));
  unsigned short* YH = (unsigned short*)(ws + alloc(PLE * 2));
  unsigned short* YM = (unsigned short*)(ws + alloc(PLE * 2));
  unsigned short* YL = (unsigned short*)(ws + alloc(PLE * 2));
  // index maps / lists / neighbor tables / counters
  int* im512 = (int*)(ws + alloc((size_t)NB * 512 * 512 * 4));
  int* im256 = (int*)(ws + alloc((size_t)NB * 256 * 256 * 4));
  int* im128 = (int*)(ws + alloc((size_t)NB * 128 * 128 * 4));
  int* im64  = (int*)(ws + alloc((size_t)NB * 64 * 64 * 4));
  int* im32  = (int*)(ws + alloc((size_t)NB * 32 * 32 * 4));
  int* l512 = (int*)(ws + alloc((size_t)NMAX512 * 4));
  int* l256 = (int*)(ws + alloc((size_t)NMAX256 * 4));
  int* l128 = (int*)(ws + alloc((size_t)NMAX128 * 4));
  int* l64  = (int*)(ws + alloc((size_t)NMAX64 * 4));
  int* l32  = (int*)(ws + alloc((size_t)NMAX32 * 4));
  int* nb512 = (int*)(ws + alloc((size_t)9 * NMAX512 * 4));
  int* nb256 = (int*)(ws + alloc((size_t)9 * NMAX256 * 4));
  int* nb128 = (int*)(ws + alloc((size_t)9 * NMAX128 * 4));
  int* nb64  = (int*)(ws + alloc((size_t)9 * NMAX64 * 4));
  int* nb32  = (int*)(ws + alloc((size_t)9 * NMAX32 * 4));
  int* nact = (int*)(ws + alloc(256));

  const dim3 blk(256);
  hipMemsetAsync(nact, 0, 32, stream);

  // ---- lists / index maps / neighbors
  hipLaunchKernelGGL(build_l0_k, dim3(2048), blk, 0, stream, x, l512, im512, F0, nact + 0, NB * 512 * 512, NMAX512);
  hipLaunchKernelGGL(build_pl_k, dim3(512), blk, 0, stream, im512, l256, im256, nact + 1, 256, NMAX256);
  hipLaunchKernelGGL(build_pl_k, dim3(128), blk, 0, stream, im256, l128, im128, nact + 2, 128, NMAX128);
  hipLaunchKernelGGL(build_pl_k, dim3(32), blk, 0, stream, im128, l64, im64, nact + 3, 64, NMAX64);
  hipLaunchKernelGGL(build_pl_k, dim3(8), blk, 0, stream, im64, l32, im32, nact + 4, 32, NMAX32);
  hipLaunchKernelGGL(build_nbr_k, dim3(NMAX512 / 256), blk, 0, stream, l512, im512, nact + 0, nb512, 512, NMAX512);
  hipLaunchKernelGGL(build_nbr_k, dim3(NMAX256 / 256), blk, 0, stream, l256, im256, nact + 1, nb256, 256, NMAX256);
  hipLaunchKernelGGL(build_nbr_k, dim3(NMAX128 / 256), blk, 0, stream, l128, im128, nact + 2, nb128, 128, NMAX128);
  hipLaunchKernelGGL(build_nbr_k, dim3(NMAX64 / 256), blk, 0, stream, l64, im64, nact + 3, nb64, 64, NMAX64);
  hipLaunchKernelGGL(build_nbr_k, dim3(NMAX32 / 256), blk, 0, stream, l32, im32, nact + 4, nb32, 32, NMAX32);

  // ---- weight prep
  for (int i = 1; i <= 4; ++i) {
    int R = CH[i], C = CH[i - 1] * 9;
    hipLaunchKernelGGL(transpose_k, dim3((C + 31) / 32, (R + 31) / 32), blk, 0,
                       stream, Wc[i], wT[i], R, C);
  }
  for (int i = 5; i <= 13; ++i) {
    int e = CH[i] * CH[i - 1];
    hipLaunchKernelGGL(wprep_k, dim3((e + 255) / 256), blk, 0, stream, Wc[i],
                       wX[i], CH[i], CH[i - 1]);
  }

  // ---- L1-L4 (fp32 path)
  hipLaunchKernelGGL((gconv_k<1, 64, 64, 4, 4>), dim3(512, 1, 1), blk, 0, stream,
                     F0, A1, wT[1], Bc[1], nb512, nact + 0, 1, 64, NMAX512, 1, 1);
  hipLaunchKernelGGL((gconv_k<8, 64, 64, 4, 4>), dim3(512, 1, 1), blk, 0, stream,
                     A1, A2, wT[2], Bc[2], nb512, nact + 0, 64, 64, NMAX512, 64, 1);
  hipLaunchKernelGGL(pool_c_k, dim3(NMAX256 * 16 / 256), blk, 0, stream, A2, P2,
                     l256, im512, nact + 1, 512, 64, (unsigned short*)nullptr,
                     (unsigned short*)nullptr, (unsigned short*)nullptr);
  hipLaunchKernelGGL((gconv_k<8, 64, 128, 4, 8>), dim3(448, 1, 1), blk, 0, stream,
                     P2, A3, wT[3], Bc[3], nb256, nact + 1, 64, 128, NMAX256, 64, 1);
  hipLaunchKernelGGL((gconv_k<8, 64, 128, 4, 8>), dim3(448, 1, 1), blk, 0, stream,
                     A3, A4, wT[4], Bc[4], nb256, nact + 1, 128, 128, NMAX256, 128, 1);
  hipLaunchKernelGGL(pool_c_k, dim3(NMAX128 * 32 / 256), blk, 0, stream, A4, P4,
                     l128, im256, nact + 2, 256, 128, XH, XM, XL);

  // ---- L5-L13 (bf16x3 MFMA path)
  // L5: 128->256 @128; grid = (NMAX128/64)*2 = 640
  hipLaunchKernelGGL((gmfma_k<false>), dim3(640, 1, 1), blk, 0, stream,
                     XH, XM, XL, A5, YH, YM, YL, wX[5], Bc[5], nb128, nact + 2,
                     128, 256, NMAX128, 128, 2);
  // L6: 256->256 @128
  hipLaunchKernelGGL((gmfma_k<false>), dim3(640, 1, 1), blk, 0, stream,
                     YH, YM, YL, A6, XH, XM, XL, wX[6], Bc[6], nb128, nact + 2,
                     256, 256, NMAX128, 256, 2);
  // L7: 256->256 @128 (output feeds pool only -> no planes)
  hipLaunchKernelGGL((gmfma_k<false>), dim3(640, 1, 1), blk, 0, stream,
                     XH, XM, XL, A5, (unsigned short*)nullptr,
                     (unsigned short*)nullptr, (unsigned short*)nullptr, wX[7],
                     Bc[7], nb128, nact + 2, 256, 256, NMAX128, 256, 2);
  hipLaunchKernelGGL(pool_c_k, dim3(NMAX64 * 64 / 256), blk, 0, stream, A5, P7,
                     l64, im128, nact + 3, 128, 256, XH, XM, XL);
  // L8: 256->512 @64; grid = (NMAX64/64)*4 = 512
  hipLaunchKernelGGL((gmfma_k<false>), dim3(512, 1, 1), blk, 0, stream,
                     XH, XM, XL, A8, YH, YM, YL, wX[8], Bc[8], nb64, nact + 3,
                     256, 512, NMAX64, 256, 4);
  // L9: 512->512 @64
  hipLaunchKernelGGL((gmfma_k<false>), dim3(512, 1, 1), blk, 0, stream,
                     YH, YM, YL, A9, XH, XM, XL, wX[9], Bc[9], nb64, nact + 3,
                     512, 512, NMAX64, 512, 4);
  // L10: 512->512 @64 (feeds pool only -> no planes)
  hipLaunchKernelGGL((gmfma_k<false>), dim3(512, 1, 1), blk, 0, stream,
                     XH, XM, XL, A8, (unsigned short*)nullptr,
                     (unsigned short*)nullptr, (unsigned short*)nullptr, wX[10],
                     Bc[10], nb64, nact + 3, 512, 512, NMAX64, 512, 4);
  hipLaunchKernelGGL(pool_c_k, dim3(NMAX32 * 128 / 256), blk, 0, stream, A8, P10,
                     l32, im64, nact + 4, 64, 512, XH, XM, XL);
  // L11-13: 512->512 @32, RAW z=4 (cinCnt=128) -> Praw + combine(+planes)
  const int SL32 = NMAX32 * 512;
  hipLaunchKernelGGL((gmfma_k<true>), dim3(128, 1, 4), blk, 0, stream,
                     XH, XM, XL, Praw, (unsigned short*)nullptr,
                     (unsigned short*)nullptr, (unsigned short*)nullptr, wX[11],
                     (const float*)nullptr, nb32, nact + 4, 512, 512, NMAX32, 128, 4);
  hipLaunchKernelGGL(combine_k, dim3(NMAX32 * 128 / 256), blk, 0, stream, Praw,
                     A11, Bc[11], nact + 4, 512, 4, SL32, YH, YM, YL);
  hipLaunchKernelGGL((gmfma_k<true>), dim3(128, 1, 4), blk, 0, stream,
                     YH, YM, YL, Praw, (unsigned short*)nullptr,
                     (unsigned short*)nullptr, (unsigned short*)nullptr, wX[12],
                     (const float*)nullptr, nb32, nact + 4, 512, 512, NMAX32, 128, 4);
  hipLaunchKernelGGL(combine_k, dim3(NMAX32 * 128 / 256), blk, 0, stream, Praw,
                     A12, Bc[12], nact + 4, 512, 4, SL32, XH, XM, XL);
  hipLaunchKernelGGL((gmfma_k<true>), dim3(128, 1, 4), blk, 0, stream,
                     XH, XM, XL, Praw, (unsigned short*)nullptr,
                     (unsigned short*)nullptr, (unsigned short*)nullptr, wX[13],
                     (const float*)nullptr, nb32, nact + 4, 512, 512, NMAX32, 128, 4);
  hipLaunchKernelGGL(combine_k, dim3(NMAX32 * 128 / 256), blk, 0, stream, Praw,
                     A11, Bc[13], nact + 4, 512, 4, SL32, (unsigned short*)nullptr,
                     (unsigned short*)nullptr, (unsigned short*)nullptr);
  hipLaunchKernelGGL(pool_d_k, dim3(256), blk, 0, stream, A11, D13, im32);

  // ---- MLP
  hipLaunchKernelGGL((fc_k<true>), dim3(1024), blk, 0, stream, D13, fw1, fb1, F1, 131072, 1024);
  hipLaunchKernelGGL((fc_k<true>), dim3(512), blk, 0, stream, F1, fw2, fb2, F2, 1024, 512);
  hipLaunchKernelGGL((fc_k<true>), dim3(256), blk, 0, stream, F2, fw3, fb3, F3, 512, 256);
  hipLaunchKernelGGL((fc_k<false>), dim3(2), blk, 0, stream, F3, fw4, fb4, (float*)d_out, 256, 2);
}

// Round 11
// 2272.333 us; speedup vs baseline: 3.0464x; 1.2928x over previous
//
#include <hip/hip_runtime.h>
#include <hip/hip_bf16.h>
#include <cstddef>
#include <cstdint>

#define NB 2

#define NMAX512 32768
#define NMAX256 28672
#define NMAX128 20480
#define NMAX64  8192
#define NMAX32  2048

typedef __attribute__((ext_vector_type(8))) short bf8v;    // 8 bf16 = 4 VGPR
typedef __attribute__((ext_vector_type(4))) float f32x4;
typedef __attribute__((ext_vector_type(16))) float f32x16;

static __device__ __forceinline__ unsigned short f2bf(float x) {
  __hip_bfloat16 h = __float2bfloat16(x);
  return *reinterpret_cast<unsigned short*>(&h);
}
static __device__ __forceinline__ float bf2f(unsigned short u) {
  __hip_bfloat16 h;
  *reinterpret_cast<unsigned short*>(&h) = u;
  return __bfloat162float(h);
}

// ------------------------------------------------------------------ list build (res 512 from x, Cin=1)
__global__ __launch_bounds__(256) void build_l0_k(const float* __restrict__ x,
    int* __restrict__ list, int* __restrict__ im, float* __restrict__ f0,
    int* __restrict__ nact, int total, int nmax) {
  int i = blockIdx.x * 256 + threadIdx.x;
  bool act = false;
  float v = 0.f;
  if (i < total) { v = x[i]; act = (v != 0.f); }
  unsigned long long mb = __ballot(act);
  int lane = threadIdx.x & 63;
  int prefix = __popcll(mb & ((1ull << lane) - 1));
  int base = 0;
  if (lane == 0) base = atomicAdd(nact, __popcll(mb));
  base = __shfl(base, 0);
  if (i < total) {
    int idx = act ? (base + prefix) : -1;
    if (idx >= nmax) idx = -1;
    im[i] = idx;
    if (idx >= 0) {
      int b = i >> 18;
      int rem = i & 262143;
      list[idx] = (b << 20) | ((rem >> 9) << 10) | (rem & 511);
      f0[idx] = v;
    }
  }
}

// ------------------------------------------------------------------ pooled list from finer idxmap
__global__ __launch_bounds__(256) void build_pl_k(const int* __restrict__ imF,
    int* __restrict__ list, int* __restrict__ im, int* __restrict__ nact,
    int Hc, int nmax) {
  int total = NB * Hc * Hc;
  int i = blockIdx.x * 256 + threadIdx.x;
  bool act = false;
  int b = 0, y = 0, x = 0;
  int Hf = Hc * 2;
  if (i < total) {
    x = i % Hc; y = (i / Hc) % Hc; b = i / (Hc * Hc);
    const int* p = imF + ((size_t)b * Hf + 2 * y) * Hf + 2 * x;
    act = (p[0] >= 0) || (p[1] >= 0) || (p[Hf] >= 0) || (p[Hf + 1] >= 0);
  }
  unsigned long long mb = __ballot(act);
  int lane = threadIdx.x & 63;
  int prefix = __popcll(mb & ((1ull << lane) - 1));
  int base = 0;
  if (lane == 0) base = atomicAdd(nact, __popcll(mb));
  base = __shfl(base, 0);
  if (i < total) {
    int idx = act ? (base + prefix) : -1;
    if (idx >= nmax) idx = -1;
    im[i] = idx;
    if (idx >= 0) list[idx] = (b << 20) | (y << 10) | x;
  }
}

// ------------------------------------------------------------------ 9-neighbor index table
__global__ __launch_bounds__(256) void build_nbr_k(const int* __restrict__ list,
    const int* __restrict__ im, const int* __restrict__ nactp,
    int* __restrict__ nbr, int H, int nmax) {
  int i = blockIdx.x * 256 + threadIdx.x;
  if (i >= nactp[0]) return;
  int code = list[i];
  int b = code >> 20, y = (code >> 10) & 1023, x = code & 1023;
#pragma unroll
  for (int k = 0; k < 9; ++k) {
    int yy = y + k / 3 - 1, xx = x + k % 3 - 1;
    int v = -1;
    if (yy >= 0 && yy < H && xx >= 0 && xx < H)
      v = im[((size_t)b * H + yy) * H + xx];
    nbr[k * nmax + i] = v;
  }
}

// ------------------------------------------------------------------ weight transpose  [R][C] -> [C][R]   (L1-L4 fp32 path)
__global__ __launch_bounds__(256) void transpose_k(const float* __restrict__ in,
                                                   float* __restrict__ out,
                                                   int R, int C) {
  __shared__ float tile[32][33];
  int bx = blockIdx.x * 32;
  int by = blockIdx.y * 32;
  int tx = threadIdx.x % 32, ty0 = threadIdx.x / 32;
  for (int ty = ty0; ty < 32; ty += 8) {
    int r = by + ty, c = bx + tx;
    tile[ty][tx] = (r < R && c < C) ? in[(size_t)r * C + c] : 0.f;
  }
  __syncthreads();
  for (int ty = ty0; ty < 32; ty += 8) {
    int r = bx + ty, c = by + tx;
    if (r < C && c < R) out[(size_t)r * R + c] = tile[tx][ty];
  }
}

// ------------------------------------------------------------------ weight bf16x3 split  w[Cout][Cin][9] -> wx[p][k][oc][cin]
__global__ __launch_bounds__(256) void wprep_k(const float* __restrict__ w,
                                               unsigned short* __restrict__ wx,
                                               int Cout, int Cin) {
  int i = blockIdx.x * 256 + threadIdx.x;
  if (i >= Cout * Cin) return;
  int oc = i / Cin, ci = i - oc * Cin;
  const float* src = w + ((size_t)oc * Cin + ci) * 9;
  const size_t sk = (size_t)Cout * Cin;
#pragma unroll
  for (int k = 0; k < 9; ++k) {
    float x = src[k];
    unsigned short h = f2bf(x);
    float r1 = x - bf2f(h);
    unsigned short m = f2bf(r1);
    float r2 = r1 - bf2f(m);
    wx[(size_t)k * sk + i] = h;
    wx[(size_t)(9 + k) * sk + i] = m;
    wx[(size_t)(18 + k) * sk + i] = f2bf(r2);
  }
}

// ------------------------------------------------------------------ gather-GEMM fp32 (256 thr, 4x8; L1-L4 only)
template <int CC, int SITES, int OCB, int SPT, int OPT>
__global__ __launch_bounds__(256, 2) void gconv_k(
    const float* __restrict__ in, float* __restrict__ out,
    const float* __restrict__ wT, const float* __restrict__ bias,
    const int* __restrict__ nbr, const int* __restrict__ nactp,
    int Cin, int Cout, int Nmax, int cinCnt, int nocb) {
  constexpr int KSL = CC * 9;
  __shared__ int s_nbr[9][SITES];
  __shared__ float s_a[KSL][SITES];
  __shared__ float s_w[KSL][OCB];
  const int n = nactp[0];
  const int gid = blockIdx.x;
  const int xcd = gid & 7;
  const int pos = gid >> 3;
  const int ocbI = pos % nocb;
  const int sb = (pos / nocb) * 8 + xcd;
  const int base = sb * SITES;
  if (base >= n) return;
  const int ocb = ocbI * OCB;
  const int t = threadIdx.x;
  for (int s = t; s < 9 * SITES; s += 256) {
    int i = s % SITES, k = s / SITES;
    int gi = base + i;
    s_nbr[k][i] = (gi < n) ? nbr[k * Nmax + gi] : -1;
  }
  constexpr int OCG = OCB / OPT;
  const int oc0 = (t % OCG) * 4;
  const int si0 = (t / OCG) * SPT;
  float acc[SPT][OPT];
#pragma unroll
  for (int a = 0; a < SPT; ++a)
#pragma unroll
    for (int j = 0; j < OPT; ++j) acc[a][j] = 0.f;
  __syncthreads();
  const int nch = cinCnt / CC;
  for (int ch = 0; ch < nch; ++ch) {
    const int c0 = ch * CC;
    const float* wrow = wT + ((size_t)c0 * 9) * Cout + ocb;
    for (int s = t; s < KSL * (OCB / 4); s += 256) {
      int j4 = s % (OCB / 4), r = s / (OCB / 4);
      *(float4*)&s_w[r][j4 * 4] = *(const float4*)(wrow + (size_t)r * Cout + j4 * 4);
    }
    if constexpr (CC == 1) {
      for (int s = t; s < 9 * SITES; s += 256) {
        int i = s % SITES, k = s / SITES;
        int row = s_nbr[k][i];
        s_a[k][i] = (row >= 0) ? in[row] : 0.f;
      }
    } else {
      constexpr int H4 = CC / 4;
      for (int s = t; s < H4 * 9 * SITES; s += 256) {
        int i = s % SITES, m = s / SITES;
        int c4 = m % H4, k = m / H4;
        int row = s_nbr[k][i];
        float4 v = make_float4(0.f, 0.f, 0.f, 0.f);
        if (row >= 0)
          v = *(const float4*)(in + (size_t)row * Cin + c0 + c4 * 4);
        s_a[(c4 * 4 + 0) * 9 + k][i] = v.x;
        s_a[(c4 * 4 + 1) * 9 + k][i] = v.y;
        s_a[(c4 * 4 + 2) * 9 + k][i] = v.z;
        s_a[(c4 * 4 + 3) * 9 + k][i] = v.w;
      }
    }
    __syncthreads();
#pragma unroll
    for (int kk = 0; kk < KSL; ++kk) {
      float av[SPT];
      if constexpr (SPT == 4) {
        float4 a4 = *(const float4*)&s_a[kk][si0];
        av[0] = a4.x; av[1] = a4.y; av[2] = a4.z; av[3] = a4.w;
      } else {
        float2 a2 = *(const float2*)&s_a[kk][si0];
        av[0] = a2.x; av[1] = a2.y;
      }
      float wv[OPT];
      if constexpr (OPT == 8) {
        float4 w4a = *(const float4*)&s_w[kk][oc0];
        float4 w4b = *(const float4*)&s_w[kk][OCB / 2 + oc0];
        wv[0] = w4a.x; wv[1] = w4a.y; wv[2] = w4a.z; wv[3] = w4a.w;
        wv[4] = w4b.x; wv[5] = w4b.y; wv[6] = w4b.z; wv[7] = w4b.w;
      } else {
        float4 w4 = *(const float4*)&s_w[kk][oc0];
        wv[0] = w4.x; wv[1] = w4.y; wv[2] = w4.z; wv[3] = w4.w;
      }
#pragma unroll
      for (int a = 0; a < SPT; ++a)
#pragma unroll
        for (int j = 0; j < OPT; ++j)
          acc[a][j] = fmaf(av[a], wv[j], acc[a][j]);
    }
    __syncthreads();
  }
  float bz[OPT];
#pragma unroll
  for (int j = 0; j < OPT; ++j) {
    int oj = (OPT == 8) ? ((j < 4) ? (oc0 + j) : (OCB / 2 + oc0 + j - 4))
                        : (oc0 + j);
    bz[j] = bias[ocb + oj];
  }
#pragma unroll
  for (int a = 0; a < SPT; ++a) {
    int gi = base + si0 + a;
    if (gi < n) {
      float* po = out + (size_t)gi * Cout + ocb;
      if constexpr (OPT == 8) {
        float4 v0, v1;
        v0.x = fmaxf(acc[a][0] + bz[0], 0.f); v0.y = fmaxf(acc[a][1] + bz[1], 0.f);
        v0.z = fmaxf(acc[a][2] + bz[2], 0.f); v0.w = fmaxf(acc[a][3] + bz[3], 0.f);
        v1.x = fmaxf(acc[a][4] + bz[4], 0.f); v1.y = fmaxf(acc[a][5] + bz[5], 0.f);
        v1.z = fmaxf(acc[a][6] + bz[6], 0.f); v1.w = fmaxf(acc[a][7] + bz[7], 0.f);
        *(float4*)(po + oc0) = v0;
        *(float4*)(po + OCB / 2 + oc0) = v1;
      } else {
        float4 v;
        v.x = fmaxf(acc[a][0] + bz[0], 0.f); v.y = fmaxf(acc[a][1] + bz[1], 0.f);
        v.z = fmaxf(acc[a][2] + bz[2], 0.f); v.w = fmaxf(acc[a][3] + bz[3], 0.f);
        *(float4*)(po + oc0) = v;
      }
    }
  }
}

// ------------------------------------------------------------------ bf16x3 32x32x16 MFMA gather-GEMM (L5-L13, RAW K-split)
// Block: 128 sites x 128 oc, 4 waves (2x2), each wave 2x2 tiles of 32x32.
// Dense LDS layout [piece][khalf][row][8ch]: 16B units, lane-contiguous frag
// reads and staging writes -> conflict-free (r10 had 4.1e7 conflicts from
// 80B-stride rows). LDS 29.2KB; __launch_bounds__(256,2) pins VGPR<=128
// (r9 cliff lesson). 6 MFMAs reconstruct fp32 (bf16x3; r10-verified).
// C/D (guide m74/m101): col(lane&31)=oc side, row=(reg&3)+8*(reg>>2)+4*(l>>5).
__global__ __launch_bounds__(256, 2) void gmfma32_k(
    const unsigned short* __restrict__ AH, const unsigned short* __restrict__ AM,
    const unsigned short* __restrict__ AL, float* __restrict__ outP,
    const unsigned short* __restrict__ WX, const int* __restrict__ nbr,
    const int* __restrict__ nactp, int Cin, int Cout, int Nmax, int cinCnt,
    int nocb) {
  __shared__ int s_nbr[9][128];
  __shared__ __align__(16) unsigned short s_a[3][2][128][8];
  __shared__ __align__(16) unsigned short s_w[3][2][128][8];
  const int n = nactp[0];
  const int gid = blockIdx.x;
  const int xcd = gid & 7, pos = gid >> 3;
  const int ocbI = pos % nocb;
  const int sb = (pos / nocb) * 8 + xcd;
  const int base = sb * 128;
  if (base >= n) return;
  const int ocb = ocbI * 128;
  const int t = threadIdx.x;
  for (int s = t; s < 1152; s += 256) {
    int i = s & 127, k = s >> 7;
    s_nbr[k][i] = (base + i < n) ? nbr[k * Nmax + base + i] : -1;
  }
  const int l = t & 63;
  const int wm = (t >> 6) & 1, wn = t >> 7;
  const int kh = l >> 5, lr = l & 31;
  const int skh = t >> 7, ssi = t & 127;   // staging: (khalf, site/oc)
  f32x16 acc[2][2];
#pragma unroll
  for (int a = 0; a < 2; ++a)
#pragma unroll
    for (int b = 0; b < 2; ++b)
#pragma unroll
      for (int r = 0; r < 16; ++r) acc[a][b][r] = 0.f;
  __syncthreads();
  const int cinStart = blockIdx.z * cinCnt;
  const int nck = cinCnt >> 4;
  const size_t pstride = (size_t)9 * Cout * Cin;
  for (int k = 0; k < 9; ++k) {
    const unsigned short* Wk =
        WX + ((size_t)k * Cout + ocb + ssi) * Cin + skh * 8;
    for (int cc = 0; cc < nck; ++cc) {
      const int c0 = cinStart + (cc << 4);
      // stage W: 3 pieces, this thread's (khalf, oc) slot
      {
        const unsigned short* W0 = Wk + c0;
        *(float4*)&s_w[0][skh][ssi][0] = *(const float4*)(W0);
        *(float4*)&s_w[1][skh][ssi][0] = *(const float4*)(W0 + pstride);
        *(float4*)&s_w[2][skh][ssi][0] = *(const float4*)(W0 + 2 * pstride);
      }
      // stage A (gather): 3 pieces, this thread's (khalf, site) slot
      {
        int row = s_nbr[k][ssi];
        if (row >= 0) {
          const size_t off = (size_t)row * Cin + c0 + skh * 8;
          *(float4*)&s_a[0][skh][ssi][0] = *(const float4*)(AH + off);
          *(float4*)&s_a[1][skh][ssi][0] = *(const float4*)(AM + off);
          *(float4*)&s_a[2][skh][ssi][0] = *(const float4*)(AL + off);
        } else {
          float4 z = make_float4(0.f, 0.f, 0.f, 0.f);
          *(float4*)&s_a[0][skh][ssi][0] = z;
          *(float4*)&s_a[1][skh][ssi][0] = z;
          *(float4*)&s_a[2][skh][ssi][0] = z;
        }
      }
      __syncthreads();
      bf8v af[2][3], wf[2][3];
#pragma unroll
      for (int mi = 0; mi < 2; ++mi)
#pragma unroll
        for (int p = 0; p < 3; ++p)
          af[mi][p] = *(const bf8v*)&s_a[p][kh][wm * 64 + mi * 32 + lr][0];
#pragma unroll
      for (int ni = 0; ni < 2; ++ni)
#pragma unroll
        for (int p = 0; p < 3; ++p)
          wf[ni][p] = *(const bf8v*)&s_w[p][kh][wn * 64 + ni * 32 + lr][0];
#pragma unroll
      for (int mi = 0; mi < 2; ++mi)
#pragma unroll
        for (int ni = 0; ni < 2; ++ni) {
          f32x16 c = acc[mi][ni];
          c = __builtin_amdgcn_mfma_f32_32x32x16_bf16(af[mi][0], wf[ni][0], c, 0, 0, 0);
          c = __builtin_amdgcn_mfma_f32_32x32x16_bf16(af[mi][0], wf[ni][1], c, 0, 0, 0);
          c = __builtin_amdgcn_mfma_f32_32x32x16_bf16(af[mi][1], wf[ni][0], c, 0, 0, 0);
          c = __builtin_amdgcn_mfma_f32_32x32x16_bf16(af[mi][1], wf[ni][1], c, 0, 0, 0);
          c = __builtin_amdgcn_mfma_f32_32x32x16_bf16(af[mi][0], wf[ni][2], c, 0, 0, 0);
          c = __builtin_amdgcn_mfma_f32_32x32x16_bf16(af[mi][2], wf[ni][0], c, 0, 0, 0);
          acc[mi][ni] = c;
        }
      __syncthreads();
    }
  }
  float* ob = outP + (size_t)blockIdx.z * Nmax * Cout;
#pragma unroll
  for (int mi = 0; mi < 2; ++mi) {
    const int sbase = base + wm * 64 + mi * 32 + 4 * kh;
#pragma unroll
    for (int ni = 0; ni < 2; ++ni) {
      const int oc = ocb + wn * 64 + ni * 32 + lr;
#pragma unroll
      for (int reg = 0; reg < 16; ++reg) {
        int gi = sbase + (reg & 3) + 8 * (reg >> 2);
        if (gi < n) ob[(size_t)gi * Cout + oc] = acc[mi][ni][reg];
      }
    }
  }
}

// ------------------------------------------------------------------ K-split combine (+bias+relu; optional f32 out; optional bf16x3 planes)
__global__ __launch_bounds__(256) void combine_k(const float* __restrict__ P,
    float* __restrict__ out, const float* __restrict__ bias,
    const int* __restrict__ nactp, int C, int S, int sliceStride,
    unsigned short* __restrict__ oh, unsigned short* __restrict__ om,
    unsigned short* __restrict__ ol) {
  int tg = blockIdx.x * 256 + threadIdx.x;
  int cg = C >> 2;
  int j = tg / cg, c4 = tg % cg;
  if (j >= nactp[0]) return;
  size_t o = (size_t)j * C + c4 * 4;
  float4 v = *(const float4*)(bias + c4 * 4);
  for (int s = 0; s < S; ++s) {
    float4 u = *(const float4*)(P + (size_t)s * sliceStride + o);
    v.x += u.x; v.y += u.y; v.z += u.z; v.w += u.w;
  }
  v.x = fmaxf(v.x, 0.f); v.y = fmaxf(v.y, 0.f);
  v.z = fmaxf(v.z, 0.f); v.w = fmaxf(v.w, 0.f);
  if (out) *(float4*)(out + o) = v;
  if (oh) {
    const float* pv = &v.x;
#pragma unroll
    for (int u = 0; u < 4; ++u) {
      float y = pv[u];
      unsigned short h = f2bf(y);
      float r1 = y - bf2f(h);
      unsigned short m2 = f2bf(r1);
      float r2 = r1 - bf2f(m2);
      oh[o + u] = h; om[o + u] = m2; ol[o + u] = f2bf(r2);
    }
  }
}

// ------------------------------------------------------------------ compact 2x2 maxpool (optional bf16x3 planes)
__global__ __launch_bounds__(256) void pool_c_k(const float* __restrict__ inF,
    float* __restrict__ outF, const int* __restrict__ listC,
    const int* __restrict__ imF, const int* __restrict__ nactp, int Hf, int C,
    unsigned short* __restrict__ oh, unsigned short* __restrict__ om,
    unsigned short* __restrict__ ol) {
  int tg = blockIdx.x * 256 + threadIdx.x;
  int cg = C >> 2;
  int j = tg / cg, c4 = tg % cg;
  if (j >= nactp[0]) return;
  int code = listC[j];
  int b = code >> 20, Y = (code >> 10) & 1023, X = code & 1023;
  float4 v = make_float4(0.f, 0.f, 0.f, 0.f);
#pragma unroll
  for (int dy = 0; dy < 2; ++dy)
#pragma unroll
    for (int dx = 0; dx < 2; ++dx) {
      int ci = imF[((size_t)b * Hf + 2 * Y + dy) * Hf + 2 * X + dx];
      if (ci >= 0) {
        float4 u = *(const float4*)(inF + (size_t)ci * C + c4 * 4);
        v.x = fmaxf(v.x, u.x); v.y = fmaxf(v.y, u.y);
        v.z = fmaxf(v.z, u.z); v.w = fmaxf(v.w, u.w);
      }
    }
  size_t o = (size_t)j * C + c4 * 4;
  *(float4*)(outF + o) = v;
  if (oh) {
    const float* pv = &v.x;
#pragma unroll
    for (int u = 0; u < 4; ++u) {
      float y = pv[u];
      unsigned short h = f2bf(y);
      float r1 = y - bf2f(h);
      unsigned short m2 = f2bf(r1);
      float r2 = r1 - bf2f(m2);
      oh[o + u] = h; om[o + u] = m2; ol[o + u] = f2bf(r2);
    }
  }
}

// ------------------------------------------------------------------ final pool -> dense [2,512,16,16]
__global__ __launch_bounds__(256) void pool_d_k(const float* __restrict__ inF,
    float* __restrict__ outD, const int* __restrict__ im32) {
  int tg = blockIdx.x * 256 + threadIdx.x;
  int c4 = tg & 127;
  int rest = tg >> 7;
  int X = rest & 15, Y = (rest >> 4) & 15, b = rest >> 8;
  float4 v = make_float4(0.f, 0.f, 0.f, 0.f);
#pragma unroll
  for (int dy = 0; dy < 2; ++dy)
#pragma unroll
    for (int dx = 0; dx < 2; ++dx) {
      int ci = im32[((size_t)b * 32 + 2 * Y + dy) * 32 + 2 * X + dx];
      if (ci >= 0) {
        float4 u = *(const float4*)(inF + (size_t)ci * 512 + c4 * 4);
        v.x = fmaxf(v.x, u.x); v.y = fmaxf(v.y, u.y);
        v.z = fmaxf(v.z, u.z); v.w = fmaxf(v.w, u.w);
      }
    }
  const float* pv = &v.x;
#pragma unroll
  for (int u = 0; u < 4; ++u) {
    int c = c4 * 4 + u;
    outD[(((size_t)b * 512 + c) * 16 + Y) * 16 + X] = pv[u];
  }
}

// ------------------------------------------------------------------ fully connected
template <bool RELU>
__global__ __launch_bounds__(256) void fc_k(const float* __restrict__ in,
                                            const float* __restrict__ w,
                                            const float* __restrict__ bias,
                                            float* __restrict__ out, int K,
                                            int R) {
  const int r = blockIdx.x;
  const int t = threadIdx.x;
  const float* wr = w + (size_t)r * K;
  float a0 = 0.f, a1 = 0.f;
  for (int k = t * 4; k < K; k += 1024) {
    float4 wv = *(const float4*)(wr + k);
    float4 x0 = *(const float4*)(in + k);
    float4 x1 = *(const float4*)(in + K + k);
    a0 += wv.x * x0.x + wv.y * x0.y + wv.z * x0.z + wv.w * x0.w;
    a1 += wv.x * x1.x + wv.y * x1.y + wv.z * x1.z + wv.w * x1.w;
  }
#pragma unroll
  for (int off = 32; off > 0; off >>= 1) {
    a0 += __shfl_down(a0, off);
    a1 += __shfl_down(a1, off);
  }
  __shared__ float s0[4], s1[4];
  const int lane = t & 63, wid = t >> 6;
  if (lane == 0) { s0[wid] = a0; s1[wid] = a1; }
  __syncthreads();
  if (t == 0) {
    float v0 = s0[0] + s0[1] + s0[2] + s0[3] + bias[r];
    float v1 = s1[0] + s1[1] + s1[2] + s1[3] + bias[r];
    if (RELU) { v0 = fmaxf(v0, 0.f); v1 = fmaxf(v1, 0.f); }
    out[r] = v0;
    out[R + r] = v1;
  }
}

// ------------------------------------------------------------------ launch
extern "C" void kernel_launch(void* const* d_in, const int* in_sizes, int n_in,
                              void* d_out, int out_size, void* d_ws,
                              size_t ws_size, hipStream_t stream) {
  (void)in_sizes; (void)n_in; (void)out_size; (void)ws_size;
  const float* x = (const float*)d_in[0];
  const float* Wc[14];
  const float* Bc[14];
  for (int i = 1; i <= 13; ++i) {
    Wc[i] = (const float*)d_in[2 * i - 1];
    Bc[i] = (const float*)d_in[2 * i];
  }
  const float* fw1 = (const float*)d_in[27];
  const float* fb1 = (const float*)d_in[28];
  const float* fw2 = (const float*)d_in[29];
  const float* fb2 = (const float*)d_in[30];
  const float* fw3 = (const float*)d_in[31];
  const float* fb3 = (const float*)d_in[32];
  const float* fw4 = (const float*)d_in[33];
  const float* fb4 = (const float*)d_in[34];

  static const int CH[14] = {1, 64, 64, 128, 128, 256, 256, 256,
                             512, 512, 512, 512, 512, 512};

  char* ws = (char*)d_ws;
  size_t cur = 0;
  auto alloc = [&](size_t bytes) {
    size_t o = cur;
    cur += (bytes + 255) & ~(size_t)255;
    return o;
  };
  // fp32 weight transposes (L1-L4)
  size_t wtOff[5];
  for (int i = 1; i <= 4; ++i)
    wtOff[i] = alloc((size_t)CH[i] * CH[i - 1] * 9 * 4);
  float* wT[5];
  for (int i = 1; i <= 4; ++i) wT[i] = (float*)(ws + wtOff[i]);
  // bf16x3 weight planes (L5-L13): layout [p][k][oc][cin]
  unsigned short* wX[14];
  for (int i = 5; i <= 13; ++i)
    wX[i] = (unsigned short*)(ws + alloc((size_t)3 * 9 * CH[i] * CH[i - 1] * 2));
  // features. Praw (K-split partials, contiguous) aliases A1..P4 (63.9MB,
  // all dead before L5): L5-7 need 42MB, L8-10 33.6MB, L11-13 33.6MB.
  float* F0  = (float*)(ws + alloc((size_t)NMAX512 * 1 * 4));
  size_t a1Off = alloc((size_t)NMAX512 * 64 * 4);
  float* A1  = (float*)(ws + a1Off);
  float* Praw = A1;
  float* A2  = (float*)(ws + alloc((size_t)NMAX512 * 64 * 4));
  float* P2  = (float*)(ws + alloc((size_t)NMAX256 * 64 * 4));
  float* A3  = (float*)(ws + alloc((size_t)NMAX256 * 128 * 4));
  float* A4  = (float*)(ws + alloc((size_t)NMAX256 * 128 * 4));
  float* P4  = (float*)(ws + alloc((size_t)NMAX128 * 128 * 4));
  float* A5  = (float*)(ws + alloc((size_t)NMAX128 * 256 * 4));
  float* P7  = (float*)(ws + alloc((size_t)NMAX64 * 256 * 4));
  float* A8  = (float*)(ws + alloc((size_t)NMAX64 * 512 * 4));
  float* P10 = (float*)(ws + alloc((size_t)NMAX32 * 512 * 4));
  float* A11 = (float*)(ws + alloc((size_t)NMAX32 * 512 * 4));
  float* D13 = (float*)(ws + alloc((size_t)NB * 512 * 16 * 16 * 4));
  float* F1  = (float*)(ws + alloc(NB * 1024 * 4));
  float* F2  = (float*)(ws + alloc(NB * 512 * 4));
  float* F3  = (float*)(ws + alloc(NB * 256 * 4));
  // bf16x3 feature plane arenas (ping-pong X/Y)
  const size_t PLE = (size_t)NMAX128 * 256;
  unsigned short* XH = (unsigned short*)(ws + alloc(PLE * 2));
  unsigned short* XM = (unsigned short*)(ws + alloc(PLE * 2));
  unsigned short* XL = (unsigned short*)(ws + alloc(PLE * 2));
  unsigned short* YH = (unsigned short*)(ws + alloc(PLE * 2));
  unsigned short* YM = (unsigned short*)(ws + alloc(PLE * 2));
  unsigned short* YL = (unsigned short*)(ws + alloc(PLE * 2));
  // index maps / lists / neighbor tables / counters
  int* im512 = (int*)(ws + alloc((size_t)NB * 512 * 512 * 4));
  int* im256 = (int*)(ws + alloc((size_t)NB * 256 * 256 * 4));
  int* im128 = (int*)(ws + alloc((size_t)NB * 128 * 128 * 4));
  int* im64  = (int*)(ws + alloc((size_t)NB * 64 * 64 * 4));
  int* im32  = (int*)(ws + alloc((size_t)NB * 32 * 32 * 4));
  int* l512 = (int*)(ws + alloc((size_t)NMAX512 * 4));
  int* l256 = (int*)(ws + alloc((size_t)NMAX256 * 4));
  int* l128 = (int*)(ws + alloc((size_t)NMAX128 * 4));
  int* l64  = (int*)(ws + alloc((size_t)NMAX64 * 4));
  int* l32  = (int*)(ws + alloc((size_t)NMAX32 * 4));
  int* nb512 = (int*)(ws + alloc((size_t)9 * NMAX512 * 4));
  int* nb256 = (int*)(ws + alloc((size_t)9 * NMAX256 * 4));
  int* nb128 = (int*)(ws + alloc((size_t)9 * NMAX128 * 4));
  int* nb64  = (int*)(ws + alloc((size_t)9 * NMAX64 * 4));
  int* nb32  = (int*)(ws + alloc((size_t)9 * NMAX32 * 4));
  int* nact = (int*)(ws + alloc(256));

  const dim3 blk(256);
  hipMemsetAsync(nact, 0, 32, stream);

  // ---- lists / index maps / neighbors
  hipLaunchKernelGGL(build_l0_k, dim3(2048), blk, 0, stream, x, l512, im512, F0, nact + 0, NB * 512 * 512, NMAX512);
  hipLaunchKernelGGL(build_pl_k, dim3(512), blk, 0, stream, im512, l256, im256, nact + 1, 256, NMAX256);
  hipLaunchKernelGGL(build_pl_k, dim3(128), blk, 0, stream, im256, l128, im128, nact + 2, 128, NMAX128);
  hipLaunchKernelGGL(build_pl_k, dim3(32), blk, 0, stream, im128, l64, im64, nact + 3, 64, NMAX64);
  hipLaunchKernelGGL(build_pl_k, dim3(8), blk, 0, stream, im64, l32, im32, nact + 4, 32, NMAX32);
  hipLaunchKernelGGL(build_nbr_k, dim3(NMAX512 / 256), blk, 0, stream, l512, im512, nact + 0, nb512, 512, NMAX512);
  hipLaunchKernelGGL(build_nbr_k, dim3(NMAX256 / 256), blk, 0, stream, l256, im256, nact + 1, nb256, 256, NMAX256);
  hipLaunchKernelGGL(build_nbr_k, dim3(NMAX128 / 256), blk, 0, stream, l128, im128, nact + 2, nb128, 128, NMAX128);
  hipLaunchKernelGGL(build_nbr_k, dim3(NMAX64 / 256), blk, 0, stream, l64, im64, nact + 3, nb64, 64, NMAX64);
  hipLaunchKernelGGL(build_nbr_k, dim3(NMAX32 / 256), blk, 0, stream, l32, im32, nact + 4, nb32, 32, NMAX32);

  // ---- weight prep
  for (int i = 1; i <= 4; ++i) {
    int R = CH[i], C = CH[i - 1] * 9;
    hipLaunchKernelGGL(transpose_k, dim3((C + 31) / 32, (R + 31) / 32), blk, 0,
                       stream, Wc[i], wT[i], R, C);
  }
  for (int i = 5; i <= 13; ++i) {
    int e = CH[i] * CH[i - 1];
    hipLaunchKernelGGL(wprep_k, dim3((e + 255) / 256), blk, 0, stream, Wc[i],
                       wX[i], CH[i], CH[i - 1]);
  }

  // ---- L1-L4 (fp32 path)
  hipLaunchKernelGGL((gconv_k<1, 64, 64, 4, 4>), dim3(512, 1, 1), blk, 0, stream,
                     F0, A1, wT[1], Bc[1], nb512, nact + 0, 1, 64, NMAX512, 1, 1);
  hipLaunchKernelGGL((gconv_k<8, 64, 64, 4, 4>), dim3(512, 1, 1), blk, 0, stream,
                     A1, A2, wT[2], Bc[2], nb512, nact + 0, 64, 64, NMAX512, 64, 1);
  hipLaunchKernelGGL(pool_c_k, dim3(NMAX256 * 16 / 256), blk, 0, stream, A2, P2,
                     l256, im512, nact + 1, 512, 64, (unsigned short*)nullptr,
                     (unsigned short*)nullptr, (unsigned short*)nullptr);
  hipLaunchKernelGGL((gconv_k<8, 64, 128, 4, 8>), dim3(448, 1, 1), blk, 0, stream,
                     P2, A3, wT[3], Bc[3], nb256, nact + 1, 64, 128, NMAX256, 64, 1);
  hipLaunchKernelGGL((gconv_k<8, 64, 128, 4, 8>), dim3(448, 1, 1), blk, 0, stream,
                     A3, A4, wT[4], Bc[4], nb256, nact + 1, 128, 128, NMAX256, 128, 1);
  hipLaunchKernelGGL(pool_c_k, dim3(NMAX128 * 32 / 256), blk, 0, stream, A4, P4,
                     l128, im256, nact + 2, 256, 128, XH, XM, XL);

  // ---- L5-L13 (bf16x3 32x32 MFMA, all RAW K-split -> Praw arena + combine)
  unsigned short* NUL = nullptr;
  const int SL128 = NMAX128 * 256;
  const int SL64  = NMAX64 * 512;
  const int SL32  = NMAX32 * 512;
  // L5: 128->256 @128, z=2 (cinCnt 64); 160 sb x nocb2 = 320
  hipLaunchKernelGGL(gmfma32_k, dim3(320, 1, 2), blk, 0, stream,
                     XH, XM, XL, Praw, wX[5], nb128, nact + 2, 128, 256, NMAX128, 64, 2);
  hipLaunchKernelGGL(combine_k, dim3(NMAX128 * 64 / 256), blk, 0, stream, Praw,
                     (float*)nullptr, Bc[5], nact + 2, 256, 2, SL128, YH, YM, YL);
  // L6: 256->256 @128, z=2 (cinCnt 128)
  hipLaunchKernelGGL(gmfma32_k, dim3(320, 1, 2), blk, 0, stream,
                     YH, YM, YL, Praw, wX[6], nb128, nact + 2, 256, 256, NMAX128, 128, 2);
  hipLaunchKernelGGL(combine_k, dim3(NMAX128 * 64 / 256), blk, 0, stream, Praw,
                     (float*)nullptr, Bc[6], nact + 2, 256, 2, SL128, XH, XM, XL);
  // L7: 256->256 @128, z=2 -> f32 only (feeds pool)
  hipLaunchKernelGGL(gmfma32_k, dim3(320, 1, 2), blk, 0, stream,
                     XH, XM, XL, Praw, wX[7], nb128, nact + 2, 256, 256, NMAX128, 128, 2);
  hipLaunchKernelGGL(combine_k, dim3(NMAX128 * 64 / 256), blk, 0, stream, Praw,
                     A5, Bc[7], nact + 2, 256, 2, SL128, NUL, NUL, NUL);
  hipLaunchKernelGGL(pool_c_k, dim3(NMAX64 * 64 / 256), blk, 0, stream, A5, P7,
                     l64, im128, nact + 3, 128, 256, XH, XM, XL);
  // L8: 256->512 @64, z=2 (cinCnt 128); 64 sb x nocb4 = 256
  hipLaunchKernelGGL(gmfma32_k, dim3(256, 1, 2), blk, 0, stream,
                     XH, XM, XL, Praw, wX[8], nb64, nact + 3, 256, 512, NMAX64, 128, 4);
  hipLaunchKernelGGL(combine_k, dim3(NMAX64 * 128 / 256), blk, 0, stream, Praw,
                     (float*)nullptr, Bc[8], nact + 3, 512, 2, SL64, YH, YM, YL);
  // L9: 512->512 @64, z=2 (cinCnt 256)
  hipLaunchKernelGGL(gmfma32_k, dim3(256, 1, 2), blk, 0, stream,
                     YH, YM, YL, Praw, wX[9], nb64, nact + 3, 512, 512, NMAX64, 256, 4);
  hipLaunchKernelGGL(combine_k, dim3(NMAX64 * 128 / 256), blk, 0, stream, Praw,
                     (float*)nullptr, Bc[9], nact + 3, 512, 2, SL64, XH, XM, XL);
  // L10: 512->512 @64, z=2 -> f32 only (feeds pool)
  hipLaunchKernelGGL(gmfma32_k, dim3(256, 1, 2), blk, 0, stream,
                     XH, XM, XL, Praw, wX[10], nb64, nact + 3, 512, 512, NMAX64, 256, 4);
  hipLaunchKernelGGL(combine_k, dim3(NMAX64 * 128 / 256), blk, 0, stream, Praw,
                     A8, Bc[10], nact + 3, 512, 2, SL64, NUL, NUL, NUL);
  hipLaunchKernelGGL(pool_c_k, dim3(NMAX32 * 128 / 256), blk, 0, stream, A8, P10,
                     l32, im64, nact + 4, 64, 512, XH, XM, XL);
  // L11-13: 512->512 @32, z=8 (cinCnt 64); 16 sb x nocb4 = 64
  hipLaunchKernelGGL(gmfma32_k, dim3(64, 1, 8), blk, 0, stream,
                     XH, XM, XL, Praw, wX[11], nb32, nact + 4, 512, 512, NMAX32, 64, 4);
  hipLaunchKernelGGL(combine_k, dim3(NMAX32 * 128 / 256), blk, 0, stream, Praw,
                     (float*)nullptr, Bc[11], nact + 4, 512, 8, SL32, YH, YM, YL);
  hipLaunchKernelGGL(gmfma32_k, dim3(64, 1, 8), blk, 0, stream,
                     YH, YM, YL, Praw, wX[12], nb32, nact + 4, 512, 512, NMAX32, 64, 4);
  hipLaunchKernelGGL(combine_k, dim3(NMAX32 * 128 / 256), blk, 0, stream, Praw,
                     (float*)nullptr, Bc[12], nact + 4, 512, 8, SL32, XH, XM, XL);
  hipLaunchKernelGGL(gmfma32_k, dim3(64, 1, 8), blk, 0, stream,
                     XH, XM, XL, Praw, wX[13], nb32, nact + 4, 512, 512, NMAX32, 64, 4);
  hipLaunchKernelGGL(combine_k, dim3(NMAX32 * 128 / 256), blk, 0, stream, Praw,
                     A11, Bc[13], nact + 4, 512, 8, SL32, NUL, NUL, NUL);
  hipLaunchKernelGGL(pool_d_k, dim3(256), blk, 0, stream, A11, D13, im32);

  // ---- MLP
  hipLaunchKernelGGL((fc_k<true>), dim3(1024), blk, 0, stream, D13, fw1, fb1, F1, 131072, 1024);
  hipLaunchKernelGGL((fc_k<true>), dim3(512), blk, 0, stream, F1, fw2, fb2, F2, 1024, 512);
  hipLaunchKernelGGL((fc_k<true>), dim3(256), blk, 0, stream, F2, fw3, fb3, F3, 512, 256);
  hipLaunchKernelGGL((fc_k<false>), dim3(2), blk, 0, stream, F3, fw4, fb4, (float*)d_out, 256, 2);
}